// Round 1
// baseline (955.518 us; speedup 1.0000x reference)
//
#include <hip/hip_runtime.h>
#include <math.h>

#define B 1024
#define M 15
#define H 256
#define E 256
#define V 30000
#define U 1000

// output layout (flat f32 concat, reference return order)
#define O_OUT   0
#define O_HID   ((size_t)B*V)
#define O_EMB   (O_HID + (size_t)B*H)
#define O_GRU   (O_EMB + (size_t)B*E)
#define O_ATT   (O_GRU + (size_t)B*H)

// ---------------- Stage A: per-user attention ----------------
__global__ __launch_bounds__(256) void attn_kernel(
    const float* __restrict__ hidden,       // (1,B,H)
    const float* __restrict__ inter_output, // (B,M,H)
    const int*   __restrict__ user_list,    // (B,)
    const float* __restrict__ inter_W,      // (U,H,H)
    const float* __restrict__ inter_b,      // (U,H)
    const float* __restrict__ hidden_W,     // (U,H,H)
    const float* __restrict__ hidden_b,     // (U,H)
    const float* __restrict__ lt1_W,        // (U,2H,H)
    const float* __restrict__ lt1_b,        // (U,H)
    const float* __restrict__ scale_W,      // (U,H)
    const float* __restrict__ scale_b,      // (U,)
    float* __restrict__ out,
    float* __restrict__ ctx_ws)             // (B,H)
{
    const int b   = blockIdx.x;
    const int tid = threadIdx.x;
    const int u   = user_list[b];

    __shared__ float ht[H];
    __shared__ float io[M * H];
    __shared__ float ht_a[H];
    __shared__ float io_a[M * H];
    __shared__ float red[4 * 16];
    __shared__ float e_lds[M];

    ht[tid] = hidden[b * H + tid];
    for (int i = tid; i < M * H; i += 256) io[i] = inter_output[(size_t)b * M * H + i];
    __syncthreads();

    // hidden_t_a[o] = sum_h ht[h] * hidden_W[u][h][o] + hidden_b[u][o]
    {
        float a = hidden_b[(size_t)u * H + tid];
        const float* W = hidden_W + (size_t)u * H * H + tid;
        #pragma unroll 4
        for (int h = 0; h < H; ++h) a += ht[h] * W[(size_t)h * H];
        ht_a[tid] = a;
    }

    // inter_output_a[m][o] = sum_h io[m][h] * inter_W[u][h][o] + inter_b[u][o]
    float acc[M];
    {
        float ib = inter_b[(size_t)u * H + tid];
        #pragma unroll
        for (int m = 0; m < M; ++m) acc[m] = ib;
        const float* W = inter_W + (size_t)u * H * H + tid;
        #pragma unroll 2
        for (int h = 0; h < H; ++h) {
            float w = W[(size_t)h * H];
            #pragma unroll
            for (int m = 0; m < M; ++m) acc[m] += io[m * H + h] * w;
        }
    }
    #pragma unroll
    for (int m = 0; m < M; ++m) io_a[m * H + tid] = acc[m];
    __syncthreads();

    // result[m][o] = tanh( sum_k ht_a[k]*lt1_W[u][k][o]
    //                    + sum_k io_a[m][k]*lt1_W[u][H+k][o] + lt1_b[u][o] )
    float res[M];
    {
        float base = lt1_b[(size_t)u * H + tid];
        const float* W1 = lt1_W + (size_t)u * 2 * H * H + tid;
        #pragma unroll 4
        for (int k = 0; k < H; ++k) base += ht_a[k] * W1[(size_t)k * H];
        #pragma unroll
        for (int m = 0; m < M; ++m) res[m] = 0.f;
        const float* W2 = W1 + (size_t)H * H;
        #pragma unroll 2
        for (int k = 0; k < H; ++k) {
            float w = W2[(size_t)k * H];
            #pragma unroll
            for (int m = 0; m < M; ++m) res[m] += io_a[m * H + k] * w;
        }
        #pragma unroll
        for (int m = 0; m < M; ++m) res[m] = tanhf(base + res[m]);
    }

    // energies[m] = sum_o res[m][o] * scale_W[u][o] + scale_b[u]
    {
        float sw = scale_W[(size_t)u * H + tid];
        #pragma unroll
        for (int m = 0; m < M; ++m) {
            float v = res[m] * sw;
            #pragma unroll
            for (int off = 32; off > 0; off >>= 1) v += __shfl_down(v, off, 64);
            if ((tid & 63) == 0) red[(tid >> 6) * 16 + m] = v;
        }
        __syncthreads();
        if (tid < M)
            e_lds[tid] = red[0 * 16 + tid] + red[1 * 16 + tid] + red[2 * 16 + tid] + red[3 * 16 + tid]
                       + scale_b[u];
        __syncthreads();
    }

    // softmax over M (computed redundantly per thread from LDS broadcast)
    float mx = -1e30f;
    #pragma unroll
    for (int m = 0; m < M; ++m) mx = fmaxf(mx, e_lds[m]);
    float s = 0.f;
    float aw[M];
    #pragma unroll
    for (int m = 0; m < M; ++m) { aw[m] = expf(e_lds[m] - mx); s += aw[m]; }
    float inv = 1.f / s;
    if (tid < M) out[O_ATT + (size_t)b * M + tid] = aw[tid] * inv;

    // context[h] = sum_m attn[m] * inter_output[b][m][h]
    float ctx = 0.f;
    #pragma unroll
    for (int m = 0; m < M; ++m) ctx += aw[m] * io[m * H + tid];
    ctx_ws[(size_t)b * H + tid] = ctx * inv;
}

// ---------------- Stage B: GRU cell ----------------
__global__ __launch_bounds__(256) void gru_kernel(
    const float* __restrict__ emb,     // (B,1,E)
    const float* __restrict__ hidden,  // (1,B,H)
    const float* __restrict__ ctx_ws,  // (B,H)
    const float* __restrict__ Wih,     // (3H,2E)
    const float* __restrict__ Whh,     // (3H,H)
    const float* __restrict__ bih,     // (3H,)
    const float* __restrict__ bhh,     // (3H,)
    float* __restrict__ out,
    float* __restrict__ hnew_ws)       // (B,H)
{
    const int b    = blockIdx.x;
    const int tid  = threadIdx.x;
    const int lane = tid & 63;
    const int wave = tid >> 6;

    __shared__ float x[2 * E];
    __shared__ float h[H];
    __shared__ float gi[3 * H];
    __shared__ float gh[3 * H];

    float ev = emb[(size_t)b * E + tid];
    x[tid]     = ev;
    x[E + tid] = ctx_ws[(size_t)b * H + tid];
    h[tid]     = hidden[(size_t)b * H + tid];
    out[O_EMB + (size_t)b * E + tid] = ev;   // embedded_input passthrough
    __syncthreads();

    // gi[r] = sum_k Wih[r][k] * x[k]   (wave-per-row, coalesced over k)
    for (int r = wave; r < 3 * H; r += 4) {
        const float* w = Wih + (size_t)r * 2 * E;
        float p = 0.f;
        #pragma unroll
        for (int i = 0; i < 8; ++i) p += w[i * 64 + lane] * x[i * 64 + lane];
        #pragma unroll
        for (int off = 32; off > 0; off >>= 1) p += __shfl_down(p, off, 64);
        if (lane == 0) gi[r] = p;
    }
    // gh[r] = sum_k Whh[r][k] * h[k]
    for (int r = wave; r < 3 * H; r += 4) {
        const float* w = Whh + (size_t)r * H;
        float p = 0.f;
        #pragma unroll
        for (int i = 0; i < 4; ++i) p += w[i * 64 + lane] * h[i * 64 + lane];
        #pragma unroll
        for (int off = 32; off > 0; off >>= 1) p += __shfl_down(p, off, 64);
        if (lane == 0) gh[r] = p;
    }
    __syncthreads();

    const int j = tid;
    float gir = gi[j]         + bih[j];
    float giz = gi[j + H]     + bih[j + H];
    float gin = gi[j + 2 * H] + bih[j + 2 * H];
    float ghr = gh[j]         + bhh[j];
    float ghz = gh[j + H]     + bhh[j + H];
    float ghn = gh[j + 2 * H] + bhh[j + 2 * H];
    float r_ = 1.f / (1.f + expf(-(gir + ghr)));
    float z_ = 1.f / (1.f + expf(-(giz + ghz)));
    float n_ = tanhf(gin + r_ * ghn);
    float hn = (1.f - z_) * n_ + z_ * h[j];

    out[O_HID + (size_t)b * H + j] = hn;   // hidden_new
    out[O_GRU + (size_t)b * H + j] = hn;   // gru_output
    hnew_ws[(size_t)b * H + j] = hn;
}

// ---------------- Stage C: output = h_new @ lin_W + lin_b ----------------
#define BT 32
__global__ __launch_bounds__(256) void out_kernel(
    const float* __restrict__ hnew_ws, // (B,H)
    const float* __restrict__ lin_W,   // (H,V)
    const float* __restrict__ lin_b,   // (V,)
    float* __restrict__ out)
{
    const int vt  = blockIdx.x;
    const int b0  = blockIdx.y * BT;
    const int tid = threadIdx.x;
    const int v   = vt * 256 + tid;

    __shared__ float hn[BT * H];
    for (int i = tid; i < BT * H; i += 256) hn[i] = hnew_ws[(size_t)b0 * H + i];
    __syncthreads();

    if (v >= V) return;

    float lb = lin_b[v];
    float acc[BT];
    #pragma unroll
    for (int i = 0; i < BT; ++i) acc[i] = lb;

    const float* W = lin_W + v;
    #pragma unroll 2
    for (int h = 0; h < H; ++h) {
        float w = W[(size_t)h * V];
        #pragma unroll
        for (int i = 0; i < BT; ++i) acc[i] += hn[i * H + h] * w;
    }
    #pragma unroll
    for (int i = 0; i < BT; ++i) out[(size_t)(b0 + i) * V + v] = acc[i];
}

extern "C" void kernel_launch(void* const* d_in, const int* in_sizes, int n_in,
                              void* d_out, int out_size, void* d_ws, size_t ws_size,
                              hipStream_t stream) {
    const float* emb    = (const float*)d_in[1];
    const float* hidden = (const float*)d_in[2];
    const float* io     = (const float*)d_in[3];
    const int*   ul     = (const int*)  d_in[4];
    const float* iW     = (const float*)d_in[5];
    const float* ib     = (const float*)d_in[6];
    const float* hW     = (const float*)d_in[7];
    const float* hb     = (const float*)d_in[8];
    const float* l1W    = (const float*)d_in[9];
    const float* l1b    = (const float*)d_in[10];
    const float* sW     = (const float*)d_in[11];
    const float* sb     = (const float*)d_in[12];
    const float* Wih    = (const float*)d_in[13];
    const float* Whh    = (const float*)d_in[14];
    const float* bih    = (const float*)d_in[15];
    const float* bhh    = (const float*)d_in[16];
    const float* lW     = (const float*)d_in[17];
    const float* lb     = (const float*)d_in[18];

    float* out  = (float*)d_out;
    float* ws   = (float*)d_ws;
    float* ctx  = ws;            // B*H floats
    float* hnew = ws + (size_t)B * H;

    attn_kernel<<<B, 256, 0, stream>>>(hidden, io, ul, iW, ib, hW, hb, l1W, l1b, sW, sb, out, ctx);
    gru_kernel<<<B, 256, 0, stream>>>(emb, hidden, ctx, Wih, Whh, bih, bhh, out, hnew);
    out_kernel<<<dim3((V + 255) / 256, B / BT), 256, 0, stream>>>(hnew, lW, lb, out);
}

// Round 2
// 527.178 us; speedup vs baseline: 1.8125x; 1.8125x over previous
//
#include <hip/hip_runtime.h>
#include <math.h>

#define B 1024
#define M 15
#define H 256
#define E 256
#define V 30000
#define U 1000

typedef float  vf4  __attribute__((ext_vector_type(4)));
typedef __bf16 bf16x8 __attribute__((ext_vector_type(8)));
typedef float  f32x4  __attribute__((ext_vector_type(4)));

// output layout (flat f32 concat, reference return order)
#define O_OUT   0
#define O_HID   ((size_t)B*V)
#define O_EMB   (O_HID + (size_t)B*H)
#define O_GRU   (O_EMB + (size_t)B*E)
#define O_ATT   (O_GRU + (size_t)B*H)

#define GLDS(g, l) __builtin_amdgcn_global_load_lds( \
    (const __attribute__((address_space(1))) void*)(g), \
    (__attribute__((address_space(3))) void*)(l), 16, 0, 0)

// ---------------- Stage A: per-user attention ----------------
__global__ __launch_bounds__(256) void attn_kernel(
    const float* __restrict__ hidden,       // (1,B,H)
    const float* __restrict__ inter_output, // (B,M,H)
    const int*   __restrict__ user_list,    // (B,)
    const float* __restrict__ inter_W,      // (U,H,H)
    const float* __restrict__ inter_b,      // (U,H)
    const float* __restrict__ hidden_W,     // (U,H,H)
    const float* __restrict__ hidden_b,     // (U,H)
    const float* __restrict__ lt1_W,        // (U,2H,H)
    const float* __restrict__ lt1_b,        // (U,H)
    const float* __restrict__ scale_W,      // (U,H)
    const float* __restrict__ scale_b,      // (U,)
    float* __restrict__ out,
    float* __restrict__ ctx_ws)             // (B,H)
{
    const int b   = blockIdx.x;
    const int tid = threadIdx.x;
    const int u   = user_list[b];

    __shared__ float ht[H];
    __shared__ float io[M * H];
    __shared__ float ht_a[H];
    __shared__ float io_a[M * H];
    __shared__ float red[4 * 16];
    __shared__ float e_lds[M];

    ht[tid] = hidden[b * H + tid];
    for (int i = tid; i < M * H; i += 256) io[i] = inter_output[(size_t)b * M * H + i];
    __syncthreads();

    // hidden_t_a[o] = sum_h ht[h] * hidden_W[u][h][o] + hidden_b[u][o]
    {
        float a = hidden_b[(size_t)u * H + tid];
        const float* W = hidden_W + (size_t)u * H * H + tid;
        #pragma unroll 2
        for (int h = 0; h < H; h += 4) {
            vf4 hv = *(const vf4*)&ht[h];
            a = fmaf(hv[0], W[(size_t)h * H], a);
            a = fmaf(hv[1], W[(size_t)(h+1) * H], a);
            a = fmaf(hv[2], W[(size_t)(h+2) * H], a);
            a = fmaf(hv[3], W[(size_t)(h+3) * H], a);
        }
        ht_a[tid] = a;
    }

    // inter_output_a[m][o] = sum_h io[m][h] * inter_W[u][h][o] + inter_b[u][o]
    float acc[M];
    {
        float ib = inter_b[(size_t)u * H + tid];
        #pragma unroll
        for (int m = 0; m < M; ++m) acc[m] = ib;
        const float* W = inter_W + (size_t)u * H * H + tid;
        #pragma unroll 2
        for (int h = 0; h < H; h += 4) {
            float w0 = W[(size_t)h * H];
            float w1 = W[(size_t)(h+1) * H];
            float w2 = W[(size_t)(h+2) * H];
            float w3 = W[(size_t)(h+3) * H];
            #pragma unroll
            for (int m = 0; m < M; ++m) {
                vf4 v = *(const vf4*)&io[m * H + h];
                acc[m] = fmaf(v[0], w0, acc[m]);
                acc[m] = fmaf(v[1], w1, acc[m]);
                acc[m] = fmaf(v[2], w2, acc[m]);
                acc[m] = fmaf(v[3], w3, acc[m]);
            }
        }
    }
    #pragma unroll
    for (int m = 0; m < M; ++m) io_a[m * H + tid] = acc[m];
    __syncthreads();

    // result[m][o] = tanh( sum_k ht_a[k]*lt1_W[u][k][o]
    //                    + sum_k io_a[m][k]*lt1_W[u][H+k][o] + lt1_b[u][o] )
    float res[M];
    {
        float base = lt1_b[(size_t)u * H + tid];
        const float* W1 = lt1_W + (size_t)u * 2 * H * H + tid;
        #pragma unroll 2
        for (int k = 0; k < H; k += 4) {
            vf4 hv = *(const vf4*)&ht_a[k];
            base = fmaf(hv[0], W1[(size_t)k * H], base);
            base = fmaf(hv[1], W1[(size_t)(k+1) * H], base);
            base = fmaf(hv[2], W1[(size_t)(k+2) * H], base);
            base = fmaf(hv[3], W1[(size_t)(k+3) * H], base);
        }
        #pragma unroll
        for (int m = 0; m < M; ++m) res[m] = 0.f;
        const float* W2 = W1 + (size_t)H * H;
        #pragma unroll 2
        for (int k = 0; k < H; k += 4) {
            float w0 = W2[(size_t)k * H];
            float w1 = W2[(size_t)(k+1) * H];
            float w2 = W2[(size_t)(k+2) * H];
            float w3 = W2[(size_t)(k+3) * H];
            #pragma unroll
            for (int m = 0; m < M; ++m) {
                vf4 v = *(const vf4*)&io_a[m * H + k];
                res[m] = fmaf(v[0], w0, res[m]);
                res[m] = fmaf(v[1], w1, res[m]);
                res[m] = fmaf(v[2], w2, res[m]);
                res[m] = fmaf(v[3], w3, res[m]);
            }
        }
        #pragma unroll
        for (int m = 0; m < M; ++m) res[m] = tanhf(base + res[m]);
    }

    // energies[m] = sum_o res[m][o] * scale_W[u][o] + scale_b[u]
    {
        float sw = scale_W[(size_t)u * H + tid];
        #pragma unroll
        for (int m = 0; m < M; ++m) {
            float v = res[m] * sw;
            #pragma unroll
            for (int off = 32; off > 0; off >>= 1) v += __shfl_down(v, off, 64);
            if ((tid & 63) == 0) red[(tid >> 6) * 16 + m] = v;
        }
        __syncthreads();
        if (tid < M)
            e_lds[tid] = red[0 * 16 + tid] + red[1 * 16 + tid] + red[2 * 16 + tid] + red[3 * 16 + tid]
                       + scale_b[u];
        __syncthreads();
    }

    // softmax over M (computed redundantly per thread from LDS broadcast)
    float mx = -1e30f;
    #pragma unroll
    for (int m = 0; m < M; ++m) mx = fmaxf(mx, e_lds[m]);
    float s = 0.f;
    float aw[M];
    #pragma unroll
    for (int m = 0; m < M; ++m) { aw[m] = expf(e_lds[m] - mx); s += aw[m]; }
    float inv = 1.f / s;
    if (tid < M) out[O_ATT + (size_t)b * M + tid] = aw[tid] * inv;

    // context[h] = sum_m attn[m] * inter_output[b][m][h]
    float ctx = 0.f;
    #pragma unroll
    for (int m = 0; m < M; ++m) ctx += aw[m] * io[m * H + tid];
    ctx_ws[(size_t)b * H + tid] = ctx * inv;
}

// ---------------- Stage B: GRU cell ----------------
__global__ __launch_bounds__(256) void gru_kernel(
    const float* __restrict__ emb,     // (B,1,E)
    const float* __restrict__ hidden,  // (1,B,H)
    const float* __restrict__ ctx_ws,  // (B,H)
    const float* __restrict__ Wih,     // (3H,2E)
    const float* __restrict__ Whh,     // (3H,H)
    const float* __restrict__ bih,     // (3H,)
    const float* __restrict__ bhh,     // (3H,)
    float* __restrict__ out,
    float* __restrict__ hnew_ws,       // (B,H) f32
    __bf16* __restrict__ hnb)          // (B,H) bf16 (nullable)
{
    const int b    = blockIdx.x;
    const int tid  = threadIdx.x;
    const int lane = tid & 63;
    const int wave = tid >> 6;

    __shared__ float x[2 * E];
    __shared__ float h[H];
    __shared__ float gi[3 * H];
    __shared__ float gh[3 * H];

    float ev = emb[(size_t)b * E + tid];
    x[tid]     = ev;
    x[E + tid] = ctx_ws[(size_t)b * H + tid];
    h[tid]     = hidden[(size_t)b * H + tid];
    out[O_EMB + (size_t)b * E + tid] = ev;   // embedded_input passthrough
    __syncthreads();

    for (int r = wave; r < 3 * H; r += 4) {
        const float* w = Wih + (size_t)r * 2 * E;
        float p = 0.f;
        #pragma unroll
        for (int i = 0; i < 8; ++i) p += w[i * 64 + lane] * x[i * 64 + lane];
        #pragma unroll
        for (int off = 32; off > 0; off >>= 1) p += __shfl_down(p, off, 64);
        if (lane == 0) gi[r] = p;
    }
    for (int r = wave; r < 3 * H; r += 4) {
        const float* w = Whh + (size_t)r * H;
        float p = 0.f;
        #pragma unroll
        for (int i = 0; i < 4; ++i) p += w[i * 64 + lane] * h[i * 64 + lane];
        #pragma unroll
        for (int off = 32; off > 0; off >>= 1) p += __shfl_down(p, off, 64);
        if (lane == 0) gh[r] = p;
    }
    __syncthreads();

    const int j = tid;
    float gir = gi[j]         + bih[j];
    float giz = gi[j + H]     + bih[j + H];
    float gin = gi[j + 2 * H] + bih[j + 2 * H];
    float ghr = gh[j]         + bhh[j];
    float ghz = gh[j + H]     + bhh[j + H];
    float ghn = gh[j + 2 * H] + bhh[j + 2 * H];
    float r_ = 1.f / (1.f + expf(-(gir + ghr)));
    float z_ = 1.f / (1.f + expf(-(giz + ghz)));
    float n_ = tanhf(gin + r_ * ghn);
    float hn = (1.f - z_) * n_ + z_ * h[j];

    out[O_HID + (size_t)b * H + j] = hn;
    out[O_GRU + (size_t)b * H + j] = hn;
    hnew_ws[(size_t)b * H + j] = hn;
    if (hnb) hnb[(size_t)b * H + j] = (__bf16)hn;
}

// -------- lin_W (H,V) f32 -> WT (V,H) bf16 transpose/convert --------
__global__ __launch_bounds__(256) void transpose_kernel(
    const float* __restrict__ lin_W, __bf16* __restrict__ WT)
{
    const int v0  = blockIdx.x * 240;
    const int k0  = blockIdx.y * 64;
    const int tid = threadIdx.x;
    const int lane = tid & 63, kq = tid >> 6;

    __shared__ __bf16 T[240 * 68];   // row stride 68 bf16 = 136 B

    if (lane < 60) {
        #pragma unroll
        for (int i = 0; i < 4; ++i) {
            int kr = kq * 16 + i * 4;
            vf4 f0 = *(const vf4*)&lin_W[(size_t)(k0 + kr + 0) * V + v0 + lane * 4];
            vf4 f1 = *(const vf4*)&lin_W[(size_t)(k0 + kr + 1) * V + v0 + lane * 4];
            vf4 f2 = *(const vf4*)&lin_W[(size_t)(k0 + kr + 2) * V + v0 + lane * 4];
            vf4 f3 = *(const vf4*)&lin_W[(size_t)(k0 + kr + 3) * V + v0 + lane * 4];
            #pragma unroll
            for (int j = 0; j < 4; ++j) {
                union { __bf16 h[4]; unsigned long long u; } pk;
                pk.h[0] = (__bf16)f0[j];
                pk.h[1] = (__bf16)f1[j];
                pk.h[2] = (__bf16)f2[j];
                pk.h[3] = (__bf16)f3[j];
                int v = lane * 4 + j;
                *(unsigned long long*)&T[v * 68 + kr] = pk.u;
            }
        }
    }
    __syncthreads();

    // write out coalesced: 240 rows x 16 chunks of 8B
    for (int r = 0; r < 15; ++r) {
        int L = r * 256 + tid;
        int v = L >> 4, c = L & 15;
        *(unsigned long long*)&WT[(size_t)(v0 + v) * H + k0 + c * 4] =
            *(const unsigned long long*)&T[v * 68 + c * 4];
    }
}

// -------- Stage C (MFMA): out = hnew(bf16) @ WT^T + lin_b --------
#define GBM 64
#define GBN 256
#define GBK 64
__global__ __launch_bounds__(256) void out_mfma_kernel(
    const __bf16* __restrict__ hnb,   // (B,H) bf16
    const __bf16* __restrict__ WT,    // (V,H) bf16
    const float* __restrict__ lin_b,  // (V,)
    float* __restrict__ out)
{
    const int n0   = blockIdx.x * GBN;
    const int m0   = blockIdx.y * GBM;
    const int tid  = threadIdx.x;
    const int wave = tid >> 6, lane = tid & 63;

    __shared__ __bf16 Al[GBM * H];    // 32 KB, chunk-swizzled
    __shared__ __bf16 Bl[GBN * GBK];  // 32 KB, chunk-swizzled

    // Stage A (full K=256) once: slots of 16B, source chunk pre-swizzled
    #pragma unroll
    for (int r = 0; r < 8; ++r) {
        int L = r * 256 + tid;        // 16B slot
        int m = L >> 5;               // 32 chunks per 512B row
        int c = L & 31;
        int sc = c ^ (m & 7);
        GLDS(hnb + (size_t)(m0 + m) * H + sc * 8, &Al[(size_t)L * 8]);
    }

    f32x4 acc[4][4];
    #pragma unroll
    for (int mf = 0; mf < 4; ++mf)
        #pragma unroll
        for (int nf = 0; nf < 4; ++nf) {
            f32x4 z = {0.f, 0.f, 0.f, 0.f};
            acc[mf][nf] = z;
        }

    const int wn0 = wave * 64;

    for (int ks = 0; ks < 4; ++ks) {
        // stage B: 256 rows(n) x 64(k) bf16, 16B slots, pre-swizzled source
        #pragma unroll
        for (int r = 0; r < 8; ++r) {
            int L = r * 256 + tid;
            int n = L >> 3;            // 8 chunks per 128B row
            int c = L & 7;
            int sc = c ^ (n & 7);
            int nn = n0 + n; if (nn >= V) nn = V - 1;
            GLDS(WT + (size_t)nn * H + ks * GBK + sc * 8, &Bl[(size_t)L * 8]);
        }
        __syncthreads();   // drains vmcnt(0): staged data visible

        #pragma unroll
        for (int kk = 0; kk < 2; ++kk) {
            bf16x8 af[4];
            #pragma unroll
            for (int mf = 0; mf < 4; ++mf) {
                int row = mf * 16 + (lane & 15);
                int c   = ks * 8 + kk * 4 + (lane >> 4);   // chunk in full-K row
                int cs  = c ^ (row & 7);
                af[mf] = *(const bf16x8*)&Al[row * H + cs * 8];
            }
            bf16x8 bfr[4];
            #pragma unroll
            for (int nf = 0; nf < 4; ++nf) {
                int col = wn0 + nf * 16 + (lane & 15);
                int c   = kk * 4 + (lane >> 4);            // chunk in 128B row
                int cs  = c ^ (col & 7);
                bfr[nf] = *(const bf16x8*)&Bl[col * GBK + cs * 8];
            }
            #pragma unroll
            for (int mf = 0; mf < 4; ++mf)
                #pragma unroll
                for (int nf = 0; nf < 4; ++nf)
                    acc[mf][nf] = __builtin_amdgcn_mfma_f32_16x16x32_bf16(
                        af[mf], bfr[nf], acc[mf][nf], 0, 0, 0);
        }
        __syncthreads();   // before restaging Bl
    }

    // epilogue: C/D layout col=lane&15, row=(lane>>4)*4+j
    #pragma unroll
    for (int nf = 0; nf < 4; ++nf) {
        int v = n0 + wn0 + nf * 16 + (lane & 15);
        if (v < V) {
            float lb = lin_b[v];
            #pragma unroll
            for (int mf = 0; mf < 4; ++mf) {
                int rbase = m0 + mf * 16 + (lane >> 4) * 4;
                f32x4 a = acc[mf][nf];
                #pragma unroll
                for (int j = 0; j < 4; ++j)
                    out[(size_t)(rbase + j) * V + v] = a[j] + lb;
            }
        }
    }
}

// ---------------- Stage C fallback (f32 vector) ----------------
#define BT 32
__global__ __launch_bounds__(256) void out_f32_kernel(
    const float* __restrict__ hnew_ws,
    const float* __restrict__ lin_W,
    const float* __restrict__ lin_b,
    float* __restrict__ out)
{
    const int vt  = blockIdx.x;
    const int b0  = blockIdx.y * BT;
    const int tid = threadIdx.x;
    const int v   = vt * 256 + tid;

    __shared__ float hn[BT * H];
    for (int i = tid; i < BT * H; i += 256) hn[i] = hnew_ws[(size_t)b0 * H + i];
    __syncthreads();

    if (v >= V) return;

    float lb = lin_b[v];
    float acc[BT];
    #pragma unroll
    for (int i = 0; i < BT; ++i) acc[i] = lb;

    const float* W = lin_W + v;
    #pragma unroll 2
    for (int h = 0; h < H; ++h) {
        float w = W[(size_t)h * V];
        #pragma unroll
        for (int i = 0; i < BT; ++i) acc[i] += hn[i * H + h] * w;
    }
    #pragma unroll
    for (int i = 0; i < BT; ++i) out[(size_t)(b0 + i) * V + v] = acc[i];
}

extern "C" void kernel_launch(void* const* d_in, const int* in_sizes, int n_in,
                              void* d_out, int out_size, void* d_ws, size_t ws_size,
                              hipStream_t stream) {
    const float* emb    = (const float*)d_in[1];
    const float* hidden = (const float*)d_in[2];
    const float* io     = (const float*)d_in[3];
    const int*   ul     = (const int*)  d_in[4];
    const float* iW     = (const float*)d_in[5];
    const float* ib     = (const float*)d_in[6];
    const float* hW     = (const float*)d_in[7];
    const float* hb     = (const float*)d_in[8];
    const float* l1W    = (const float*)d_in[9];
    const float* l1b    = (const float*)d_in[10];
    const float* sW     = (const float*)d_in[11];
    const float* sb     = (const float*)d_in[12];
    const float* Wih    = (const float*)d_in[13];
    const float* Whh    = (const float*)d_in[14];
    const float* bih    = (const float*)d_in[15];
    const float* bhh    = (const float*)d_in[16];
    const float* lW     = (const float*)d_in[17];
    const float* lb     = (const float*)d_in[18];

    float* out  = (float*)d_out;
    float*  ctx   = (float*)d_ws;                      // B*H f32
    float*  hnewf = ctx + (size_t)B * H;               // B*H f32
    __bf16* hnb   = (__bf16*)(hnewf + (size_t)B * H);  // B*H bf16
    __bf16* WT    = hnb + (size_t)B * H;               // V*H bf16

    const size_t need = (size_t)B * H * 4 * 2 + (size_t)B * H * 2 + (size_t)V * H * 2;
    const bool mfma_ok = ws_size >= need;

    attn_kernel<<<B, 256, 0, stream>>>(hidden, io, ul, iW, ib, hW, hb, l1W, l1b, sW, sb, out, ctx);
    gru_kernel<<<B, 256, 0, stream>>>(emb, hidden, ctx, Wih, Whh, bih, bhh, out, hnewf,
                                      mfma_ok ? hnb : (__bf16*)nullptr);
    if (mfma_ok) {
        transpose_kernel<<<dim3(125, 4), 256, 0, stream>>>(lW, WT);
        out_mfma_kernel<<<dim3((V + GBN - 1) / GBN, B / GBM), 256, 0, stream>>>(hnb, WT, lb, out);
    } else {
        out_f32_kernel<<<dim3((V + 255) / 256, B / BT), 256, 0, stream>>>(hnewf, lW, lb, out);
    }
}

// Round 3
// 495.776 us; speedup vs baseline: 1.9273x; 1.0633x over previous
//
#include <hip/hip_runtime.h>
#include <math.h>

#define B 1024
#define M 15
#define H 256
#define E 256
#define V 30000
#define U 1000

typedef float  vf4    __attribute__((ext_vector_type(4)));
typedef __bf16 bf16x8 __attribute__((ext_vector_type(8)));
typedef float  f32x4  __attribute__((ext_vector_type(4)));

// output layout (flat f32 concat, reference return order)
#define O_OUT   0
#define O_HID   ((size_t)B*V)
#define O_EMB   (O_HID + (size_t)B*H)
#define O_GRU   (O_EMB + (size_t)B*E)
#define O_ATT   (O_GRU + (size_t)B*H)

#define GLDS(g, l) __builtin_amdgcn_global_load_lds( \
    (const __attribute__((address_space(1))) void*)(g), \
    (__attribute__((address_space(3))) void*)(l), 16, 0, 0)

union BF8 { __bf16 h[8]; bf16x8 v; };
union BF4 { __bf16 h[4]; unsigned long long u; };

// ---------------- Stage A: per-user attention (MFMA) ----------------
// Per block: one sample b, user u.
// GEMM1: A1(16x512) = [io(15x256)|0 ; 0|ht(256)],  B1(512x256) = [Wi ; Wh]
//   -> rows 0..14 = io_a (io@Wi), row 15 = ht_a (ht@Wh)
// GEMM2: A2(16x512) = [ht_a bcast(256) | io_a+bi], B2(512x256) = lt1_W
//   -> res = tanh(D + lt1_b); energies/softmax/context follow.
__global__ __launch_bounds__(256, 3) void attn_kernel(
    const float* __restrict__ hidden,       // (1,B,H)
    const float* __restrict__ inter_output, // (B,M,H)
    const int*   __restrict__ user_list,    // (B,)
    const float* __restrict__ inter_W,      // (U,H,H)
    const float* __restrict__ inter_b,      // (U,H)
    const float* __restrict__ hidden_W,     // (U,H,H)
    const float* __restrict__ hidden_b,     // (U,H)
    const float* __restrict__ lt1_W,        // (U,2H,H)
    const float* __restrict__ lt1_b,        // (U,H)
    const float* __restrict__ scale_W,      // (U,H)
    const float* __restrict__ scale_b,      // (U,)
    float* __restrict__ out,
    float* __restrict__ ctx_ws)             // (B,H)
{
    const int b    = blockIdx.x;
    const int tid  = threadIdx.x;
    const int lane = tid & 63;
    const int wave = tid >> 6;
    const int wn0  = wave * 64;
    const int u    = user_list[b];

    // LDS: ~50.4 KB -> 3 blocks/CU
    __shared__ __align__(16) __bf16 Wt[256 * 64];    // B chunk [o][64k], swizzled
    __shared__ __align__(16) __bf16 Abuf[16 * 512];  // A operand, swizzled
    __shared__ float hta[H];
    __shared__ float red[64];
    __shared__ float e_lds[M];

    // ---- stage A phase 1: [io | 0 ; 0 | ht] as bf16, chunk-swizzled ----
    {
        const int m  = tid >> 4;
        const int l4 = (tid & 15) * 4;
        #pragma unroll
        for (int it = 0; it < 8; ++it) {
            int k = l4 + it * 64;
            BF4 p; p.u = 0ULL;
            if (m < 15 && k < 256) {
                vf4 f = *(const vf4*)&inter_output[(size_t)b * M * H + m * H + k];
                p.h[0] = (__bf16)f[0]; p.h[1] = (__bf16)f[1];
                p.h[2] = (__bf16)f[2]; p.h[3] = (__bf16)f[3];
            } else if (m == 15 && k >= 256) {
                vf4 f = *(const vf4*)&hidden[(size_t)b * H + (k - 256)];
                p.h[0] = (__bf16)f[0]; p.h[1] = (__bf16)f[1];
                p.h[2] = (__bf16)f[2]; p.h[3] = (__bf16)f[3];
            }
            int sc = (k >> 3) ^ (m & 7);
            *(unsigned long long*)&Abuf[m * 512 + sc * 8 + (k & 7)] = p.u;
        }
    }

    f32x4 acc1[4];
    #pragma unroll
    for (int nf = 0; nf < 4; ++nf) { f32x4 z = {0.f,0.f,0.f,0.f}; acc1[nf] = z; }

    const float* Wi_base  = inter_W  + (size_t)u * H * H;
    const float* Wh_base  = hidden_W + (size_t)u * H * H;
    const float* lt1_base = lt1_W    + (size_t)u * 2 * H * H;

    const int so0 = (tid & 127) * 2;     // staging: o-pair
    const int shh = (tid >> 7) * 32;     // staging: h-half
    const int skey = (so0 >> 1) & 7;     // swizzle key (same for o0,o0+1)

    // ================= GEMM 1 =================
    for (int ks = 0; ks < 8; ++ks) {
        const float* Bsrc = (ks < 4) ? (Wi_base + (size_t)ks * 64 * H)
                                     : (Wh_base + (size_t)(ks - 4) * 64 * H);
        #pragma unroll
        for (int i = 0; i < 4; ++i) {
            int cl = (shh >> 3) + i;
            float2 f[8];
            #pragma unroll
            for (int j = 0; j < 8; ++j)
                f[j] = *(const float2*)&Bsrc[(size_t)(shh + i * 8 + j) * H + so0];
            BF8 p0, p1;
            #pragma unroll
            for (int j = 0; j < 8; ++j) { p0.h[j] = (__bf16)f[j].x; p1.h[j] = (__bf16)f[j].y; }
            int sc = (cl ^ skey) * 8;
            *(bf16x8*)&Wt[so0 * 64 + sc]       = p0.v;
            *(bf16x8*)&Wt[(so0 + 1) * 64 + sc] = p1.v;
        }
        __syncthreads();
        #pragma unroll
        for (int kk = 0; kk < 2; ++kk) {
            int ca = ks * 8 + kk * 4 + (lane >> 4);
            bf16x8 a = *(const bf16x8*)&Abuf[(lane & 15) * 512 + ((ca ^ (lane & 7))) * 8];
            #pragma unroll
            for (int nf = 0; nf < 4; ++nf) {
                int col = wn0 + nf * 16 + (lane & 15);
                int cb  = kk * 4 + (lane >> 4);
                bf16x8 bb = *(const bf16x8*)&Wt[col * 64 + ((cb ^ ((col >> 1) & 7))) * 8];
                acc1[nf] = __builtin_amdgcn_mfma_f32_16x16x32_bf16(a, bb, acc1[nf], 0, 0, 0);
            }
        }
        __syncthreads();
    }

    // ---- extract ht_a (row 15) + hidden_b ----
    if ((lane >> 4) == 3) {
        #pragma unroll
        for (int nf = 0; nf < 4; ++nf) {
            int o = wn0 + nf * 16 + (lane & 15);
            hta[o] = acc1[nf][3] + hidden_b[(size_t)u * H + o];
        }
    }
    __syncthreads();

    // ---- stage A phase 2: [ht_a bcast | io_a + bi] ----
    {
        const int m  = tid >> 4;
        const int l4 = (tid & 15) * 4;
        #pragma unroll
        for (int it = 0; it < 4; ++it) {
            int k = l4 + it * 64;
            vf4 f = *(const vf4*)&hta[k];
            BF4 p;
            p.h[0] = (__bf16)f[0]; p.h[1] = (__bf16)f[1];
            p.h[2] = (__bf16)f[2]; p.h[3] = (__bf16)f[3];
            int sc = (k >> 3) ^ (m & 7);
            *(unsigned long long*)&Abuf[m * 512 + sc * 8 + (k & 7)] = p.u;
        }
    }
    #pragma unroll
    for (int nf = 0; nf < 4; ++nf) {
        int o  = wn0 + nf * 16 + (lane & 15);
        float bi = inter_b[(size_t)u * H + o];
        int k  = 256 + o;
        #pragma unroll
        for (int j = 0; j < 4; ++j) {
            int m  = (lane >> 4) * 4 + j;
            int sc = (k >> 3) ^ (m & 7);
            Abuf[m * 512 + sc * 8 + (k & 7)] = (__bf16)(acc1[nf][j] + bi);
        }
    }

    f32x4 acc2[4];
    #pragma unroll
    for (int nf = 0; nf < 4; ++nf) { f32x4 z = {0.f,0.f,0.f,0.f}; acc2[nf] = z; }

    // ================= GEMM 2 =================
    for (int ks = 0; ks < 8; ++ks) {
        const float* Bsrc = lt1_base + (size_t)ks * 64 * H;
        #pragma unroll
        for (int i = 0; i < 4; ++i) {
            int cl = (shh >> 3) + i;
            float2 f[8];
            #pragma unroll
            for (int j = 0; j < 8; ++j)
                f[j] = *(const float2*)&Bsrc[(size_t)(shh + i * 8 + j) * H + so0];
            BF8 p0, p1;
            #pragma unroll
            for (int j = 0; j < 8; ++j) { p0.h[j] = (__bf16)f[j].x; p1.h[j] = (__bf16)f[j].y; }
            int sc = (cl ^ skey) * 8;
            *(bf16x8*)&Wt[so0 * 64 + sc]       = p0.v;
            *(bf16x8*)&Wt[(so0 + 1) * 64 + sc] = p1.v;
        }
        __syncthreads();
        #pragma unroll
        for (int kk = 0; kk < 2; ++kk) {
            int ca = ks * 8 + kk * 4 + (lane >> 4);
            bf16x8 a = *(const bf16x8*)&Abuf[(lane & 15) * 512 + ((ca ^ (lane & 7))) * 8];
            #pragma unroll
            for (int nf = 0; nf < 4; ++nf) {
                int col = wn0 + nf * 16 + (lane & 15);
                int cb  = kk * 4 + (lane >> 4);
                bf16x8 bb = *(const bf16x8*)&Wt[col * 64 + ((cb ^ ((col >> 1) & 7))) * 8];
                acc2[nf] = __builtin_amdgcn_mfma_f32_16x16x32_bf16(a, bb, acc2[nf], 0, 0, 0);
            }
        }
        __syncthreads();
    }

    // ---- energies: e[m] = sum_o tanh(D2+l1b)[m][o]*sw[o] ----
    float p[4] = {0.f, 0.f, 0.f, 0.f};
    #pragma unroll
    for (int nf = 0; nf < 4; ++nf) {
        int o = wn0 + nf * 16 + (lane & 15);
        float l1b = lt1_b[(size_t)u * H + o];
        float sw  = scale_W[(size_t)u * H + o];
        #pragma unroll
        for (int j = 0; j < 4; ++j)
            p[j] += tanhf(acc2[nf][j] + l1b) * sw;
    }
    #pragma unroll
    for (int j = 0; j < 4; ++j) {
        float v = p[j];
        v += __shfl_xor(v, 1, 64);
        v += __shfl_xor(v, 2, 64);
        v += __shfl_xor(v, 4, 64);
        v += __shfl_xor(v, 8, 64);
        if ((lane & 15) == 0) red[wave * 16 + (lane >> 4) * 4 + j] = v;
    }
    __syncthreads();
    if (tid < M)
        e_lds[tid] = red[tid] + red[16 + tid] + red[32 + tid] + red[48 + tid]
                   + scale_b[u];
    __syncthreads();

    // softmax over M (redundant per thread)
    float mx = -1e30f;
    #pragma unroll
    for (int m = 0; m < M; ++m) mx = fmaxf(mx, e_lds[m]);
    float s = 0.f;
    float aw[M];
    #pragma unroll
    for (int m = 0; m < M; ++m) { aw[m] = expf(e_lds[m] - mx); s += aw[m]; }
    float inv = 1.f / s;
    if (tid < M) out[O_ATT + (size_t)b * M + tid] = aw[tid] * inv;

    // context[h] = sum_m attn[m] * inter_output[b][m][h]  (io is L2-hot)
    float ctx = 0.f;
    #pragma unroll
    for (int m = 0; m < M; ++m)
        ctx += aw[m] * inter_output[(size_t)b * M * H + m * H + tid];
    ctx_ws[(size_t)b * H + tid] = ctx * inv;
}

// ---------------- Stage B: GRU cell ----------------
__global__ __launch_bounds__(256) void gru_kernel(
    const float* __restrict__ emb,     // (B,1,E)
    const float* __restrict__ hidden,  // (1,B,H)
    const float* __restrict__ ctx_ws,  // (B,H)
    const float* __restrict__ Wih,     // (3H,2E)
    const float* __restrict__ Whh,     // (3H,H)
    const float* __restrict__ bih,     // (3H,)
    const float* __restrict__ bhh,     // (3H,)
    float* __restrict__ out,
    float* __restrict__ hnew_ws,       // (B,H) f32
    __bf16* __restrict__ hnb)          // (B,H) bf16 (nullable)
{
    const int b    = blockIdx.x;
    const int tid  = threadIdx.x;
    const int lane = tid & 63;
    const int wave = tid >> 6;

    __shared__ float x[2 * E];
    __shared__ float h[H];
    __shared__ float gi[3 * H];
    __shared__ float gh[3 * H];

    float ev = emb[(size_t)b * E + tid];
    x[tid]     = ev;
    x[E + tid] = ctx_ws[(size_t)b * H + tid];
    h[tid]     = hidden[(size_t)b * H + tid];
    out[O_EMB + (size_t)b * E + tid] = ev;
    __syncthreads();

    for (int r = wave; r < 3 * H; r += 4) {
        const float* w = Wih + (size_t)r * 2 * E;
        float p = 0.f;
        #pragma unroll
        for (int i = 0; i < 8; ++i) p += w[i * 64 + lane] * x[i * 64 + lane];
        #pragma unroll
        for (int off = 32; off > 0; off >>= 1) p += __shfl_down(p, off, 64);
        if (lane == 0) gi[r] = p;
    }
    for (int r = wave; r < 3 * H; r += 4) {
        const float* w = Whh + (size_t)r * H;
        float p = 0.f;
        #pragma unroll
        for (int i = 0; i < 4; ++i) p += w[i * 64 + lane] * h[i * 64 + lane];
        #pragma unroll
        for (int off = 32; off > 0; off >>= 1) p += __shfl_down(p, off, 64);
        if (lane == 0) gh[r] = p;
    }
    __syncthreads();

    const int j = tid;
    float gir = gi[j]         + bih[j];
    float giz = gi[j + H]     + bih[j + H];
    float gin = gi[j + 2 * H] + bih[j + 2 * H];
    float ghr = gh[j]         + bhh[j];
    float ghz = gh[j + H]     + bhh[j + H];
    float ghn = gh[j + 2 * H] + bhh[j + 2 * H];
    float r_ = 1.f / (1.f + expf(-(gir + ghr)));
    float z_ = 1.f / (1.f + expf(-(giz + ghz)));
    float n_ = tanhf(gin + r_ * ghn);
    float hn = (1.f - z_) * n_ + z_ * h[j];

    out[O_HID + (size_t)b * H + j] = hn;
    out[O_GRU + (size_t)b * H + j] = hn;
    hnew_ws[(size_t)b * H + j] = hn;
    if (hnb) hnb[(size_t)b * H + j] = (__bf16)hn;
}

// -------- lin_W (H,V) f32 -> WT (V,H) bf16 transpose/convert --------
__global__ __launch_bounds__(256) void transpose_kernel(
    const float* __restrict__ lin_W, __bf16* __restrict__ WT)
{
    const int v0  = blockIdx.x * 240;
    const int k0  = blockIdx.y * 64;
    const int tid = threadIdx.x;
    const int lane = tid & 63, kq = tid >> 6;

    __shared__ __bf16 T[240 * 68];

    if (lane < 60) {
        #pragma unroll
        for (int i = 0; i < 4; ++i) {
            int kr = kq * 16 + i * 4;
            vf4 f0 = *(const vf4*)&lin_W[(size_t)(k0 + kr + 0) * V + v0 + lane * 4];
            vf4 f1 = *(const vf4*)&lin_W[(size_t)(k0 + kr + 1) * V + v0 + lane * 4];
            vf4 f2 = *(const vf4*)&lin_W[(size_t)(k0 + kr + 2) * V + v0 + lane * 4];
            vf4 f3 = *(const vf4*)&lin_W[(size_t)(k0 + kr + 3) * V + v0 + lane * 4];
            #pragma unroll
            for (int j = 0; j < 4; ++j) {
                BF4 pk;
                pk.h[0] = (__bf16)f0[j];
                pk.h[1] = (__bf16)f1[j];
                pk.h[2] = (__bf16)f2[j];
                pk.h[3] = (__bf16)f3[j];
                int v = lane * 4 + j;
                *(unsigned long long*)&T[v * 68 + kr] = pk.u;
            }
        }
    }
    __syncthreads();

    for (int r = 0; r < 15; ++r) {
        int L = r * 256 + tid;
        int v = L >> 4, c = L & 15;
        *(unsigned long long*)&WT[(size_t)(v0 + v) * H + k0 + c * 4] =
            *(const unsigned long long*)&T[v * 68 + c * 4];
    }
}

// -------- Stage C (MFMA): out = hnew(bf16) @ WT^T + lin_b --------
#define GBM 64
#define GBN 256
#define GBK 64
__global__ __launch_bounds__(256) void out_mfma_kernel(
    const __bf16* __restrict__ hnb,
    const __bf16* __restrict__ WT,
    const float* __restrict__ lin_b,
    float* __restrict__ out)
{
    const int n0   = blockIdx.x * GBN;
    const int m0   = blockIdx.y * GBM;
    const int tid  = threadIdx.x;
    const int wave = tid >> 6, lane = tid & 63;

    __shared__ __bf16 Al[GBM * H];
    __shared__ __bf16 Bl[GBN * GBK];

    #pragma unroll
    for (int r = 0; r < 8; ++r) {
        int L = r * 256 + tid;
        int m = L >> 5;
        int c = L & 31;
        int sc = c ^ (m & 7);
        GLDS(hnb + (size_t)(m0 + m) * H + sc * 8, &Al[(size_t)L * 8]);
    }

    f32x4 acc[4][4];
    #pragma unroll
    for (int mf = 0; mf < 4; ++mf)
        #pragma unroll
        for (int nf = 0; nf < 4; ++nf) {
            f32x4 z = {0.f, 0.f, 0.f, 0.f};
            acc[mf][nf] = z;
        }

    const int wn0 = wave * 64;

    for (int ks = 0; ks < 4; ++ks) {
        #pragma unroll
        for (int r = 0; r < 8; ++r) {
            int L = r * 256 + tid;
            int n = L >> 3;
            int c = L & 7;
            int sc = c ^ (n & 7);
            int nn = n0 + n; if (nn >= V) nn = V - 1;
            GLDS(WT + (size_t)nn * H + ks * GBK + sc * 8, &Bl[(size_t)L * 8]);
        }
        __syncthreads();

        #pragma unroll
        for (int kk = 0; kk < 2; ++kk) {
            bf16x8 af[4];
            #pragma unroll
            for (int mf = 0; mf < 4; ++mf) {
                int row = mf * 16 + (lane & 15);
                int c   = ks * 8 + kk * 4 + (lane >> 4);
                int cs  = c ^ (row & 7);
                af[mf] = *(const bf16x8*)&Al[row * H + cs * 8];
            }
            bf16x8 bfr[4];
            #pragma unroll
            for (int nf = 0; nf < 4; ++nf) {
                int col = wn0 + nf * 16 + (lane & 15);
                int c   = kk * 4 + (lane >> 4);
                int cs  = c ^ (col & 7);
                bfr[nf] = *(const bf16x8*)&Bl[col * GBK + cs * 8];
            }
            #pragma unroll
            for (int mf = 0; mf < 4; ++mf)
                #pragma unroll
                for (int nf = 0; nf < 4; ++nf)
                    acc[mf][nf] = __builtin_amdgcn_mfma_f32_16x16x32_bf16(
                        af[mf], bfr[nf], acc[mf][nf], 0, 0, 0);
        }
        __syncthreads();
    }

    #pragma unroll
    for (int nf = 0; nf < 4; ++nf) {
        int v = n0 + wn0 + nf * 16 + (lane & 15);
        if (v < V) {
            float lb = lin_b[v];
            #pragma unroll
            for (int mf = 0; mf < 4; ++mf) {
                int rbase = m0 + mf * 16 + (lane >> 4) * 4;
                f32x4 a = acc[mf][nf];
                #pragma unroll
                for (int j = 0; j < 4; ++j)
                    out[(size_t)(rbase + j) * V + v] = a[j] + lb;
            }
        }
    }
}

// ---------------- Stage C fallback (f32 vector) ----------------
#define BT 32
__global__ __launch_bounds__(256) void out_f32_kernel(
    const float* __restrict__ hnew_ws,
    const float* __restrict__ lin_W,
    const float* __restrict__ lin_b,
    float* __restrict__ out)
{
    const int vt  = blockIdx.x;
    const int b0  = blockIdx.y * BT;
    const int tid = threadIdx.x;
    const int v   = vt * 256 + tid;

    __shared__ float hn[BT * H];
    for (int i = tid; i < BT * H; i += 256) hn[i] = hnew_ws[(size_t)b0 * H + i];
    __syncthreads();

    if (v >= V) return;

    float lb = lin_b[v];
    float acc[BT];
    #pragma unroll
    for (int i = 0; i < BT; ++i) acc[i] = lb;

    const float* W = lin_W + v;
    #pragma unroll 2
    for (int h = 0; h < H; ++h) {
        float w = W[(size_t)h * V];
        #pragma unroll
        for (int i = 0; i < BT; ++i) acc[i] += hn[i * H + h] * w;
    }
    #pragma unroll
    for (int i = 0; i < BT; ++i) out[(size_t)(b0 + i) * V + v] = acc[i];
}

extern "C" void kernel_launch(void* const* d_in, const int* in_sizes, int n_in,
                              void* d_out, int out_size, void* d_ws, size_t ws_size,
                              hipStream_t stream) {
    const float* emb    = (const float*)d_in[1];
    const float* hidden = (const float*)d_in[2];
    const float* io     = (const float*)d_in[3];
    const int*   ul     = (const int*)  d_in[4];
    const float* iW     = (const float*)d_in[5];
    const float* ib     = (const float*)d_in[6];
    const float* hW     = (const float*)d_in[7];
    const float* hb     = (const float*)d_in[8];
    const float* l1W    = (const float*)d_in[9];
    const float* l1b    = (const float*)d_in[10];
    const float* sW     = (const float*)d_in[11];
    const float* sb     = (const float*)d_in[12];
    const float* Wih    = (const float*)d_in[13];
    const float* Whh    = (const float*)d_in[14];
    const float* bih    = (const float*)d_in[15];
    const float* bhh    = (const float*)d_in[16];
    const float* lW     = (const float*)d_in[17];
    const float* lb     = (const float*)d_in[18];

    float* out  = (float*)d_out;
    float*  ctx   = (float*)d_ws;
    float*  hnewf = ctx + (size_t)B * H;
    __bf16* hnb   = (__bf16*)(hnewf + (size_t)B * H);
    __bf16* WT    = hnb + (size_t)B * H;

    const size_t need = (size_t)B * H * 4 * 2 + (size_t)B * H * 2 + (size_t)V * H * 2;
    const bool mfma_ok = ws_size >= need;

    attn_kernel<<<B, 256, 0, stream>>>(hidden, io, ul, iW, ib, hW, hb, l1W, l1b, sW, sb, out, ctx);
    gru_kernel<<<B, 256, 0, stream>>>(emb, hidden, ctx, Wih, Whh, bih, bhh, out, hnewf,
                                      mfma_ok ? hnb : (__bf16*)nullptr);
    if (mfma_ok) {
        transpose_kernel<<<dim3(125, 4), 256, 0, stream>>>(lW, WT);
        out_mfma_kernel<<<dim3((V + GBN - 1) / GBN, B / GBM), 256, 0, stream>>>(hnb, WT, lb, out);
    } else {
        out_f32_kernel<<<dim3((V + 255) / 256, B / BT), 256, 0, stream>>>(hnewf, lW, lb, out);
    }
}

// Round 4
// 481.008 us; speedup vs baseline: 1.9865x; 1.0307x over previous
//
#include <hip/hip_runtime.h>
#include <math.h>

#define B 1024
#define M 15
#define H 256
#define E 256
#define V 30000
#define U 1000

typedef float  vf4    __attribute__((ext_vector_type(4)));
typedef __bf16 bf16x8 __attribute__((ext_vector_type(8)));
typedef float  f32x4  __attribute__((ext_vector_type(4)));

// output layout (flat f32 concat, reference return order)
#define O_OUT   0
#define O_HID   ((size_t)B*V)
#define O_EMB   (O_HID + (size_t)B*H)
#define O_GRU   (O_EMB + (size_t)B*E)
#define O_ATT   (O_GRU + (size_t)B*H)

#define GLDS(g, l) __builtin_amdgcn_global_load_lds( \
    (const __attribute__((address_space(1))) void*)(g), \
    (__attribute__((address_space(3))) void*)(l), 16, 0, 0)

union BF8 { __bf16 h[8]; bf16x8 v; };
union BF4 { __bf16 h[4]; unsigned long long u; };

// ---------------- sort samples by user (counting sort, 1 block) ----------------
__global__ __launch_bounds__(1024) void sort_kernel(
    const int* __restrict__ ul, int* __restrict__ order)
{
    __shared__ int cnt[1024];
    __shared__ int base[1024];
    const int tid = threadIdx.x;
    cnt[tid] = 0;
    __syncthreads();
    const int u = ul[tid];
    atomicAdd(&cnt[u], 1);
    __syncthreads();
    int c0 = cnt[tid];
    int v  = c0;
    for (int off = 1; off < 1024; off <<= 1) {
        int add = (tid >= off) ? cnt[tid - off] : 0;
        __syncthreads();
        v += add;
        cnt[tid] = v;
        __syncthreads();
    }
    base[tid] = v - c0;          // exclusive prefix
    __syncthreads();
    int pos = atomicAdd(&base[u], 1);
    order[pos] = tid;
}

// ---------------- Stage A: per-user attention (MFMA) ----------------
// Blocks process samples in user-sorted order; XCD-chunked swizzle keeps
// same-user samples on one XCD so duplicate weight reads hit L2.
__global__ __launch_bounds__(256, 2) void attn_kernel(
    const float* __restrict__ hidden,       // (1,B,H)
    const float* __restrict__ inter_output, // (B,M,H)
    const int*   __restrict__ user_list,    // (B,)
    const int*   __restrict__ order,        // (B,) sorted-by-user sample ids
    const float* __restrict__ inter_W,      // (U,H,H)
    const float* __restrict__ inter_b,      // (U,H)
    const float* __restrict__ hidden_W,     // (U,H,H)
    const float* __restrict__ hidden_b,     // (U,H)
    const float* __restrict__ lt1_W,        // (U,2H,H)
    const float* __restrict__ lt1_b,        // (U,H)
    const float* __restrict__ scale_W,      // (U,H)
    const float* __restrict__ scale_b,      // (U,)
    float* __restrict__ out,
    float* __restrict__ ctx_ws)             // (B,H)
{
    const int s    = ((blockIdx.x & 7) << 7) + (blockIdx.x >> 3);  // XCD chunk swizzle
    const int b    = order[s];
    const int tid  = threadIdx.x;
    const int lane = tid & 63;
    const int wave = tid >> 6;
    const int wn0  = wave * 64;
    const int u    = user_list[b];

    __shared__ __align__(16) __bf16 Wt[256 * 64];    // B panel [o][64k], swizzled
    __shared__ __align__(16) __bf16 Abuf[16 * 512];  // A operand, swizzled
    __shared__ float hta[H];
    __shared__ float red[64];
    __shared__ float e_lds[M];

    // ---- A phase 1: [io | 0 ; 0 | ht] as bf16, chunk-swizzled ----
    {
        const int m  = tid >> 4;
        const int l4 = (tid & 15) * 4;
        #pragma unroll
        for (int it = 0; it < 8; ++it) {
            int k = l4 + it * 64;
            BF4 p; p.u = 0ULL;
            if (m < 15 && k < 256) {
                vf4 f = *(const vf4*)&inter_output[(size_t)b * M * H + m * H + k];
                p.h[0] = (__bf16)f[0]; p.h[1] = (__bf16)f[1];
                p.h[2] = (__bf16)f[2]; p.h[3] = (__bf16)f[3];
            } else if (m == 15 && k >= 256) {
                vf4 f = *(const vf4*)&hidden[(size_t)b * H + (k - 256)];
                p.h[0] = (__bf16)f[0]; p.h[1] = (__bf16)f[1];
                p.h[2] = (__bf16)f[2]; p.h[3] = (__bf16)f[3];
            }
            int sc = (k >> 3) ^ (m & 7);
            *(unsigned long long*)&Abuf[m * 512 + sc * 8 + (k & 7)] = p.u;
        }
    }

    f32x4 acc1[4];
    #pragma unroll
    for (int nf = 0; nf < 4; ++nf) { f32x4 z = {0.f,0.f,0.f,0.f}; acc1[nf] = z; }

    const float* Wi_base  = inter_W  + (size_t)u * H * H;
    const float* Wh_base  = hidden_W + (size_t)u * H * H;
    const float* lt1_base = lt1_W    + (size_t)u * 2 * H * H;

    const int so0  = (tid & 127) * 2;     // staging: o-pair
    const int shh  = (tid >> 7) * 32;     // staging: h-half
    const int skey = (so0 >> 1) & 7;      // swizzle key

    float2 f[32];
    // prologue: prefetch GEMM1 panel 0
    #pragma unroll
    for (int i = 0; i < 4; ++i)
        #pragma unroll
        for (int j = 0; j < 8; ++j)
            f[i*8+j] = *(const float2*)&Wi_base[(size_t)(shh + i * 8 + j) * H + so0];

    // ================= GEMM 1 =================
    for (int ks = 0; ks < 8; ++ks) {
        // cvt + LDS-write panel ks (from prefetched regs)
        #pragma unroll
        for (int i = 0; i < 4; ++i) {
            int cl = (shh >> 3) + i;
            BF8 p0, p1;
            #pragma unroll
            for (int j = 0; j < 8; ++j) { p0.h[j] = (__bf16)f[i*8+j].x; p1.h[j] = (__bf16)f[i*8+j].y; }
            int sc = (cl ^ skey) * 8;
            *(bf16x8*)&Wt[so0 * 64 + sc]       = p0.v;
            *(bf16x8*)&Wt[(so0 + 1) * 64 + sc] = p1.v;
        }
        __syncthreads();
        // issue prefetch of next panel (overlaps MFMA below)
        {
            const float* Bn = (ks < 3) ? (Wi_base + (size_t)(ks + 1) * 64 * H)
                            : (ks < 7) ? (Wh_base + (size_t)(ks - 3) * 64 * H)
                                       : lt1_base;   // GEMM2 panel 0
            #pragma unroll
            for (int i = 0; i < 4; ++i)
                #pragma unroll
                for (int j = 0; j < 8; ++j)
                    f[i*8+j] = *(const float2*)&Bn[(size_t)(shh + i * 8 + j) * H + so0];
        }
        #pragma unroll
        for (int kk = 0; kk < 2; ++kk) {
            int ca = ks * 8 + kk * 4 + (lane >> 4);
            bf16x8 a = *(const bf16x8*)&Abuf[(lane & 15) * 512 + ((ca ^ (lane & 7))) * 8];
            #pragma unroll
            for (int nf = 0; nf < 4; ++nf) {
                int col = wn0 + nf * 16 + (lane & 15);
                int cb  = kk * 4 + (lane >> 4);
                bf16x8 bb = *(const bf16x8*)&Wt[col * 64 + ((cb ^ ((col >> 1) & 7))) * 8];
                acc1[nf] = __builtin_amdgcn_mfma_f32_16x16x32_bf16(a, bb, acc1[nf], 0, 0, 0);
            }
        }
        __syncthreads();
    }

    // ---- extract ht_a (row 15) + hidden_b ----
    if ((lane >> 4) == 3) {
        #pragma unroll
        for (int nf = 0; nf < 4; ++nf) {
            int o = wn0 + nf * 16 + (lane & 15);
            hta[o] = acc1[nf][3] + hidden_b[(size_t)u * H + o];
        }
    }
    __syncthreads();

    // ---- A phase 2: [ht_a bcast | io_a + bi] ----
    {
        const int m  = tid >> 4;
        const int l4 = (tid & 15) * 4;
        #pragma unroll
        for (int it = 0; it < 4; ++it) {
            int k = l4 + it * 64;
            vf4 fv = *(const vf4*)&hta[k];
            BF4 p;
            p.h[0] = (__bf16)fv[0]; p.h[1] = (__bf16)fv[1];
            p.h[2] = (__bf16)fv[2]; p.h[3] = (__bf16)fv[3];
            int sc = (k >> 3) ^ (m & 7);
            *(unsigned long long*)&Abuf[m * 512 + sc * 8 + (k & 7)] = p.u;
        }
    }
    #pragma unroll
    for (int nf = 0; nf < 4; ++nf) {
        int o  = wn0 + nf * 16 + (lane & 15);
        float bi = inter_b[(size_t)u * H + o];
        int k  = 256 + o;
        #pragma unroll
        for (int j = 0; j < 4; ++j) {
            int m  = (lane >> 4) * 4 + j;
            int sc = (k >> 3) ^ (m & 7);
            Abuf[m * 512 + sc * 8 + (k & 7)] = (__bf16)(acc1[nf][j] + bi);
        }
    }

    f32x4 acc2[4];
    #pragma unroll
    for (int nf = 0; nf < 4; ++nf) { f32x4 z = {0.f,0.f,0.f,0.f}; acc2[nf] = z; }

    // ================= GEMM 2 =================
    for (int ks = 0; ks < 8; ++ks) {
        #pragma unroll
        for (int i = 0; i < 4; ++i) {
            int cl = (shh >> 3) + i;
            BF8 p0, p1;
            #pragma unroll
            for (int j = 0; j < 8; ++j) { p0.h[j] = (__bf16)f[i*8+j].x; p1.h[j] = (__bf16)f[i*8+j].y; }
            int sc = (cl ^ skey) * 8;
            *(bf16x8*)&Wt[so0 * 64 + sc]       = p0.v;
            *(bf16x8*)&Wt[(so0 + 1) * 64 + sc] = p1.v;
        }
        __syncthreads();
        if (ks < 7) {
            const float* Bn = lt1_base + (size_t)(ks + 1) * 64 * H;
            #pragma unroll
            for (int i = 0; i < 4; ++i)
                #pragma unroll
                for (int j = 0; j < 8; ++j)
                    f[i*8+j] = *(const float2*)&Bn[(size_t)(shh + i * 8 + j) * H + so0];
        }
        #pragma unroll
        for (int kk = 0; kk < 2; ++kk) {
            int ca = ks * 8 + kk * 4 + (lane >> 4);
            bf16x8 a = *(const bf16x8*)&Abuf[(lane & 15) * 512 + ((ca ^ (lane & 7))) * 8];
            #pragma unroll
            for (int nf = 0; nf < 4; ++nf) {
                int col = wn0 + nf * 16 + (lane & 15);
                int cb  = kk * 4 + (lane >> 4);
                bf16x8 bb = *(const bf16x8*)&Wt[col * 64 + ((cb ^ ((col >> 1) & 7))) * 8];
                acc2[nf] = __builtin_amdgcn_mfma_f32_16x16x32_bf16(a, bb, acc2[nf], 0, 0, 0);
            }
        }
        __syncthreads();
    }

    // ---- energies ----
    float p[4] = {0.f, 0.f, 0.f, 0.f};
    #pragma unroll
    for (int nf = 0; nf < 4; ++nf) {
        int o = wn0 + nf * 16 + (lane & 15);
        float l1b = lt1_b[(size_t)u * H + o];
        float sw  = scale_W[(size_t)u * H + o];
        #pragma unroll
        for (int j = 0; j < 4; ++j)
            p[j] += tanhf(acc2[nf][j] + l1b) * sw;
    }
    #pragma unroll
    for (int j = 0; j < 4; ++j) {
        float v = p[j];
        v += __shfl_xor(v, 1, 64);
        v += __shfl_xor(v, 2, 64);
        v += __shfl_xor(v, 4, 64);
        v += __shfl_xor(v, 8, 64);
        if ((lane & 15) == 0) red[wave * 16 + (lane >> 4) * 4 + j] = v;
    }
    __syncthreads();
    if (tid < M)
        e_lds[tid] = red[tid] + red[16 + tid] + red[32 + tid] + red[48 + tid]
                   + scale_b[u];
    __syncthreads();

    float mx = -1e30f;
    #pragma unroll
    for (int m = 0; m < M; ++m) mx = fmaxf(mx, e_lds[m]);
    float sum = 0.f;
    float aw[M];
    #pragma unroll
    for (int m = 0; m < M; ++m) { aw[m] = expf(e_lds[m] - mx); sum += aw[m]; }
    float inv = 1.f / sum;
    if (tid < M) out[O_ATT + (size_t)b * M + tid] = aw[tid] * inv;

    float ctx = 0.f;
    #pragma unroll
    for (int m = 0; m < M; ++m)
        ctx += aw[m] * inter_output[(size_t)b * M * H + m * H + tid];
    ctx_ws[(size_t)b * H + tid] = ctx * inv;
}

// ---------------- Stage B: GRU cell ----------------
__global__ __launch_bounds__(256) void gru_kernel(
    const float* __restrict__ emb,     // (B,1,E)
    const float* __restrict__ hidden,  // (1,B,H)
    const float* __restrict__ ctx_ws,  // (B,H)
    const float* __restrict__ Wih,     // (3H,2E)
    const float* __restrict__ Whh,     // (3H,H)
    const float* __restrict__ bih,     // (3H,)
    const float* __restrict__ bhh,     // (3H,)
    float* __restrict__ out,
    __bf16* __restrict__ hnb)          // (B,H) bf16
{
    const int b    = blockIdx.x;
    const int tid  = threadIdx.x;
    const int lane = tid & 63;
    const int wave = tid >> 6;

    __shared__ float x[2 * E];
    __shared__ float h[H];
    __shared__ float gi[3 * H];
    __shared__ float gh[3 * H];

    float ev = emb[(size_t)b * E + tid];
    x[tid]     = ev;
    x[E + tid] = ctx_ws[(size_t)b * H + tid];
    h[tid]     = hidden[(size_t)b * H + tid];
    out[O_EMB + (size_t)b * E + tid] = ev;
    __syncthreads();

    for (int r = wave; r < 3 * H; r += 4) {
        const float* w = Wih + (size_t)r * 2 * E;
        float p = 0.f;
        #pragma unroll
        for (int i = 0; i < 8; ++i) p += w[i * 64 + lane] * x[i * 64 + lane];
        #pragma unroll
        for (int off = 32; off > 0; off >>= 1) p += __shfl_down(p, off, 64);
        if (lane == 0) gi[r] = p;
    }
    for (int r = wave; r < 3 * H; r += 4) {
        const float* w = Whh + (size_t)r * H;
        float p = 0.f;
        #pragma unroll
        for (int i = 0; i < 4; ++i) p += w[i * 64 + lane] * h[i * 64 + lane];
        #pragma unroll
        for (int off = 32; off > 0; off >>= 1) p += __shfl_down(p, off, 64);
        if (lane == 0) gh[r] = p;
    }
    __syncthreads();

    const int j = tid;
    float gir = gi[j]         + bih[j];
    float giz = gi[j + H]     + bih[j + H];
    float gin = gi[j + 2 * H] + bih[j + 2 * H];
    float ghr = gh[j]         + bhh[j];
    float ghz = gh[j + H]     + bhh[j + H];
    float ghn = gh[j + 2 * H] + bhh[j + 2 * H];
    float r_ = 1.f / (1.f + expf(-(gir + ghr)));
    float z_ = 1.f / (1.f + expf(-(giz + ghz)));
    float n_ = tanhf(gin + r_ * ghn);
    float hn = (1.f - z_) * n_ + z_ * h[j];

    out[O_HID + (size_t)b * H + j] = hn;
    out[O_GRU + (size_t)b * H + j] = hn;
    hnb[(size_t)b * H + j] = (__bf16)hn;
}

// -------- lin_W (H,V) f32 -> WT (V,H) bf16 transpose/convert --------
__global__ __launch_bounds__(256) void transpose_kernel(
    const float* __restrict__ lin_W, __bf16* __restrict__ WT)
{
    const int v0  = blockIdx.x * 240;
    const int k0  = blockIdx.y * 64;
    const int tid = threadIdx.x;
    const int lane = tid & 63, kq = tid >> 6;

    __shared__ __bf16 T[240 * 68];

    if (lane < 60) {
        #pragma unroll
        for (int i = 0; i < 4; ++i) {
            int kr = kq * 16 + i * 4;
            vf4 f0 = *(const vf4*)&lin_W[(size_t)(k0 + kr + 0) * V + v0 + lane * 4];
            vf4 f1 = *(const vf4*)&lin_W[(size_t)(k0 + kr + 1) * V + v0 + lane * 4];
            vf4 f2 = *(const vf4*)&lin_W[(size_t)(k0 + kr + 2) * V + v0 + lane * 4];
            vf4 f3 = *(const vf4*)&lin_W[(size_t)(k0 + kr + 3) * V + v0 + lane * 4];
            #pragma unroll
            for (int j = 0; j < 4; ++j) {
                BF4 pk;
                pk.h[0] = (__bf16)f0[j];
                pk.h[1] = (__bf16)f1[j];
                pk.h[2] = (__bf16)f2[j];
                pk.h[3] = (__bf16)f3[j];
                int v = lane * 4 + j;
                *(unsigned long long*)&T[v * 68 + kr] = pk.u;
            }
        }
    }
    __syncthreads();

    for (int r = 0; r < 15; ++r) {
        int L = r * 256 + tid;
        int v = L >> 4, c = L & 15;
        *(unsigned long long*)&WT[(size_t)(v0 + v) * H + k0 + c * 4] =
            *(const unsigned long long*)&T[v * 68 + c * 4];
    }
}

// -------- Stage C (MFMA): out = hnew(bf16) @ WT^T + lin_b --------
// 1D grid + XCD-chunked swizzle: all 16 m-blocks of one n-tile share an XCD,
// so WT panels are fetched from HBM ~once and hit L2 thereafter.
#define GBM 64
#define GBN 256
#define GBK 64
#define NTM 16                       // B/GBM
#define NWG ((117 + 1) * NTM)        // 118 n-tiles * 16 m-tiles = 1888
__global__ __launch_bounds__(256) void out_mfma_kernel(
    const __bf16* __restrict__ hnb,
    const __bf16* __restrict__ WT,
    const float* __restrict__ lin_b,
    float* __restrict__ out)
{
    const int L  = blockIdx.x;
    const int s  = (L & 7) * (NWG / 8) + (L >> 3);
    const int nt = s >> 4, mt = s & 15;
    const int n0 = nt * GBN;
    const int m0 = mt * GBM;
    const int tid  = threadIdx.x;
    const int wave = tid >> 6, lane = tid & 63;

    __shared__ __bf16 Al[GBM * H];
    __shared__ __bf16 Bl[GBN * GBK];

    #pragma unroll
    for (int r = 0; r < 8; ++r) {
        int Li = r * 256 + tid;
        int m = Li >> 5;
        int c = Li & 31;
        int sc = c ^ (m & 7);
        GLDS(hnb + (size_t)(m0 + m) * H + sc * 8, &Al[(size_t)Li * 8]);
    }

    f32x4 acc[4][4];
    #pragma unroll
    for (int mf = 0; mf < 4; ++mf)
        #pragma unroll
        for (int nf = 0; nf < 4; ++nf) {
            f32x4 z = {0.f, 0.f, 0.f, 0.f};
            acc[mf][nf] = z;
        }

    const int wn0 = wave * 64;

    for (int ks = 0; ks < 4; ++ks) {
        #pragma unroll
        for (int r = 0; r < 8; ++r) {
            int Li = r * 256 + tid;
            int n = Li >> 3;
            int c = Li & 7;
            int sc = c ^ (n & 7);
            int nn = n0 + n; if (nn >= V) nn = V - 1;
            GLDS(WT + (size_t)nn * H + ks * GBK + sc * 8, &Bl[(size_t)Li * 8]);
        }
        __syncthreads();

        #pragma unroll
        for (int kk = 0; kk < 2; ++kk) {
            bf16x8 af[4];
            #pragma unroll
            for (int mf = 0; mf < 4; ++mf) {
                int row = mf * 16 + (lane & 15);
                int c   = ks * 8 + kk * 4 + (lane >> 4);
                int cs  = c ^ (row & 7);
                af[mf] = *(const bf16x8*)&Al[row * H + cs * 8];
            }
            bf16x8 bfr[4];
            #pragma unroll
            for (int nf = 0; nf < 4; ++nf) {
                int col = wn0 + nf * 16 + (lane & 15);
                int c   = kk * 4 + (lane >> 4);
                int cs  = c ^ (col & 7);
                bfr[nf] = *(const bf16x8*)&Bl[col * GBK + cs * 8];
            }
            #pragma unroll
            for (int mf = 0; mf < 4; ++mf)
                #pragma unroll
                for (int nf = 0; nf < 4; ++nf)
                    acc[mf][nf] = __builtin_amdgcn_mfma_f32_16x16x32_bf16(
                        af[mf], bfr[nf], acc[mf][nf], 0, 0, 0);
        }
        __syncthreads();
    }

    #pragma unroll
    for (int nf = 0; nf < 4; ++nf) {
        int v = n0 + wn0 + nf * 16 + (lane & 15);
        if (v < V) {
            float lb = lin_b[v];
            #pragma unroll
            for (int mf = 0; mf < 4; ++mf) {
                int rbase = m0 + mf * 16 + (lane >> 4) * 4;
                f32x4 a = acc[mf][nf];
                #pragma unroll
                for (int j = 0; j < 4; ++j)
                    out[(size_t)(rbase + j) * V + v] = a[j] + lb;
            }
        }
    }
}

extern "C" void kernel_launch(void* const* d_in, const int* in_sizes, int n_in,
                              void* d_out, int out_size, void* d_ws, size_t ws_size,
                              hipStream_t stream) {
    const float* emb    = (const float*)d_in[1];
    const float* hidden = (const float*)d_in[2];
    const float* io     = (const float*)d_in[3];
    const int*   ul     = (const int*)  d_in[4];
    const float* iW     = (const float*)d_in[5];
    const float* ib     = (const float*)d_in[6];
    const float* hW     = (const float*)d_in[7];
    const float* hb     = (const float*)d_in[8];
    const float* l1W    = (const float*)d_in[9];
    const float* l1b    = (const float*)d_in[10];
    const float* sW     = (const float*)d_in[11];
    const float* sb     = (const float*)d_in[12];
    const float* Wih    = (const float*)d_in[13];
    const float* Whh    = (const float*)d_in[14];
    const float* bih    = (const float*)d_in[15];
    const float* bhh    = (const float*)d_in[16];
    const float* lW     = (const float*)d_in[17];
    const float* lb     = (const float*)d_in[18];

    float* out  = (float*)d_out;
    int*    order = (int*)d_ws;                         // B ints
    float*  ctx   = (float*)(order + B);                // B*H f32
    __bf16* hnb   = (__bf16*)(ctx + (size_t)B * H);     // B*H bf16
    __bf16* WT    = hnb + (size_t)B * H;                // V*H bf16

    sort_kernel<<<1, 1024, 0, stream>>>(ul, order);
    attn_kernel<<<B, 256, 0, stream>>>(hidden, io, ul, order, iW, ib, hW, hb, l1W, l1b, sW, sb, out, ctx);
    gru_kernel<<<B, 256, 0, stream>>>(emb, hidden, ctx, Wih, Whh, bih, bhh, out, hnb);
    transpose_kernel<<<dim3(125, 4), 256, 0, stream>>>(lW, WT);
    out_mfma_kernel<<<NWG, 256, 0, stream>>>(hnb, WT, lb, out);
}

// Round 5
// 263.838 us; speedup vs baseline: 3.6216x; 1.8231x over previous
//
#include <hip/hip_runtime.h>
#include <math.h>

#define B 1024
#define M 15
#define H 256
#define E 256
#define V 30000
#define U 1000

typedef float  vf4    __attribute__((ext_vector_type(4)));
typedef __bf16 bf16x8 __attribute__((ext_vector_type(8)));
typedef float  f32x4  __attribute__((ext_vector_type(4)));

// output layout (flat f32 concat, reference return order)
#define O_OUT   0
#define O_HID   ((size_t)B*V)
#define O_EMB   (O_HID + (size_t)B*H)
#define O_GRU   (O_EMB + (size_t)B*E)
#define O_ATT   (O_GRU + (size_t)B*H)

#define GLDS(g, l) __builtin_amdgcn_global_load_lds( \
    (const __attribute__((address_space(1))) void*)(g), \
    (__attribute__((address_space(3))) void*)(l), 16, 0, 0)

union BF8 { __bf16 h[8]; bf16x8 v; };
union BF4 { __bf16 h[4]; unsigned long long u; };

// ---------------- sort samples by user (counting sort, 1 block) ----------------
__global__ __launch_bounds__(1024) void sort_kernel(
    const int* __restrict__ ul, int* __restrict__ order)
{
    __shared__ int cnt[1024];
    __shared__ int base[1024];
    const int tid = threadIdx.x;
    cnt[tid] = 0;
    __syncthreads();
    const int u = ul[tid];
    atomicAdd(&cnt[u], 1);
    __syncthreads();
    int c0 = cnt[tid];
    int v  = c0;
    for (int off = 1; off < 1024; off <<= 1) {
        int add = (tid >= off) ? cnt[tid - off] : 0;
        __syncthreads();
        v += add;
        cnt[tid] = v;
        __syncthreads();
    }
    base[tid] = v - c0;          // exclusive prefix
    __syncthreads();
    int pos = atomicAdd(&base[u], 1);
    order[pos] = tid;
}

// ---------------- Stage A: per-user attention (MFMA) ----------------
// GEMM1: A1(16x512)=[io|0 ; 0|ht] (IN REGISTERS), B1=[Wi;Wh] staged to LDS.
// GEMM2: A2(16x512)=[ht_a bcast | io_a+bi] via Abuf LDS, B2=lt1_W.
// ctx written as bf16 straight into xcat[b][256..511].
__global__ __launch_bounds__(256, 3) void attn_kernel(
    const float* __restrict__ hidden,       // (1,B,H)
    const float* __restrict__ inter_output, // (B,M,H)
    const int*   __restrict__ user_list,    // (B,)
    const int*   __restrict__ order,        // (B,)
    const float* __restrict__ inter_W,      // (U,H,H)
    const float* __restrict__ inter_b,      // (U,H)
    const float* __restrict__ hidden_W,     // (U,H,H)
    const float* __restrict__ hidden_b,     // (U,H)
    const float* __restrict__ lt1_W,        // (U,2H,H)
    const float* __restrict__ lt1_b,        // (U,H)
    const float* __restrict__ scale_W,      // (U,H)
    const float* __restrict__ scale_b,      // (U,)
    float* __restrict__ out,
    __bf16* __restrict__ xcat)              // (B,768) bf16
{
    const int s    = ((blockIdx.x & 7) << 7) + (blockIdx.x >> 3);  // XCD chunk swizzle
    const int b    = order[s];
    const int tid  = threadIdx.x;
    const int lane = tid & 63;
    const int wave = tid >> 6;
    const int wn0  = wave * 64;
    const int u    = user_list[b];

    __shared__ __align__(16) __bf16 Wt[256 * 64];    // B panel [o][64k], swizzled
    __shared__ __align__(16) __bf16 Abuf[16 * 512];  // GEMM2 A operand, swizzled
    __shared__ float hta[H];
    __shared__ float red[64];
    __shared__ float e_lds[M];

    // ---- GEMM1 A fragments in registers: row m=lane&15, k = t*32+(lane>>4)*8 ----
    bf16x8 afrag[16];
    {
        const int m  = lane & 15;
        const int ko = (lane >> 4) * 8;
        #pragma unroll
        for (int t = 0; t < 16; ++t) {
            int k = t * 32 + ko;
            BF8 p;
            #pragma unroll
            for (int j = 0; j < 8; ++j) p.h[j] = (__bf16)0.f;
            if (m < 15 && k < 256) {
                vf4 f0 = *(const vf4*)&inter_output[(size_t)b * M * H + m * H + k];
                vf4 f1 = *(const vf4*)&inter_output[(size_t)b * M * H + m * H + k + 4];
                p.h[0]=(__bf16)f0[0]; p.h[1]=(__bf16)f0[1]; p.h[2]=(__bf16)f0[2]; p.h[3]=(__bf16)f0[3];
                p.h[4]=(__bf16)f1[0]; p.h[5]=(__bf16)f1[1]; p.h[6]=(__bf16)f1[2]; p.h[7]=(__bf16)f1[3];
            } else if (m == 15 && k >= 256) {
                vf4 f0 = *(const vf4*)&hidden[(size_t)b * H + (k - 256)];
                vf4 f1 = *(const vf4*)&hidden[(size_t)b * H + (k - 256) + 4];
                p.h[0]=(__bf16)f0[0]; p.h[1]=(__bf16)f0[1]; p.h[2]=(__bf16)f0[2]; p.h[3]=(__bf16)f0[3];
                p.h[4]=(__bf16)f1[0]; p.h[5]=(__bf16)f1[1]; p.h[6]=(__bf16)f1[2]; p.h[7]=(__bf16)f1[3];
            }
            afrag[t] = p.v;
        }
    }

    f32x4 acc1[4];
    #pragma unroll
    for (int nf = 0; nf < 4; ++nf) { f32x4 z = {0.f,0.f,0.f,0.f}; acc1[nf] = z; }

    const float* Wi_base  = inter_W  + (size_t)u * H * H;
    const float* Wh_base  = hidden_W + (size_t)u * H * H;
    const float* lt1_base = lt1_W    + (size_t)u * 2 * H * H;

    const int so0  = (tid & 127) * 2;     // staging: o-pair
    const int shh  = (tid >> 7) * 32;     // staging: h-half
    const int skey = (so0 >> 1) & 7;      // swizzle key

    // ================= GEMM 1 =================
    for (int ks = 0; ks < 8; ++ks) {
        const float* Bsrc = (ks < 4) ? (Wi_base + (size_t)ks * 64 * H)
                                     : (Wh_base + (size_t)(ks - 4) * 64 * H);
        #pragma unroll
        for (int i = 0; i < 4; ++i) {
            int cl = (shh >> 3) + i;
            float2 f[8];
            #pragma unroll
            for (int j = 0; j < 8; ++j)
                f[j] = *(const float2*)&Bsrc[(size_t)(shh + i * 8 + j) * H + so0];
            BF8 p0, p1;
            #pragma unroll
            for (int j = 0; j < 8; ++j) { p0.h[j] = (__bf16)f[j].x; p1.h[j] = (__bf16)f[j].y; }
            int sc = (cl ^ skey) * 8;
            *(bf16x8*)&Wt[so0 * 64 + sc]       = p0.v;
            *(bf16x8*)&Wt[(so0 + 1) * 64 + sc] = p1.v;
        }
        __syncthreads();
        #pragma unroll
        for (int kk = 0; kk < 2; ++kk) {
            bf16x8 a = afrag[ks * 2 + kk];
            #pragma unroll
            for (int nf = 0; nf < 4; ++nf) {
                int col = wn0 + nf * 16 + (lane & 15);
                int cb  = kk * 4 + (lane >> 4);
                bf16x8 bb = *(const bf16x8*)&Wt[col * 64 + ((cb ^ ((col >> 1) & 7))) * 8];
                acc1[nf] = __builtin_amdgcn_mfma_f32_16x16x32_bf16(a, bb, acc1[nf], 0, 0, 0);
            }
        }
        __syncthreads();
    }

    // ---- extract ht_a (row 15) + hidden_b ----
    if ((lane >> 4) == 3) {
        #pragma unroll
        for (int nf = 0; nf < 4; ++nf) {
            int o = wn0 + nf * 16 + (lane & 15);
            hta[o] = acc1[nf][3] + hidden_b[(size_t)u * H + o];
        }
    }
    __syncthreads();

    // ---- build GEMM2 A: [ht_a bcast | io_a + bi] (full rewrite of Abuf) ----
    {
        const int m  = tid >> 4;
        const int l4 = (tid & 15) * 4;
        #pragma unroll
        for (int it = 0; it < 4; ++it) {
            int k = l4 + it * 64;
            vf4 fv = *(const vf4*)&hta[k];
            BF4 p;
            p.h[0] = (__bf16)fv[0]; p.h[1] = (__bf16)fv[1];
            p.h[2] = (__bf16)fv[2]; p.h[3] = (__bf16)fv[3];
            int sc = (k >> 3) ^ (m & 7);
            *(unsigned long long*)&Abuf[m * 512 + sc * 8 + (k & 7)] = p.u;
        }
    }
    #pragma unroll
    for (int nf = 0; nf < 4; ++nf) {
        int o  = wn0 + nf * 16 + (lane & 15);
        float bi = inter_b[(size_t)u * H + o];
        int k  = 256 + o;
        #pragma unroll
        for (int j = 0; j < 4; ++j) {
            int m  = (lane >> 4) * 4 + j;
            int sc = (k >> 3) ^ (m & 7);
            Abuf[m * 512 + sc * 8 + (k & 7)] = (__bf16)(acc1[nf][j] + bi);
        }
    }

    f32x4 acc2[4];
    #pragma unroll
    for (int nf = 0; nf < 4; ++nf) { f32x4 z = {0.f,0.f,0.f,0.f}; acc2[nf] = z; }

    // ================= GEMM 2 =================
    for (int ks = 0; ks < 8; ++ks) {
        const float* Bsrc = lt1_base + (size_t)ks * 64 * H;
        #pragma unroll
        for (int i = 0; i < 4; ++i) {
            int cl = (shh >> 3) + i;
            float2 f[8];
            #pragma unroll
            for (int j = 0; j < 8; ++j)
                f[j] = *(const float2*)&Bsrc[(size_t)(shh + i * 8 + j) * H + so0];
            BF8 p0, p1;
            #pragma unroll
            for (int j = 0; j < 8; ++j) { p0.h[j] = (__bf16)f[j].x; p1.h[j] = (__bf16)f[j].y; }
            int sc = (cl ^ skey) * 8;
            *(bf16x8*)&Wt[so0 * 64 + sc]       = p0.v;
            *(bf16x8*)&Wt[(so0 + 1) * 64 + sc] = p1.v;
        }
        __syncthreads();
        #pragma unroll
        for (int kk = 0; kk < 2; ++kk) {
            int ca = ks * 8 + kk * 4 + (lane >> 4);
            bf16x8 a = *(const bf16x8*)&Abuf[(lane & 15) * 512 + ((ca ^ (lane & 7))) * 8];
            #pragma unroll
            for (int nf = 0; nf < 4; ++nf) {
                int col = wn0 + nf * 16 + (lane & 15);
                int cb  = kk * 4 + (lane >> 4);
                bf16x8 bb = *(const bf16x8*)&Wt[col * 64 + ((cb ^ ((col >> 1) & 7))) * 8];
                acc2[nf] = __builtin_amdgcn_mfma_f32_16x16x32_bf16(a, bb, acc2[nf], 0, 0, 0);
            }
        }
        __syncthreads();
    }

    // ---- energies ----
    float p[4] = {0.f, 0.f, 0.f, 0.f};
    #pragma unroll
    for (int nf = 0; nf < 4; ++nf) {
        int o = wn0 + nf * 16 + (lane & 15);
        float l1b = lt1_b[(size_t)u * H + o];
        float sw  = scale_W[(size_t)u * H + o];
        #pragma unroll
        for (int j = 0; j < 4; ++j)
            p[j] += tanhf(acc2[nf][j] + l1b) * sw;
    }
    #pragma unroll
    for (int j = 0; j < 4; ++j) {
        float v = p[j];
        v += __shfl_xor(v, 1, 64);
        v += __shfl_xor(v, 2, 64);
        v += __shfl_xor(v, 4, 64);
        v += __shfl_xor(v, 8, 64);
        if ((lane & 15) == 0) red[wave * 16 + (lane >> 4) * 4 + j] = v;
    }
    __syncthreads();
    if (tid < M)
        e_lds[tid] = red[tid] + red[16 + tid] + red[32 + tid] + red[48 + tid]
                   + scale_b[u];
    __syncthreads();

    float mx = -1e30f;
    #pragma unroll
    for (int m = 0; m < M; ++m) mx = fmaxf(mx, e_lds[m]);
    float sum = 0.f;
    float aw[M];
    #pragma unroll
    for (int m = 0; m < M; ++m) { aw[m] = expf(e_lds[m] - mx); sum += aw[m]; }
    float inv = 1.f / sum;
    if (tid < M) out[O_ATT + (size_t)b * M + tid] = aw[tid] * inv;

    float ctx = 0.f;
    #pragma unroll
    for (int m = 0; m < M; ++m)
        ctx += aw[m] * inter_output[(size_t)b * M * H + m * H + tid];
    xcat[(size_t)b * 768 + 256 + tid] = (__bf16)(ctx * inv);
}

// ---------------- xcat fill: emb + h (bf16) + O_EMB passthrough ----------------
__global__ __launch_bounds__(256) void cvt_xh_kernel(
    const float* __restrict__ emb, const float* __restrict__ hidden,
    __bf16* __restrict__ xcat, float* __restrict__ out)
{
    const int b = blockIdx.x, tid = threadIdx.x;
    float ev = emb[(size_t)b * E + tid];
    float hv = hidden[(size_t)b * H + tid];
    xcat[(size_t)b * 768 + tid]       = (__bf16)ev;
    xcat[(size_t)b * 768 + 512 + tid] = (__bf16)hv;
    out[O_EMB + (size_t)b * E + tid]  = ev;
}

// ---------------- Wcat build: (1024 out-cols, 768 k) bf16 ----------------
// n<512:    [Wih[n] | Whh[n]]            (r,z fused sums)
// 512..767: [Wih[n] | 0]                 (gi_n)
// 768..1023:[0      | Whh[n-256]]        (gh_n)
__global__ __launch_bounds__(192) void wcat_kernel(
    const float* __restrict__ Wih, const float* __restrict__ Whh,
    __bf16* __restrict__ wcat)
{
    const int n = blockIdx.x;
    const int k = threadIdx.x * 4;
    vf4 v = {0.f, 0.f, 0.f, 0.f};
    if (n < 512) {
        v = (k < 512) ? *(const vf4*)&Wih[(size_t)n * 512 + k]
                      : *(const vf4*)&Whh[(size_t)n * 256 + (k - 512)];
    } else if (n < 768) {
        if (k < 512) v = *(const vf4*)&Wih[(size_t)n * 512 + k];
    } else {
        if (k >= 512) v = *(const vf4*)&Whh[(size_t)(n - 256) * 256 + (k - 512)];
    }
    BF4 p;
    p.h[0]=(__bf16)v[0]; p.h[1]=(__bf16)v[1]; p.h[2]=(__bf16)v[2]; p.h[3]=(__bf16)v[3];
    *(unsigned long long*)&wcat[(size_t)n * 768 + k] = p.u;
}

// ---------------- gates = xcat(B,768) @ wcat^T -> (B,1024) f32 ----------------
__global__ __launch_bounds__(256) void xgemm_kernel(
    const __bf16* __restrict__ xcat, const __bf16* __restrict__ wcat,
    float* __restrict__ gates)
{
    const int n0   = blockIdx.x * 256;
    const int m0   = blockIdx.y * 64;
    const int tid  = threadIdx.x;
    const int wave = tid >> 6, lane = tid & 63;
    const int wn0  = wave * 64;

    __shared__ __align__(16) __bf16 Al[64 * 64];
    __shared__ __align__(16) __bf16 Bl[256 * 64];

    f32x4 acc[4][4];
    #pragma unroll
    for (int mf = 0; mf < 4; ++mf)
        #pragma unroll
        for (int nf = 0; nf < 4; ++nf) { f32x4 z = {0.f,0.f,0.f,0.f}; acc[mf][nf] = z; }

    for (int ks = 0; ks < 12; ++ks) {
        #pragma unroll
        for (int r = 0; r < 2; ++r) {
            int L = r * 256 + tid;
            int m = L >> 3, c = L & 7;
            int sc = c ^ (m & 7);
            GLDS(xcat + (size_t)(m0 + m) * 768 + ks * 64 + sc * 8, &Al[(size_t)L * 8]);
        }
        #pragma unroll
        for (int r = 0; r < 8; ++r) {
            int L = r * 256 + tid;
            int n = L >> 3, c = L & 7;
            int sc = c ^ (n & 7);
            GLDS(wcat + (size_t)(n0 + n) * 768 + ks * 64 + sc * 8, &Bl[(size_t)L * 8]);
        }
        __syncthreads();
        #pragma unroll
        for (int kk = 0; kk < 2; ++kk) {
            bf16x8 af[4];
            #pragma unroll
            for (int mf = 0; mf < 4; ++mf) {
                int row = mf * 16 + (lane & 15);
                int c   = kk * 4 + (lane >> 4);
                af[mf] = *(const bf16x8*)&Al[row * 64 + (c ^ (row & 7)) * 8];
            }
            bf16x8 bfr[4];
            #pragma unroll
            for (int nf = 0; nf < 4; ++nf) {
                int col = wn0 + nf * 16 + (lane & 15);
                int c   = kk * 4 + (lane >> 4);
                bfr[nf] = *(const bf16x8*)&Bl[col * 64 + (c ^ (col & 7)) * 8];
            }
            #pragma unroll
            for (int mf = 0; mf < 4; ++mf)
                #pragma unroll
                for (int nf = 0; nf < 4; ++nf)
                    acc[mf][nf] = __builtin_amdgcn_mfma_f32_16x16x32_bf16(
                        af[mf], bfr[nf], acc[mf][nf], 0, 0, 0);
        }
        __syncthreads();
    }

    #pragma unroll
    for (int nf = 0; nf < 4; ++nf) {
        int n = n0 + wn0 + nf * 16 + (lane & 15);
        #pragma unroll
        for (int mf = 0; mf < 4; ++mf) {
            int rbase = m0 + mf * 16 + (lane >> 4) * 4;
            f32x4 a = acc[mf][nf];
            #pragma unroll
            for (int j = 0; j < 4; ++j)
                gates[(size_t)(rbase + j) * 1024 + n] = a[j];
        }
    }
}

// ---------------- GRU gates elementwise ----------------
__global__ __launch_bounds__(256) void gate_kernel(
    const float* __restrict__ gates,   // (B,1024)
    const float* __restrict__ hidden,  // (1,B,H)
    const float* __restrict__ bih, const float* __restrict__ bhh,
    float* __restrict__ out, __bf16* __restrict__ hnb)
{
    const int b = blockIdx.x, j = threadIdx.x;
    const float* g = gates + (size_t)b * 1024;
    float rs  = g[j]       + bih[j]       + bhh[j];
    float zs  = g[256 + j] + bih[256 + j] + bhh[256 + j];
    float gin = g[512 + j] + bih[512 + j];
    float ghn = g[768 + j] + bhh[512 + j];
    float h   = hidden[(size_t)b * H + j];
    float r_  = 1.f / (1.f + expf(-rs));
    float z_  = 1.f / (1.f + expf(-zs));
    float n_  = tanhf(gin + r_ * ghn);
    float hn  = (1.f - z_) * n_ + z_ * h;
    out[O_HID + (size_t)b * H + j] = hn;
    out[O_GRU + (size_t)b * H + j] = hn;
    hnb[(size_t)b * H + j] = (__bf16)hn;
}

// -------- lin_W (H,V) f32 -> WT (V,H) bf16 transpose/convert --------
__global__ __launch_bounds__(256) void transpose_kernel(
    const float* __restrict__ lin_W, __bf16* __restrict__ WT)
{
    const int v0  = blockIdx.x * 240;
    const int k0  = blockIdx.y * 64;
    const int tid = threadIdx.x;
    const int lane = tid & 63, kq = tid >> 6;

    __shared__ __bf16 T[240 * 68];

    if (lane < 60) {
        #pragma unroll
        for (int i = 0; i < 4; ++i) {
            int kr = kq * 16 + i * 4;
            vf4 f0 = *(const vf4*)&lin_W[(size_t)(k0 + kr + 0) * V + v0 + lane * 4];
            vf4 f1 = *(const vf4*)&lin_W[(size_t)(k0 + kr + 1) * V + v0 + lane * 4];
            vf4 f2 = *(const vf4*)&lin_W[(size_t)(k0 + kr + 2) * V + v0 + lane * 4];
            vf4 f3 = *(const vf4*)&lin_W[(size_t)(k0 + kr + 3) * V + v0 + lane * 4];
            #pragma unroll
            for (int j = 0; j < 4; ++j) {
                BF4 pk;
                pk.h[0] = (__bf16)f0[j];
                pk.h[1] = (__bf16)f1[j];
                pk.h[2] = (__bf16)f2[j];
                pk.h[3] = (__bf16)f3[j];
                int v = lane * 4 + j;
                *(unsigned long long*)&T[v * 68 + kr] = pk.u;
            }
        }
    }
    __syncthreads();

    for (int r = 0; r < 15; ++r) {
        int L = r * 256 + tid;
        int v = L >> 4, c = L & 15;
        *(unsigned long long*)&WT[(size_t)(v0 + v) * H + k0 + c * 4] =
            *(const unsigned long long*)&T[v * 68 + c * 4];
    }
}

// -------- Stage C (MFMA): out = hnew(bf16) @ WT^T + lin_b --------
#define GBM 64
#define GBN 256
#define GBK 64
#define NTM 16
#define NWG ((117 + 1) * NTM)
__global__ __launch_bounds__(256) void out_mfma_kernel(
    const __bf16* __restrict__ hnb,
    const __bf16* __restrict__ WT,
    const float* __restrict__ lin_b,
    float* __restrict__ out)
{
    const int L  = blockIdx.x;
    const int s  = (L & 7) * (NWG / 8) + (L >> 3);
    const int nt = s >> 4, mt = s & 15;
    const int n0 = nt * GBN;
    const int m0 = mt * GBM;
    const int tid  = threadIdx.x;
    const int wave = tid >> 6, lane = tid & 63;

    __shared__ __bf16 Al[GBM * H];
    __shared__ __bf16 Bl[GBN * GBK];

    #pragma unroll
    for (int r = 0; r < 8; ++r) {
        int Li = r * 256 + tid;
        int m = Li >> 5;
        int c = Li & 31;
        int sc = c ^ (m & 7);
        GLDS(hnb + (size_t)(m0 + m) * H + sc * 8, &Al[(size_t)Li * 8]);
    }

    f32x4 acc[4][4];
    #pragma unroll
    for (int mf = 0; mf < 4; ++mf)
        #pragma unroll
        for (int nf = 0; nf < 4; ++nf) {
            f32x4 z = {0.f, 0.f, 0.f, 0.f};
            acc[mf][nf] = z;
        }

    const int wn0 = wave * 64;

    for (int ks = 0; ks < 4; ++ks) {
        #pragma unroll
        for (int r = 0; r < 8; ++r) {
            int Li = r * 256 + tid;
            int n = Li >> 3;
            int c = Li & 7;
            int sc = c ^ (n & 7);
            int nn = n0 + n; if (nn >= V) nn = V - 1;
            GLDS(WT + (size_t)nn * H + ks * GBK + sc * 8, &Bl[(size_t)Li * 8]);
        }
        __syncthreads();

        #pragma unroll
        for (int kk = 0; kk < 2; ++kk) {
            bf16x8 af[4];
            #pragma unroll
            for (int mf = 0; mf < 4; ++mf) {
                int row = mf * 16 + (lane & 15);
                int c   = ks * 8 + kk * 4 + (lane >> 4);
                int cs  = c ^ (row & 7);
                af[mf] = *(const bf16x8*)&Al[row * H + cs * 8];
            }
            bf16x8 bfr[4];
            #pragma unroll
            for (int nf = 0; nf < 4; ++nf) {
                int col = wn0 + nf * 16 + (lane & 15);
                int c   = kk * 4 + (lane >> 4);
                int cs  = c ^ (col & 7);
                bfr[nf] = *(const bf16x8*)&Bl[col * GBK + cs * 8];
            }
            #pragma unroll
            for (int mf = 0; mf < 4; ++mf)
                #pragma unroll
                for (int nf = 0; nf < 4; ++nf)
                    acc[mf][nf] = __builtin_amdgcn_mfma_f32_16x16x32_bf16(
                        af[mf], bfr[nf], acc[mf][nf], 0, 0, 0);
        }
        __syncthreads();
    }

    #pragma unroll
    for (int nf = 0; nf < 4; ++nf) {
        int v = n0 + wn0 + nf * 16 + (lane & 15);
        if (v < V) {
            float lb = lin_b[v];
            #pragma unroll
            for (int mf = 0; mf < 4; ++mf) {
                int rbase = m0 + mf * 16 + (lane >> 4) * 4;
                f32x4 a = acc[mf][nf];
                #pragma unroll
                for (int j = 0; j < 4; ++j)
                    out[(size_t)(rbase + j) * V + v] = a[j] + lb;
            }
        }
    }
}

extern "C" void kernel_launch(void* const* d_in, const int* in_sizes, int n_in,
                              void* d_out, int out_size, void* d_ws, size_t ws_size,
                              hipStream_t stream) {
    const float* emb    = (const float*)d_in[1];
    const float* hidden = (const float*)d_in[2];
    const float* io     = (const float*)d_in[3];
    const int*   ul     = (const int*)  d_in[4];
    const float* iW     = (const float*)d_in[5];
    const float* ib     = (const float*)d_in[6];
    const float* hW     = (const float*)d_in[7];
    const float* hb     = (const float*)d_in[8];
    const float* l1W    = (const float*)d_in[9];
    const float* l1b    = (const float*)d_in[10];
    const float* sW     = (const float*)d_in[11];
    const float* sb     = (const float*)d_in[12];
    const float* Wih    = (const float*)d_in[13];
    const float* Whh    = (const float*)d_in[14];
    const float* bih    = (const float*)d_in[15];
    const float* bhh    = (const float*)d_in[16];
    const float* lW     = (const float*)d_in[17];
    const float* lb     = (const float*)d_in[18];

    float* out = (float*)d_out;
    char* ws = (char*)d_ws;
    int*    order = (int*)ws;                                  // 4 KB
    __bf16* xcat  = (__bf16*)(ws + 4096);                      // 1.57 MB
    __bf16* wcat  = (__bf16*)(ws + 4096 + 1572864);            // 1.57 MB
    float*  gates = (float*) (ws + 4096 + 2 * 1572864);        // 4 MB
    __bf16* hnb   = (__bf16*)(ws + 4096 + 2 * 1572864 + 4194304);   // 0.5 MB
    __bf16* WT    = (__bf16*)(ws + 4096 + 2 * 1572864 + 4194304 + 524288);

    sort_kernel<<<1, 1024, 0, stream>>>(ul, order);
    attn_kernel<<<B, 256, 0, stream>>>(hidden, io, ul, order, iW, ib, hW, hb,
                                       l1W, l1b, sW, sb, out, xcat);
    cvt_xh_kernel<<<B, 256, 0, stream>>>(emb, hidden, xcat, out);
    wcat_kernel<<<1024, 192, 0, stream>>>(Wih, Whh, wcat);
    xgemm_kernel<<<dim3(4, 16), 256, 0, stream>>>(xcat, wcat, gates);
    gate_kernel<<<B, 256, 0, stream>>>(gates, hidden, bih, bhh, out, hnb);
    transpose_kernel<<<dim3(125, 4), 256, 0, stream>>>(lW, WT);
    out_mfma_kernel<<<NWG, 256, 0, stream>>>(hnb, WT, lb, out);
}

// Round 6
// 253.649 us; speedup vs baseline: 3.7671x; 1.0402x over previous
//
#include <hip/hip_runtime.h>
#include <math.h>

#define B 1024
#define M 15
#define H 256
#define E 256
#define V 30000
#define U 1000

typedef float  vf4    __attribute__((ext_vector_type(4)));
typedef __bf16 bf16x8 __attribute__((ext_vector_type(8)));
typedef float  f32x4  __attribute__((ext_vector_type(4)));

// output layout (flat f32 concat, reference return order)
#define O_OUT   0
#define O_HID   ((size_t)B*V)
#define O_EMB   (O_HID + (size_t)B*H)
#define O_GRU   (O_EMB + (size_t)B*E)
#define O_ATT   (O_GRU + (size_t)B*H)

#define GLDS(g, l) __builtin_amdgcn_global_load_lds( \
    (const __attribute__((address_space(1))) void*)(g), \
    (__attribute__((address_space(3))) void*)(l), 16, 0, 0)

union BF8 { __bf16 h[8]; bf16x8 v; };
union BF4 { __bf16 h[4]; unsigned long long u; };

// ------------- sort samples by user (counting sort, 1 block) + run starts -------------
__global__ __launch_bounds__(1024) void sort_kernel(
    const int* __restrict__ ul, int* __restrict__ order, int* __restrict__ rbase_g)
{
    __shared__ int cnt[1024];
    __shared__ int base[1024];
    const int tid = threadIdx.x;
    cnt[tid] = 0;
    __syncthreads();
    const int u = ul[tid];
    atomicAdd(&cnt[u], 1);
    __syncthreads();
    int c0 = cnt[tid];
    int v  = c0;
    for (int off = 1; off < 1024; off <<= 1) {
        int add = (tid >= off) ? cnt[tid - off] : 0;
        __syncthreads();
        v += add;
        cnt[tid] = v;
        __syncthreads();
    }
    base[tid]   = v - c0;          // exclusive prefix = run start for user tid
    rbase_g[tid] = v - c0;
    __syncthreads();
    int pos = atomicAdd(&base[u], 1);
    order[pos] = tid;
}

// ---------------- Stage A: per-user attention (MFMA, reg-B, paired) ----------------
// Head block handles 1-2 samples of one user. B-operand (weights) read straight
// from global into MFMA fragments (no LDS staging, no per-panel barriers).
// GEMM1: A(32x512)=[io_s|0 ; 0|ht_s] x2 samples, B=[Wi;Wh] -> io_a rows + ht_a rows.
// GEMM2: A(32x512)=[ht_a bcast | io_a+bi],        B=lt1_W  -> tanh -> energies.
__global__ __launch_bounds__(256, 4) void attn_kernel(
    const float* __restrict__ hidden,       // (1,B,H)
    const float* __restrict__ inter_output, // (B,M,H)
    const int*   __restrict__ user_list,    // (B,)
    const int*   __restrict__ order,        // (B,)
    const int*   __restrict__ rbase,        // (1024,)
    const float* __restrict__ inter_W,      // (U,H,H)
    const float* __restrict__ inter_b,      // (U,H)
    const float* __restrict__ hidden_W,     // (U,H,H)
    const float* __restrict__ hidden_b,     // (U,H)
    const float* __restrict__ lt1_W,        // (U,2H,H)
    const float* __restrict__ lt1_b,        // (U,H)
    const float* __restrict__ scale_W,      // (U,H)
    const float* __restrict__ scale_b,      // (U,)
    float* __restrict__ out,
    __bf16* __restrict__ xcat)              // (B,768) bf16
{
    const int s   = ((blockIdx.x & 7) << 7) + (blockIdx.x >> 3);  // XCD chunk swizzle
    const int b0  = order[s];
    const int u   = user_list[b0];
    if ((s - rbase[u]) & 1) return;         // not a run head -> handled by partner
    bool paired = false;
    int  b1 = b0;
    if (s + 1 < B) {
        int ob = order[s + 1];
        if (user_list[ob] == u) { paired = true; b1 = ob; }
    }

    const int tid  = threadIdx.x;
    const int lane = tid & 63;
    const int wave = tid >> 6;
    const int wn0  = wave * 64;

    __shared__ __align__(16) __bf16 Abuf[32 * 512];  // 32 KB, chunk-swizzled
    __shared__ __align__(16) __bf16 hta[2][256];
    __shared__ float red[2][64];
    __shared__ float e_lds[2][16];

    // ---- phase 1: A = [io|0 ; 0|ht] for both samples ----
    {
        const int r    = tid >> 3;          // row 0..31
        const int part = tid & 7;
        const int sm   = r >> 4;
        const int mr   = r & 15;
        const int bs   = sm ? b1 : b0;
        const bool zr  = (sm == 1) && !paired;
        #pragma unroll
        for (int it = 0; it < 8; ++it) {
            int c = part + it * 8;          // chunk 0..63
            int k = c * 8;
            BF8 p;
            #pragma unroll
            for (int j = 0; j < 8; ++j) p.h[j] = (__bf16)0.f;
            if (!zr) {
                if (mr < 15 && k < 256) {
                    vf4 f0 = *(const vf4*)&inter_output[(size_t)bs * M * H + mr * H + k];
                    vf4 f1 = *(const vf4*)&inter_output[(size_t)bs * M * H + mr * H + k + 4];
                    p.h[0]=(__bf16)f0[0]; p.h[1]=(__bf16)f0[1]; p.h[2]=(__bf16)f0[2]; p.h[3]=(__bf16)f0[3];
                    p.h[4]=(__bf16)f1[0]; p.h[5]=(__bf16)f1[1]; p.h[6]=(__bf16)f1[2]; p.h[7]=(__bf16)f1[3];
                } else if (mr == 15 && k >= 256) {
                    vf4 f0 = *(const vf4*)&hidden[(size_t)bs * H + (k - 256)];
                    vf4 f1 = *(const vf4*)&hidden[(size_t)bs * H + (k - 256) + 4];
                    p.h[0]=(__bf16)f0[0]; p.h[1]=(__bf16)f0[1]; p.h[2]=(__bf16)f0[2]; p.h[3]=(__bf16)f0[3];
                    p.h[4]=(__bf16)f1[0]; p.h[5]=(__bf16)f1[1]; p.h[6]=(__bf16)f1[2]; p.h[7]=(__bf16)f1[3];
                }
            }
            *(bf16x8*)&Abuf[r * 512 + (c ^ (r & 7)) * 8] = p.v;
        }
    }
    __syncthreads();

    const float* Wi_base  = inter_W  + (size_t)u * H * H;
    const float* Wh_base  = hidden_W + (size_t)u * H * H;
    const float* lt1_base = lt1_W    + (size_t)u * 2 * H * H;

    const int ocol = wn0 + (lane & 15);           // this lane's base output col
    const int krow = (lane >> 4) * 8;             // this lane's k-subrow in 32-K step

    f32x4 acc1[2][4];
    #pragma unroll
    for (int mf = 0; mf < 2; ++mf)
        #pragma unroll
        for (int nf = 0; nf < 4; ++nf) { f32x4 z = {0.f,0.f,0.f,0.f}; acc1[mf][nf] = z; }

    // ================= GEMM 1 (K=512, 16 steps of 32) =================
    #pragma unroll 2
    for (int ks = 0; ks < 16; ++ks) {
        const float* Bp = ((ks < 8) ? (Wi_base + (size_t)(ks * 32) * H)
                                    : (Wh_base + (size_t)((ks - 8) * 32) * H))
                          + (size_t)krow * H + ocol;
        float t[4][8];
        #pragma unroll
        for (int j = 0; j < 8; ++j)
            #pragma unroll
            for (int nf = 0; nf < 4; ++nf)
                t[nf][j] = Bp[(size_t)j * H + nf * 16];
        bf16x8 bfr[4];
        #pragma unroll
        for (int nf = 0; nf < 4; ++nf) {
            BF8 pk;
            #pragma unroll
            for (int j = 0; j < 8; ++j) pk.h[j] = (__bf16)t[nf][j];
            bfr[nf] = pk.v;
        }
        int sca = ((ks * 4 + (lane >> 4)) ^ (lane & 7)) * 8;
        bf16x8 a0 = *(const bf16x8*)&Abuf[(lane & 15) * 512 + sca];
        #pragma unroll
        for (int nf = 0; nf < 4; ++nf)
            acc1[0][nf] = __builtin_amdgcn_mfma_f32_16x16x32_bf16(a0, bfr[nf], acc1[0][nf], 0, 0, 0);
        if (paired) {
            bf16x8 a1 = *(const bf16x8*)&Abuf[(16 + (lane & 15)) * 512 + sca];
            #pragma unroll
            for (int nf = 0; nf < 4; ++nf)
                acc1[1][nf] = __builtin_amdgcn_mfma_f32_16x16x32_bf16(a1, bfr[nf], acc1[1][nf], 0, 0, 0);
        }
    }
    __syncthreads();   // GEMM1 A reads done; Abuf may be overwritten

    // ---- extract ht_a (row 15 per sample) + hidden_b ; io_a+bi into Abuf k>=256 ----
    if ((lane >> 4) == 3) {
        #pragma unroll
        for (int nf = 0; nf < 4; ++nf) {
            int o = wn0 + nf * 16 + (lane & 15);
            float hb = hidden_b[(size_t)u * H + o];
            hta[0][o] = (__bf16)(acc1[0][nf][3] + hb);
            hta[1][o] = (__bf16)(acc1[1][nf][3] + hb);
        }
    }
    #pragma unroll
    for (int mf = 0; mf < 2; ++mf) {
        #pragma unroll
        for (int nf = 0; nf < 4; ++nf) {
            int o  = wn0 + nf * 16 + (lane & 15);
            float bi = inter_b[(size_t)u * H + o];
            int k  = 256 + o;
            #pragma unroll
            for (int j = 0; j < 4; ++j) {
                int r  = mf * 16 + (lane >> 4) * 4 + j;
                Abuf[r * 512 + ((k >> 3) ^ (r & 7)) * 8 + (k & 7)] = (__bf16)(acc1[mf][nf][j] + bi);
            }
        }
    }
    __syncthreads();   // hta visible

    // ---- phase 2 low-K: rows get hta[sample] broadcast (k<256) ----
    {
        const int r    = tid >> 3;
        const int part = tid & 7;
        const int sm   = r >> 4;
        #pragma unroll
        for (int it = 0; it < 4; ++it) {
            int c = part + it * 8;          // chunk 0..31
            bf16x8 hv = *(const bf16x8*)&hta[sm][c * 8];
            *(bf16x8*)&Abuf[r * 512 + (c ^ (r & 7)) * 8] = hv;
        }
    }
    __syncthreads();

    f32x4 acc2[2][4];
    #pragma unroll
    for (int mf = 0; mf < 2; ++mf)
        #pragma unroll
        for (int nf = 0; nf < 4; ++nf) { f32x4 z = {0.f,0.f,0.f,0.f}; acc2[mf][nf] = z; }

    // ================= GEMM 2 (K=512, 16 steps of 32) =================
    #pragma unroll 2
    for (int ks = 0; ks < 16; ++ks) {
        const float* Bp = lt1_base + (size_t)(ks * 32) * H + (size_t)krow * H + ocol;
        float t[4][8];
        #pragma unroll
        for (int j = 0; j < 8; ++j)
            #pragma unroll
            for (int nf = 0; nf < 4; ++nf)
                t[nf][j] = Bp[(size_t)j * H + nf * 16];
        bf16x8 bfr[4];
        #pragma unroll
        for (int nf = 0; nf < 4; ++nf) {
            BF8 pk;
            #pragma unroll
            for (int j = 0; j < 8; ++j) pk.h[j] = (__bf16)t[nf][j];
            bfr[nf] = pk.v;
        }
        int sca = ((ks * 4 + (lane >> 4)) ^ (lane & 7)) * 8;
        bf16x8 a0 = *(const bf16x8*)&Abuf[(lane & 15) * 512 + sca];
        #pragma unroll
        for (int nf = 0; nf < 4; ++nf)
            acc2[0][nf] = __builtin_amdgcn_mfma_f32_16x16x32_bf16(a0, bfr[nf], acc2[0][nf], 0, 0, 0);
        if (paired) {
            bf16x8 a1 = *(const bf16x8*)&Abuf[(16 + (lane & 15)) * 512 + sca];
            #pragma unroll
            for (int nf = 0; nf < 4; ++nf)
                acc2[1][nf] = __builtin_amdgcn_mfma_f32_16x16x32_bf16(a1, bfr[nf], acc2[1][nf], 0, 0, 0);
        }
    }

    // ---- energies ----
    float p0[4] = {0.f,0.f,0.f,0.f};
    float p1[4] = {0.f,0.f,0.f,0.f};
    #pragma unroll
    for (int nf = 0; nf < 4; ++nf) {
        int o = wn0 + nf * 16 + (lane & 15);
        float l1b = lt1_b[(size_t)u * H + o];
        float sw  = scale_W[(size_t)u * H + o];
        #pragma unroll
        for (int j = 0; j < 4; ++j)
            p0[j] += tanhf(acc2[0][nf][j] + l1b) * sw;
        if (paired)
            #pragma unroll
            for (int j = 0; j < 4; ++j)
                p1[j] += tanhf(acc2[1][nf][j] + l1b) * sw;
    }
    #pragma unroll
    for (int j = 0; j < 4; ++j) {
        float v = p0[j];
        v += __shfl_xor(v, 1, 64); v += __shfl_xor(v, 2, 64);
        v += __shfl_xor(v, 4, 64); v += __shfl_xor(v, 8, 64);
        if ((lane & 15) == 0) red[0][wave * 16 + (lane >> 4) * 4 + j] = v;
        float w = p1[j];
        w += __shfl_xor(w, 1, 64); w += __shfl_xor(w, 2, 64);
        w += __shfl_xor(w, 4, 64); w += __shfl_xor(w, 8, 64);
        if ((lane & 15) == 0) red[1][wave * 16 + (lane >> 4) * 4 + j] = w;
    }
    __syncthreads();
    if (tid < 32) {
        int sm = tid >> 4, mm = tid & 15;
        e_lds[sm][mm] = red[sm][mm] + red[sm][16 + mm] + red[sm][32 + mm] + red[sm][48 + mm]
                      + scale_b[u];
    }
    __syncthreads();

    const int nsm = paired ? 2 : 1;
    for (int sm = 0; sm < nsm; ++sm) {
        const int bs = sm ? b1 : b0;
        float mx = -1e30f;
        #pragma unroll
        for (int m = 0; m < M; ++m) mx = fmaxf(mx, e_lds[sm][m]);
        float sum = 0.f;
        float aw[M];
        #pragma unroll
        for (int m = 0; m < M; ++m) { aw[m] = expf(e_lds[sm][m] - mx); sum += aw[m]; }
        float inv = 1.f / sum;
        if (tid < M) out[O_ATT + (size_t)bs * M + tid] = aw[tid] * inv;
        float ctx = 0.f;
        #pragma unroll
        for (int m = 0; m < M; ++m)
            ctx += aw[m] * inter_output[(size_t)bs * M * H + m * H + tid];
        xcat[(size_t)bs * 768 + 256 + tid] = (__bf16)(ctx * inv);
    }
}

// ---------------- xcat fill: emb + h (bf16) + O_EMB passthrough ----------------
__global__ __launch_bounds__(256) void cvt_xh_kernel(
    const float* __restrict__ emb, const float* __restrict__ hidden,
    __bf16* __restrict__ xcat, float* __restrict__ out)
{
    const int b = blockIdx.x, tid = threadIdx.x;
    float ev = emb[(size_t)b * E + tid];
    float hv = hidden[(size_t)b * H + tid];
    xcat[(size_t)b * 768 + tid]       = (__bf16)ev;
    xcat[(size_t)b * 768 + 512 + tid] = (__bf16)hv;
    out[O_EMB + (size_t)b * E + tid]  = ev;
}

// ---------------- Wcat build: (1024 out-cols, 768 k) bf16 ----------------
__global__ __launch_bounds__(192) void wcat_kernel(
    const float* __restrict__ Wih, const float* __restrict__ Whh,
    __bf16* __restrict__ wcat)
{
    const int n = blockIdx.x;
    const int k = threadIdx.x * 4;
    vf4 v = {0.f, 0.f, 0.f, 0.f};
    if (n < 512) {
        v = (k < 512) ? *(const vf4*)&Wih[(size_t)n * 512 + k]
                      : *(const vf4*)&Whh[(size_t)n * 256 + (k - 512)];
    } else if (n < 768) {
        if (k < 512) v = *(const vf4*)&Wih[(size_t)n * 512 + k];
    } else {
        if (k >= 512) v = *(const vf4*)&Whh[(size_t)(n - 256) * 256 + (k - 512)];
    }
    BF4 p;
    p.h[0]=(__bf16)v[0]; p.h[1]=(__bf16)v[1]; p.h[2]=(__bf16)v[2]; p.h[3]=(__bf16)v[3];
    *(unsigned long long*)&wcat[(size_t)n * 768 + k] = p.u;
}

// ---------------- gates = xcat(B,768) @ wcat^T -> (B,1024) f32 ----------------
__global__ __launch_bounds__(256) void xgemm_kernel(
    const __bf16* __restrict__ xcat, const __bf16* __restrict__ wcat,
    float* __restrict__ gates)
{
    const int n0   = blockIdx.x * 256;
    const int m0   = blockIdx.y * 64;
    const int tid  = threadIdx.x;
    const int wave = tid >> 6, lane = tid & 63;
    const int wn0  = wave * 64;

    __shared__ __align__(16) __bf16 Al[64 * 64];
    __shared__ __align__(16) __bf16 Bl[256 * 64];

    f32x4 acc[4][4];
    #pragma unroll
    for (int mf = 0; mf < 4; ++mf)
        #pragma unroll
        for (int nf = 0; nf < 4; ++nf) { f32x4 z = {0.f,0.f,0.f,0.f}; acc[mf][nf] = z; }

    for (int ks = 0; ks < 12; ++ks) {
        #pragma unroll
        for (int r = 0; r < 2; ++r) {
            int L = r * 256 + tid;
            int m = L >> 3, c = L & 7;
            int sc = c ^ (m & 7);
            GLDS(xcat + (size_t)(m0 + m) * 768 + ks * 64 + sc * 8, &Al[(size_t)L * 8]);
        }
        #pragma unroll
        for (int r = 0; r < 8; ++r) {
            int L = r * 256 + tid;
            int n = L >> 3, c = L & 7;
            int sc = c ^ (n & 7);
            GLDS(wcat + (size_t)(n0 + n) * 768 + ks * 64 + sc * 8, &Bl[(size_t)L * 8]);
        }
        __syncthreads();
        #pragma unroll
        for (int kk = 0; kk < 2; ++kk) {
            bf16x8 af[4];
            #pragma unroll
            for (int mf = 0; mf < 4; ++mf) {
                int row = mf * 16 + (lane & 15);
                int c   = kk * 4 + (lane >> 4);
                af[mf] = *(const bf16x8*)&Al[row * 64 + (c ^ (row & 7)) * 8];
            }
            bf16x8 bfr[4];
            #pragma unroll
            for (int nf = 0; nf < 4; ++nf) {
                int col = wn0 + nf * 16 + (lane & 15);
                int c   = kk * 4 + (lane >> 4);
                bfr[nf] = *(const bf16x8*)&Bl[col * 64 + (c ^ (col & 7)) * 8];
            }
            #pragma unroll
            for (int mf = 0; mf < 4; ++mf)
                #pragma unroll
                for (int nf = 0; nf < 4; ++nf)
                    acc[mf][nf] = __builtin_amdgcn_mfma_f32_16x16x32_bf16(
                        af[mf], bfr[nf], acc[mf][nf], 0, 0, 0);
        }
        __syncthreads();
    }

    #pragma unroll
    for (int nf = 0; nf < 4; ++nf) {
        int n = n0 + wn0 + nf * 16 + (lane & 15);
        #pragma unroll
        for (int mf = 0; mf < 4; ++mf) {
            int rbase_ = m0 + mf * 16 + (lane >> 4) * 4;
            f32x4 a = acc[mf][nf];
            #pragma unroll
            for (int j = 0; j < 4; ++j)
                gates[(size_t)(rbase_ + j) * 1024 + n] = a[j];
        }
    }
}

// ---------------- GRU gates elementwise ----------------
__global__ __launch_bounds__(256) void gate_kernel(
    const float* __restrict__ gates,   // (B,1024)
    const float* __restrict__ hidden,  // (1,B,H)
    const float* __restrict__ bih, const float* __restrict__ bhh,
    float* __restrict__ out, __bf16* __restrict__ hnb)
{
    const int b = blockIdx.x, j = threadIdx.x;
    const float* g = gates + (size_t)b * 1024;
    float rs  = g[j]       + bih[j]       + bhh[j];
    float zs  = g[256 + j] + bih[256 + j] + bhh[256 + j];
    float gin = g[512 + j] + bih[512 + j];
    float ghn = g[768 + j] + bhh[512 + j];
    float h   = hidden[(size_t)b * H + j];
    float r_  = 1.f / (1.f + expf(-rs));
    float z_  = 1.f / (1.f + expf(-zs));
    float n_  = tanhf(gin + r_ * ghn);
    float hn  = (1.f - z_) * n_ + z_ * h;
    out[O_HID + (size_t)b * H + j] = hn;
    out[O_GRU + (size_t)b * H + j] = hn;
    hnb[(size_t)b * H + j] = (__bf16)hn;
}

// -------- lin_W (H,V) f32 -> WT (V,H) bf16 transpose/convert --------
__global__ __launch_bounds__(256) void transpose_kernel(
    const float* __restrict__ lin_W, __bf16* __restrict__ WT)
{
    const int v0  = blockIdx.x * 240;
    const int k0  = blockIdx.y * 64;
    const int tid = threadIdx.x;
    const int lane = tid & 63, kq = tid >> 6;

    __shared__ __bf16 T[240 * 68];

    if (lane < 60) {
        #pragma unroll
        for (int i = 0; i < 4; ++i) {
            int kr = kq * 16 + i * 4;
            vf4 f0 = *(const vf4*)&lin_W[(size_t)(k0 + kr + 0) * V + v0 + lane * 4];
            vf4 f1 = *(const vf4*)&lin_W[(size_t)(k0 + kr + 1) * V + v0 + lane * 4];
            vf4 f2 = *(const vf4*)&lin_W[(size_t)(k0 + kr + 2) * V + v0 + lane * 4];
            vf4 f3 = *(const vf4*)&lin_W[(size_t)(k0 + kr + 3) * V + v0 + lane * 4];
            #pragma unroll
            for (int j = 0; j < 4; ++j) {
                BF4 pk;
                pk.h[0] = (__bf16)f0[j];
                pk.h[1] = (__bf16)f1[j];
                pk.h[2] = (__bf16)f2[j];
                pk.h[3] = (__bf16)f3[j];
                int v = lane * 4 + j;
                *(unsigned long long*)&T[v * 68 + kr] = pk.u;
            }
        }
    }
    __syncthreads();

    for (int r = 0; r < 15; ++r) {
        int L = r * 256 + tid;
        int v = L >> 4, c = L & 15;
        *(unsigned long long*)&WT[(size_t)(v0 + v) * H + k0 + c * 4] =
            *(const unsigned long long*)&T[v * 68 + c * 4];
    }
}

// -------- Stage C (MFMA): out = hnew(bf16) @ WT^T + lin_b --------
#define GBM 64
#define GBN 256
#define GBK 64
#define NTM 16
#define NWG ((117 + 1) * NTM)
__global__ __launch_bounds__(256) void out_mfma_kernel(
    const __bf16* __restrict__ hnb,
    const __bf16* __restrict__ WT,
    const float* __restrict__ lin_b,
    float* __restrict__ out)
{
    const int L  = blockIdx.x;
    const int s  = (L & 7) * (NWG / 8) + (L >> 3);
    const int nt = s >> 4, mt = s & 15;
    const int n0 = nt * GBN;
    const int m0 = mt * GBM;
    const int tid  = threadIdx.x;
    const int wave = tid >> 6, lane = tid & 63;

    __shared__ __bf16 Al[GBM * H];
    __shared__ __bf16 Bl[GBN * GBK];

    #pragma unroll
    for (int r = 0; r < 8; ++r) {
        int Li = r * 256 + tid;
        int m = Li >> 5;
        int c = Li & 31;
        int sc = c ^ (m & 7);
        GLDS(hnb + (size_t)(m0 + m) * H + sc * 8, &Al[(size_t)Li * 8]);
    }

    f32x4 acc[4][4];
    #pragma unroll
    for (int mf = 0; mf < 4; ++mf)
        #pragma unroll
        for (int nf = 0; nf < 4; ++nf) {
            f32x4 z = {0.f, 0.f, 0.f, 0.f};
            acc[mf][nf] = z;
        }

    const int wn0 = wave * 64;

    for (int ks = 0; ks < 4; ++ks) {
        #pragma unroll
        for (int r = 0; r < 8; ++r) {
            int Li = r * 256 + tid;
            int n = Li >> 3;
            int c = Li & 7;
            int sc = c ^ (n & 7);
            int nn = n0 + n; if (nn >= V) nn = V - 1;
            GLDS(WT + (size_t)nn * H + ks * GBK + sc * 8, &Bl[(size_t)Li * 8]);
        }
        __syncthreads();

        #pragma unroll
        for (int kk = 0; kk < 2; ++kk) {
            bf16x8 af[4];
            #pragma unroll
            for (int mf = 0; mf < 4; ++mf) {
                int row = mf * 16 + (lane & 15);
                int c   = ks * 8 + kk * 4 + (lane >> 4);
                int cs  = c ^ (row & 7);
                af[mf] = *(const bf16x8*)&Al[row * H + cs * 8];
            }
            bf16x8 bfr[4];
            #pragma unroll
            for (int nf = 0; nf < 4; ++nf) {
                int col = wn0 + nf * 16 + (lane & 15);
                int c   = kk * 4 + (lane >> 4);
                int cs  = c ^ (col & 7);
                bfr[nf] = *(const bf16x8*)&Bl[col * GBK + cs * 8];
            }
            #pragma unroll
            for (int mf = 0; mf < 4; ++mf)
                #pragma unroll
                for (int nf = 0; nf < 4; ++nf)
                    acc[mf][nf] = __builtin_amdgcn_mfma_f32_16x16x32_bf16(
                        af[mf], bfr[nf], acc[mf][nf], 0, 0, 0);
        }
        __syncthreads();
    }

    #pragma unroll
    for (int nf = 0; nf < 4; ++nf) {
        int v = n0 + wn0 + nf * 16 + (lane & 15);
        if (v < V) {
            float lb = lin_b[v];
            #pragma unroll
            for (int mf = 0; mf < 4; ++mf) {
                int rbase_ = m0 + mf * 16 + (lane >> 4) * 4;
                f32x4 a = acc[mf][nf];
                #pragma unroll
                for (int j = 0; j < 4; ++j)
                    out[(size_t)(rbase_ + j) * V + v] = a[j] + lb;
            }
        }
    }
}

extern "C" void kernel_launch(void* const* d_in, const int* in_sizes, int n_in,
                              void* d_out, int out_size, void* d_ws, size_t ws_size,
                              hipStream_t stream) {
    const float* emb    = (const float*)d_in[1];
    const float* hidden = (const float*)d_in[2];
    const float* io     = (const float*)d_in[3];
    const int*   ul     = (const int*)  d_in[4];
    const float* iW     = (const float*)d_in[5];
    const float* ib     = (const float*)d_in[6];
    const float* hW     = (const float*)d_in[7];
    const float* hb     = (const float*)d_in[8];
    const float* l1W    = (const float*)d_in[9];
    const float* l1b    = (const float*)d_in[10];
    const float* sW     = (const float*)d_in[11];
    const float* sb     = (const float*)d_in[12];
    const float* Wih    = (const float*)d_in[13];
    const float* Whh    = (const float*)d_in[14];
    const float* bih    = (const float*)d_in[15];
    const float* bhh    = (const float*)d_in[16];
    const float* lW     = (const float*)d_in[17];
    const float* lb     = (const float*)d_in[18];

    float* out = (float*)d_out;
    char* ws = (char*)d_ws;
    int*    order = (int*)ws;                                       // 4 KB
    int*    rbase = (int*)(ws + 4096);                              // 4 KB
    __bf16* xcat  = (__bf16*)(ws + 8192);                           // 1.57 MB
    __bf16* wcat  = (__bf16*)(ws + 8192 + 1572864);                 // 1.57 MB
    float*  gates = (float*) (ws + 8192 + 2 * 1572864);             // 4 MB
    __bf16* hnb   = (__bf16*)(ws + 8192 + 2 * 1572864 + 4194304);   // 0.5 MB
    __bf16* WT    = (__bf16*)(ws + 8192 + 2 * 1572864 + 4194304 + 524288);

    sort_kernel<<<1, 1024, 0, stream>>>(ul, order, rbase);
    attn_kernel<<<B, 256, 0, stream>>>(hidden, io, ul, order, rbase, iW, ib, hW, hb,
                                       l1W, l1b, sW, sb, out, xcat);
    cvt_xh_kernel<<<B, 256, 0, stream>>>(emb, hidden, xcat, out);
    wcat_kernel<<<1024, 192, 0, stream>>>(Wih, Whh, wcat);
    xgemm_kernel<<<dim3(4, 16), 256, 0, stream>>>(xcat, wcat, gates);
    gate_kernel<<<B, 256, 0, stream>>>(gates, hidden, bih, bhh, out, hnb);
    transpose_kernel<<<dim3(125, 4), 256, 0, stream>>>(lW, WT);
    out_mfma_kernel<<<NWG, 256, 0, stream>>>(hnb, WT, lb, out);
}

// Round 7
// 244.050 us; speedup vs baseline: 3.9153x; 1.0393x over previous
//
#include <hip/hip_runtime.h>
#include <math.h>

#define B 1024
#define M 15
#define H 256
#define E 256
#define V 30000
#define U 1000

typedef float  vf4    __attribute__((ext_vector_type(4)));
typedef __bf16 bf16x8 __attribute__((ext_vector_type(8)));
typedef float  f32x4  __attribute__((ext_vector_type(4)));

// output layout (flat f32 concat, reference return order)
#define O_OUT   0
#define O_HID   ((size_t)B*V)
#define O_EMB   (O_HID + (size_t)B*H)
#define O_GRU   (O_EMB + (size_t)B*E)
#define O_ATT   (O_GRU + (size_t)B*H)

#define GLDS(g, l) __builtin_amdgcn_global_load_lds( \
    (const __attribute__((address_space(1))) void*)(g), \
    (__attribute__((address_space(3))) void*)(l), 16, 0, 0)

union BF8 { __bf16 h[8]; bf16x8 v; };
union BF4 { __bf16 h[4]; unsigned long long u; };

// ------------- sort samples by user (counting sort, 1 block) + run starts -------------
__global__ __launch_bounds__(1024) void sort_kernel(
    const int* __restrict__ ul, int* __restrict__ order, int* __restrict__ rbase_g)
{
    __shared__ int cnt[1024];
    __shared__ int base[1024];
    const int tid = threadIdx.x;
    cnt[tid] = 0;
    __syncthreads();
    const int u = ul[tid];
    atomicAdd(&cnt[u], 1);
    __syncthreads();
    int c0 = cnt[tid];
    int v  = c0;
    for (int off = 1; off < 1024; off <<= 1) {
        int add = (tid >= off) ? cnt[tid - off] : 0;
        __syncthreads();
        v += add;
        cnt[tid] = v;
        __syncthreads();
    }
    base[tid]   = v - c0;
    rbase_g[tid] = v - c0;
    __syncthreads();
    int pos = atomicAdd(&base[u], 1);
    order[pos] = tid;
}

// =============== fused: attn (0..1023) | transpose (1024..1523) | wcat (1524..1779) ===============
#define FB_ATTN 1024
#define FB_TR   500
#define FB_WC   256
#define FB_TOT  (FB_ATTN + FB_TR + FB_WC)

__global__ __launch_bounds__(256, 4) void fused_pre_kernel(
    const float* __restrict__ hidden,       // (1,B,H)
    const float* __restrict__ inter_output, // (B,M,H)
    const int*   __restrict__ user_list,    // (B,)
    const int*   __restrict__ order,        // (B,)
    const int*   __restrict__ rbase,        // (1024,)
    const float* __restrict__ inter_W,      // (U,H,H)
    const float* __restrict__ inter_b,      // (U,H)
    const float* __restrict__ hidden_W,     // (U,H,H)
    const float* __restrict__ hidden_b,     // (U,H)
    const float* __restrict__ lt1_W,        // (U,2H,H)
    const float* __restrict__ lt1_b,        // (U,H)
    const float* __restrict__ scale_W,      // (U,H)
    const float* __restrict__ scale_b,      // (U,)
    const float* __restrict__ emb,          // (B,1,E)
    const float* __restrict__ Wih,          // (3H,2E)
    const float* __restrict__ Whh,          // (3H,H)
    const float* __restrict__ lin_W,        // (H,V)
    float* __restrict__ out,
    __bf16* __restrict__ xcat,              // (B,768)
    __bf16* __restrict__ wcat,              // (1024,768)
    __bf16* __restrict__ WT)                // (V,H)
{
    __shared__ __align__(16) char smem[34432];
    const int bid = blockIdx.x;
    const int tid = threadIdx.x;

    if (bid >= FB_ATTN + FB_TR) {
        // ---------------- wcat section ----------------
        const int wb   = bid - (FB_ATTN + FB_TR);
        const int wave = tid >> 6, lane = tid & 63;
        const int n    = wb * 4 + wave;
        #pragma unroll
        for (int i = 0; i < 3; ++i) {
            int k = i * 256 + lane * 4;
            vf4 v = {0.f, 0.f, 0.f, 0.f};
            if (n < 512) {
                v = (k < 512) ? *(const vf4*)&Wih[(size_t)n * 512 + k]
                              : *(const vf4*)&Whh[(size_t)n * 256 + (k - 512)];
            } else if (n < 768) {
                if (k < 512) v = *(const vf4*)&Wih[(size_t)n * 512 + k];
            } else {
                if (k >= 512) v = *(const vf4*)&Whh[(size_t)(n - 256) * 256 + (k - 512)];
            }
            BF4 p;
            p.h[0]=(__bf16)v[0]; p.h[1]=(__bf16)v[1]; p.h[2]=(__bf16)v[2]; p.h[3]=(__bf16)v[3];
            *(unsigned long long*)&wcat[(size_t)n * 768 + k] = p.u;
        }
        return;
    }

    if (bid >= FB_ATTN) {
        // ---------------- transpose section: lin_W -> WT ----------------
        const int t   = bid - FB_ATTN;
        const int v0  = (t % 125) * 240;
        const int k0  = (t / 125) * 64;
        const int lane = tid & 63, kq = tid >> 6;
        __bf16* T = (__bf16*)smem;            // 240*68 bf16 = 32640 B

        if (lane < 60) {
            #pragma unroll
            for (int i = 0; i < 4; ++i) {
                int kr = kq * 16 + i * 4;
                vf4 f0 = *(const vf4*)&lin_W[(size_t)(k0 + kr + 0) * V + v0 + lane * 4];
                vf4 f1 = *(const vf4*)&lin_W[(size_t)(k0 + kr + 1) * V + v0 + lane * 4];
                vf4 f2 = *(const vf4*)&lin_W[(size_t)(k0 + kr + 2) * V + v0 + lane * 4];
                vf4 f3 = *(const vf4*)&lin_W[(size_t)(k0 + kr + 3) * V + v0 + lane * 4];
                #pragma unroll
                for (int j = 0; j < 4; ++j) {
                    BF4 pk;
                    pk.h[0] = (__bf16)f0[j];
                    pk.h[1] = (__bf16)f1[j];
                    pk.h[2] = (__bf16)f2[j];
                    pk.h[3] = (__bf16)f3[j];
                    int v = lane * 4 + j;
                    *(unsigned long long*)&T[v * 68 + kr] = pk.u;
                }
            }
        }
        __syncthreads();
        for (int r = 0; r < 15; ++r) {
            int L = r * 256 + tid;
            int v = L >> 4, c = L & 15;
            *(unsigned long long*)&WT[(size_t)(v0 + v) * H + k0 + c * 4] =
                *(const unsigned long long*)&T[v * 68 + c * 4];
        }
        return;
    }

    // ---------------- attn section ----------------
    const int s   = ((bid & 7) << 7) + (bid >> 3);  // XCD chunk swizzle
    const int b0  = order[s];
    const int u   = user_list[b0];

    // cvt_xh for this block's sample (done by ALL 1024 blocks, head or not)
    {
        float ev = emb[(size_t)b0 * E + tid];
        float hv = hidden[(size_t)b0 * H + tid];
        xcat[(size_t)b0 * 768 + tid]       = (__bf16)ev;
        xcat[(size_t)b0 * 768 + 512 + tid] = (__bf16)hv;
        out[O_EMB + (size_t)b0 * E + tid]  = ev;
    }

    if ((s - rbase[u]) & 1) return;         // not a run head
    bool paired = false;
    int  b1 = b0;
    if (s + 1 < B) {
        int ob = order[s + 1];
        if (user_list[ob] == u) { paired = true; b1 = ob; }
    }

    const int lane = tid & 63;
    const int wave = tid >> 6;
    const int wn0  = wave * 64;

    __bf16* Abuf = (__bf16*)smem;                       // 32 KB
    __bf16* hta  = (__bf16*)(smem + 32768);             // 2*256 bf16 = 1 KB
    float*  red  = (float*)(smem + 32768 + 1024);       // 2*64 f32 = 512 B
    float*  e_lds= (float*)(smem + 32768 + 1024 + 512); // 2*16 f32 = 128 B

    // ---- phase 1: A = [io|0 ; 0|ht] for both samples ----
    {
        const int r    = tid >> 3;
        const int part = tid & 7;
        const int sm   = r >> 4;
        const int mr   = r & 15;
        const int bs   = sm ? b1 : b0;
        const bool zr  = (sm == 1) && !paired;
        #pragma unroll
        for (int it = 0; it < 8; ++it) {
            int c = part + it * 8;
            int k = c * 8;
            BF8 p;
            #pragma unroll
            for (int j = 0; j < 8; ++j) p.h[j] = (__bf16)0.f;
            if (!zr) {
                if (mr < 15 && k < 256) {
                    vf4 f0 = *(const vf4*)&inter_output[(size_t)bs * M * H + mr * H + k];
                    vf4 f1 = *(const vf4*)&inter_output[(size_t)bs * M * H + mr * H + k + 4];
                    p.h[0]=(__bf16)f0[0]; p.h[1]=(__bf16)f0[1]; p.h[2]=(__bf16)f0[2]; p.h[3]=(__bf16)f0[3];
                    p.h[4]=(__bf16)f1[0]; p.h[5]=(__bf16)f1[1]; p.h[6]=(__bf16)f1[2]; p.h[7]=(__bf16)f1[3];
                } else if (mr == 15 && k >= 256) {
                    vf4 f0 = *(const vf4*)&hidden[(size_t)bs * H + (k - 256)];
                    vf4 f1 = *(const vf4*)&hidden[(size_t)bs * H + (k - 256) + 4];
                    p.h[0]=(__bf16)f0[0]; p.h[1]=(__bf16)f0[1]; p.h[2]=(__bf16)f0[2]; p.h[3]=(__bf16)f0[3];
                    p.h[4]=(__bf16)f1[0]; p.h[5]=(__bf16)f1[1]; p.h[6]=(__bf16)f1[2]; p.h[7]=(__bf16)f1[3];
                }
            }
            *(bf16x8*)&Abuf[r * 512 + (c ^ (r & 7)) * 8] = p.v;
        }
    }
    __syncthreads();

    const float* Wi_base  = inter_W  + (size_t)u * H * H;
    const float* Wh_base  = hidden_W + (size_t)u * H * H;
    const float* lt1_base = lt1_W    + (size_t)u * 2 * H * H;

    const int ocol = wn0 + (lane & 15);
    const int krow = (lane >> 4) * 8;

    f32x4 acc1[2][4];
    #pragma unroll
    for (int mf = 0; mf < 2; ++mf)
        #pragma unroll
        for (int nf = 0; nf < 4; ++nf) { f32x4 z = {0.f,0.f,0.f,0.f}; acc1[mf][nf] = z; }

    // ================= GEMM 1 =================
    #pragma unroll 2
    for (int ks = 0; ks < 16; ++ks) {
        const float* Bp = ((ks < 8) ? (Wi_base + (size_t)(ks * 32) * H)
                                    : (Wh_base + (size_t)((ks - 8) * 32) * H))
                          + (size_t)krow * H + ocol;
        float t[4][8];
        #pragma unroll
        for (int j = 0; j < 8; ++j)
            #pragma unroll
            for (int nf = 0; nf < 4; ++nf)
                t[nf][j] = Bp[(size_t)j * H + nf * 16];
        bf16x8 bfr[4];
        #pragma unroll
        for (int nf = 0; nf < 4; ++nf) {
            BF8 pk;
            #pragma unroll
            for (int j = 0; j < 8; ++j) pk.h[j] = (__bf16)t[nf][j];
            bfr[nf] = pk.v;
        }
        int sca = ((ks * 4 + (lane >> 4)) ^ (lane & 7)) * 8;
        bf16x8 a0 = *(const bf16x8*)&Abuf[(lane & 15) * 512 + sca];
        #pragma unroll
        for (int nf = 0; nf < 4; ++nf)
            acc1[0][nf] = __builtin_amdgcn_mfma_f32_16x16x32_bf16(a0, bfr[nf], acc1[0][nf], 0, 0, 0);
        if (paired) {
            bf16x8 a1 = *(const bf16x8*)&Abuf[(16 + (lane & 15)) * 512 + sca];
            #pragma unroll
            for (int nf = 0; nf < 4; ++nf)
                acc1[1][nf] = __builtin_amdgcn_mfma_f32_16x16x32_bf16(a1, bfr[nf], acc1[1][nf], 0, 0, 0);
        }
    }
    __syncthreads();

    // ---- extract ht_a + hidden_b ; io_a+bi into Abuf k>=256 ----
    if ((lane >> 4) == 3) {
        #pragma unroll
        for (int nf = 0; nf < 4; ++nf) {
            int o = wn0 + nf * 16 + (lane & 15);
            float hb = hidden_b[(size_t)u * H + o];
            hta[o]       = (__bf16)(acc1[0][nf][3] + hb);
            hta[256 + o] = (__bf16)(acc1[1][nf][3] + hb);
        }
    }
    #pragma unroll
    for (int mf = 0; mf < 2; ++mf) {
        #pragma unroll
        for (int nf = 0; nf < 4; ++nf) {
            int o  = wn0 + nf * 16 + (lane & 15);
            float bi = inter_b[(size_t)u * H + o];
            int k  = 256 + o;
            #pragma unroll
            for (int j = 0; j < 4; ++j) {
                int r  = mf * 16 + (lane >> 4) * 4 + j;
                Abuf[r * 512 + ((k >> 3) ^ (r & 7)) * 8 + (k & 7)] = (__bf16)(acc1[mf][nf][j] + bi);
            }
        }
    }
    __syncthreads();

    // ---- phase 2 low-K: hta broadcast ----
    {
        const int r    = tid >> 3;
        const int part = tid & 7;
        const int sm   = r >> 4;
        #pragma unroll
        for (int it = 0; it < 4; ++it) {
            int c = part + it * 8;
            bf16x8 hv = *(const bf16x8*)&hta[sm * 256 + c * 8];
            *(bf16x8*)&Abuf[r * 512 + (c ^ (r & 7)) * 8] = hv;
        }
    }
    __syncthreads();

    f32x4 acc2[2][4];
    #pragma unroll
    for (int mf = 0; mf < 2; ++mf)
        #pragma unroll
        for (int nf = 0; nf < 4; ++nf) { f32x4 z = {0.f,0.f,0.f,0.f}; acc2[mf][nf] = z; }

    // ================= GEMM 2 =================
    #pragma unroll 2
    for (int ks = 0; ks < 16; ++ks) {
        const float* Bp = lt1_base + (size_t)(ks * 32) * H + (size_t)krow * H + ocol;
        float t[4][8];
        #pragma unroll
        for (int j = 0; j < 8; ++j)
            #pragma unroll
            for (int nf = 0; nf < 4; ++nf)
                t[nf][j] = Bp[(size_t)j * H + nf * 16];
        bf16x8 bfr[4];
        #pragma unroll
        for (int nf = 0; nf < 4; ++nf) {
            BF8 pk;
            #pragma unroll
            for (int j = 0; j < 8; ++j) pk.h[j] = (__bf16)t[nf][j];
            bfr[nf] = pk.v;
        }
        int sca = ((ks * 4 + (lane >> 4)) ^ (lane & 7)) * 8;
        bf16x8 a0 = *(const bf16x8*)&Abuf[(lane & 15) * 512 + sca];
        #pragma unroll
        for (int nf = 0; nf < 4; ++nf)
            acc2[0][nf] = __builtin_amdgcn_mfma_f32_16x16x32_bf16(a0, bfr[nf], acc2[0][nf], 0, 0, 0);
        if (paired) {
            bf16x8 a1 = *(const bf16x8*)&Abuf[(16 + (lane & 15)) * 512 + sca];
            #pragma unroll
            for (int nf = 0; nf < 4; ++nf)
                acc2[1][nf] = __builtin_amdgcn_mfma_f32_16x16x32_bf16(a1, bfr[nf], acc2[1][nf], 0, 0, 0);
        }
    }

    // ---- energies ----
    float p0[4] = {0.f,0.f,0.f,0.f};
    float p1[4] = {0.f,0.f,0.f,0.f};
    #pragma unroll
    for (int nf = 0; nf < 4; ++nf) {
        int o = wn0 + nf * 16 + (lane & 15);
        float l1b = lt1_b[(size_t)u * H + o];
        float sw  = scale_W[(size_t)u * H + o];
        #pragma unroll
        for (int j = 0; j < 4; ++j)
            p0[j] += tanhf(acc2[0][nf][j] + l1b) * sw;
        if (paired)
            #pragma unroll
            for (int j = 0; j < 4; ++j)
                p1[j] += tanhf(acc2[1][nf][j] + l1b) * sw;
    }
    #pragma unroll
    for (int j = 0; j < 4; ++j) {
        float v = p0[j];
        v += __shfl_xor(v, 1, 64); v += __shfl_xor(v, 2, 64);
        v += __shfl_xor(v, 4, 64); v += __shfl_xor(v, 8, 64);
        if ((lane & 15) == 0) red[0 * 64 + wave * 16 + (lane >> 4) * 4 + j] = v;
        float w = p1[j];
        w += __shfl_xor(w, 1, 64); w += __shfl_xor(w, 2, 64);
        w += __shfl_xor(w, 4, 64); w += __shfl_xor(w, 8, 64);
        if ((lane & 15) == 0) red[1 * 64 + wave * 16 + (lane >> 4) * 4 + j] = w;
    }
    __syncthreads();
    if (tid < 32) {
        int sm = tid >> 4, mm = tid & 15;
        e_lds[sm * 16 + mm] = red[sm * 64 + mm] + red[sm * 64 + 16 + mm]
                            + red[sm * 64 + 32 + mm] + red[sm * 64 + 48 + mm]
                            + scale_b[u];
    }
    __syncthreads();

    const int nsm = paired ? 2 : 1;
    for (int sm = 0; sm < nsm; ++sm) {
        const int bs = sm ? b1 : b0;
        float mx = -1e30f;
        #pragma unroll
        for (int m = 0; m < M; ++m) mx = fmaxf(mx, e_lds[sm * 16 + m]);
        float sum = 0.f;
        float aw[M];
        #pragma unroll
        for (int m = 0; m < M; ++m) { aw[m] = expf(e_lds[sm * 16 + m] - mx); sum += aw[m]; }
        float inv = 1.f / sum;
        if (tid < M) out[O_ATT + (size_t)bs * M + tid] = aw[tid] * inv;
        float ctx = 0.f;
        #pragma unroll
        for (int m = 0; m < M; ++m)
            ctx += aw[m] * inter_output[(size_t)bs * M * H + m * H + tid];
        xcat[(size_t)bs * 768 + 256 + tid] = (__bf16)(ctx * inv);
    }
}

// ---------------- gates = xcat(B,768) @ wcat^T -> (B,1024) f32; 64x64 tiles, BK=128 ----------------
__global__ __launch_bounds__(256) void xgemm_kernel(
    const __bf16* __restrict__ xcat, const __bf16* __restrict__ wcat,
    float* __restrict__ gates)
{
    const int n0   = blockIdx.x * 64;
    const int m0   = blockIdx.y * 64;
    const int tid  = threadIdx.x;
    const int wave = tid >> 6, lane = tid & 63;
    const int wm   = wave >> 1, wn = wave & 1;

    __shared__ __align__(16) __bf16 Al[64 * 128];
    __shared__ __align__(16) __bf16 Bl[64 * 128];

    f32x4 acc[2][2];
    #pragma unroll
    for (int mf = 0; mf < 2; ++mf)
        #pragma unroll
        for (int nf = 0; nf < 2; ++nf) { f32x4 z = {0.f,0.f,0.f,0.f}; acc[mf][nf] = z; }

    for (int ks = 0; ks < 6; ++ks) {
        #pragma unroll
        for (int r = 0; r < 4; ++r) {
            int L = r * 256 + tid;
            int row = L >> 4, c = L & 15;
            int sc = c ^ (row & 7);
            GLDS(xcat + (size_t)(m0 + row) * 768 + ks * 128 + sc * 8, &Al[(size_t)L * 8]);
        }
        #pragma unroll
        for (int r = 0; r < 4; ++r) {
            int L = r * 256 + tid;
            int row = L >> 4, c = L & 15;
            int sc = c ^ (row & 7);
            GLDS(wcat + (size_t)(n0 + row) * 768 + ks * 128 + sc * 8, &Bl[(size_t)L * 8]);
        }
        __syncthreads();
        #pragma unroll
        for (int kk = 0; kk < 4; ++kk) {
            bf16x8 af[2];
            #pragma unroll
            for (int mf = 0; mf < 2; ++mf) {
                int row = wm * 32 + mf * 16 + (lane & 15);
                int c   = kk * 4 + (lane >> 4);
                af[mf] = *(const bf16x8*)&Al[row * 128 + (c ^ (row & 7)) * 8];
            }
            bf16x8 bfr[2];
            #pragma unroll
            for (int nf = 0; nf < 2; ++nf) {
                int col = wn * 32 + nf * 16 + (lane & 15);
                int c   = kk * 4 + (lane >> 4);
                bfr[nf] = *(const bf16x8*)&Bl[col * 128 + (c ^ (col & 7)) * 8];
            }
            #pragma unroll
            for (int mf = 0; mf < 2; ++mf)
                #pragma unroll
                for (int nf = 0; nf < 2; ++nf)
                    acc[mf][nf] = __builtin_amdgcn_mfma_f32_16x16x32_bf16(
                        af[mf], bfr[nf], acc[mf][nf], 0, 0, 0);
        }
        __syncthreads();
    }

    #pragma unroll
    for (int nf = 0; nf < 2; ++nf) {
        int n = n0 + wn * 32 + nf * 16 + (lane & 15);
        #pragma unroll
        for (int mf = 0; mf < 2; ++mf) {
            int rb = m0 + wm * 32 + mf * 16 + (lane >> 4) * 4;
            f32x4 a = acc[mf][nf];
            #pragma unroll
            for (int j = 0; j < 4; ++j)
                gates[(size_t)(rb + j) * 1024 + n] = a[j];
        }
    }
}

// ---------------- GRU gates elementwise ----------------
__global__ __launch_bounds__(256) void gate_kernel(
    const float* __restrict__ gates,
    const float* __restrict__ hidden,
    const float* __restrict__ bih, const float* __restrict__ bhh,
    float* __restrict__ out, __bf16* __restrict__ hnb)
{
    const int b = blockIdx.x, j = threadIdx.x;
    const float* g = gates + (size_t)b * 1024;
    float rs  = g[j]       + bih[j]       + bhh[j];
    float zs  = g[256 + j] + bih[256 + j] + bhh[256 + j];
    float gin = g[512 + j] + bih[512 + j];
    float ghn = g[768 + j] + bhh[512 + j];
    float h   = hidden[(size_t)b * H + j];
    float r_  = 1.f / (1.f + expf(-rs));
    float z_  = 1.f / (1.f + expf(-zs));
    float n_  = tanhf(gin + r_ * ghn);
    float hn  = (1.f - z_) * n_ + z_ * h;
    out[O_HID + (size_t)b * H + j] = hn;
    out[O_GRU + (size_t)b * H + j] = hn;
    hnb[(size_t)b * H + j] = (__bf16)hn;
}

// -------- Stage C (MFMA): out = hnew(bf16) @ WT^T + lin_b; LDS-staged coalesced C-write --------
#define GBM 64
#define GBN 256
#define GBK 64
#define NTM 16
#define NWG ((117 + 1) * NTM)
__global__ __launch_bounds__(256) void out_mfma_kernel(
    const __bf16* __restrict__ hnb,
    const __bf16* __restrict__ WT,
    const float* __restrict__ lin_b,
    float* __restrict__ out)
{
    const int L  = blockIdx.x;
    const int s  = (L & 7) * (NWG / 8) + (L >> 3);
    const int nt = s >> 4, mt = s & 15;
    const int n0 = nt * GBN;
    const int m0 = mt * GBM;
    const int tid  = threadIdx.x;
    const int wave = tid >> 6, lane = tid & 63;

    __shared__ __align__(16) char gsm[GBM * H * 2 + GBN * GBK * 2];  // 64 KB
    __bf16* Al = (__bf16*)gsm;
    __bf16* Bl = (__bf16*)(gsm + GBM * H * 2);

    #pragma unroll
    for (int r = 0; r < 8; ++r) {
        int Li = r * 256 + tid;
        int m = Li >> 5;
        int c = Li & 31;
        int sc = c ^ (m & 7);
        GLDS(hnb + (size_t)(m0 + m) * H + sc * 8, &Al[(size_t)Li * 8]);
    }

    f32x4 acc[4][4];
    #pragma unroll
    for (int mf = 0; mf < 4; ++mf)
        #pragma unroll
        for (int nf = 0; nf < 4; ++nf) {
            f32x4 z = {0.f, 0.f, 0.f, 0.f};
            acc[mf][nf] = z;
        }

    const int wn0 = wave * 64;

    for (int ks = 0; ks < 4; ++ks) {
        #pragma unroll
        for (int r = 0; r < 8; ++r) {
            int Li = r * 256 + tid;
            int n = Li >> 3;
            int c = Li & 7;
            int sc = c ^ (n & 7);
            int nn = n0 + n; if (nn >= V) nn = V - 1;
            GLDS(WT + (size_t)nn * H + ks * GBK + sc * 8, &Bl[(size_t)Li * 8]);
        }
        __syncthreads();

        #pragma unroll
        for (int kk = 0; kk < 2; ++kk) {
            bf16x8 af[4];
            #pragma unroll
            for (int mf = 0; mf < 4; ++mf) {
                int row = mf * 16 + (lane & 15);
                int c   = ks * 8 + kk * 4 + (lane >> 4);
                int cs  = c ^ (row & 7);
                af[mf] = *(const bf16x8*)&Al[row * H + cs * 8];
            }
            bf16x8 bfr[4];
            #pragma unroll
            for (int nf = 0; nf < 4; ++nf) {
                int col = wn0 + nf * 16 + (lane & 15);
                int c   = kk * 4 + (lane >> 4);
                int cs  = c ^ (col & 7);
                bfr[nf] = *(const bf16x8*)&Bl[col * GBK + cs * 8];
            }
            #pragma unroll
            for (int mf = 0; mf < 4; ++mf)
                #pragma unroll
                for (int nf = 0; nf < 4; ++nf)
                    acc[mf][nf] = __builtin_amdgcn_mfma_f32_16x16x32_bf16(
                        af[mf], bfr[nf], acc[mf][nf], 0, 0, 0);
        }
        __syncthreads();
    }

    // ---- epilogue: stage C tile in LDS (reusing gsm), write full-wave coalesced rows ----
    float* Cs = (float*)gsm;   // 64 x 256 f32 = 64 KB exactly
    #pragma unroll
    for (int nf = 0; nf < 4; ++nf) {
        int col = wn0 + nf * 16 + (lane & 15);
        #pragma unroll
        for (int mf = 0; mf < 4; ++mf) {
            #pragma unroll
            for (int j = 0; j < 4; ++j)
                Cs[(mf * 16 + (lane >> 4) * 4 + j) * 256 + col] = acc[mf][nf][j];
        }
    }
    __syncthreads();

    const bool nok = (n0 + lane * 4 + 3 < V);
    f32x4 lb = {0.f, 0.f, 0.f, 0.f};
    if (nok) lb = *(const f32x4*)&lin_b[n0 + lane * 4];
    for (int r = wave; r < 64; r += 4) {
        f32x4 c = *(const f32x4*)&Cs[r * 256 + lane * 4];
        c += lb;
        if (nok)
            *(f32x4*)&out[(size_t)(m0 + r) * V + n0 + lane * 4] = c;
    }
}

extern "C" void kernel_launch(void* const* d_in, const int* in_sizes, int n_in,
                              void* d_out, int out_size, void* d_ws, size_t ws_size,
                              hipStream_t stream) {
    const float* emb    = (const float*)d_in[1];
    const float* hidden = (const float*)d_in[2];
    const float* io     = (const float*)d_in[3];
    const int*   ul     = (const int*)  d_in[4];
    const float* iW     = (const float*)d_in[5];
    const float* ib     = (const float*)d_in[6];
    const float* hW     = (const float*)d_in[7];
    const float* hb     = (const float*)d_in[8];
    const float* l1W    = (const float*)d_in[9];
    const float* l1b    = (const float*)d_in[10];
    const float* sW     = (const float*)d_in[11];
    const float* sb     = (const float*)d_in[12];
    const float* Wih    = (const float*)d_in[13];
    const float* Whh    = (const float*)d_in[14];
    const float* bih    = (const float*)d_in[15];
    const float* bhh    = (const float*)d_in[16];
    const float* lW     = (const float*)d_in[17];
    const float* lb     = (const float*)d_in[18];

    float* out = (float*)d_out;
    char* ws = (char*)d_ws;
    int*    order = (int*)ws;                                       // 4 KB
    int*    rbase = (int*)(ws + 4096);                              // 4 KB
    __bf16* xcat  = (__bf16*)(ws + 8192);                           // 1.57 MB
    __bf16* wcat  = (__bf16*)(ws + 8192 + 1572864);                 // 1.57 MB
    float*  gates = (float*) (ws + 8192 + 2 * 1572864);             // 4 MB
    __bf16* hnb   = (__bf16*)(ws + 8192 + 2 * 1572864 + 4194304);   // 0.5 MB
    __bf16* WT    = (__bf16*)(ws + 8192 + 2 * 1572864 + 4194304 + 524288);

    sort_kernel<<<1, 1024, 0, stream>>>(ul, order, rbase);
    fused_pre_kernel<<<FB_TOT, 256, 0, stream>>>(
        hidden, io, ul, order, rbase, iW, ib, hW, hb, l1W, l1b, sW, sb,
        emb, Wih, Whh, lW, out, xcat, wcat, WT);
    xgemm_kernel<<<dim3(16, 16), 256, 0, stream>>>(xcat, wcat, gates);
    gate_kernel<<<B, 256, 0, stream>>>(gates, hidden, bih, bhh, out, hnb);
    out_mfma_kernel<<<NWG, 256, 0, stream>>>(hnb, WT, lb, out);
}

// Round 8
// 240.054 us; speedup vs baseline: 3.9804x; 1.0166x over previous
//
#include <hip/hip_runtime.h>
#include <math.h>

#define B 1024
#define M 15
#define H 256
#define E 256
#define V 30000
#define U 1000

typedef float  vf4    __attribute__((ext_vector_type(4)));
typedef __bf16 bf16x8 __attribute__((ext_vector_type(8)));
typedef float  f32x4  __attribute__((ext_vector_type(4)));

// output layout (flat f32 concat, reference return order)
#define O_OUT   0
#define O_HID   ((size_t)B*V)
#define O_EMB   (O_HID + (size_t)B*H)
#define O_GRU   (O_EMB + (size_t)B*E)
#define O_ATT   (O_GRU + (size_t)B*H)

#define GLDS(g, l) __builtin_amdgcn_global_load_lds( \
    (const __attribute__((address_space(1))) void*)(g), \
    (__attribute__((address_space(3))) void*)(l), 16, 0, 0)

union BF8 { __bf16 h[8]; bf16x8 v; };
union BF4 { __bf16 h[4]; unsigned long long u; };

// ------------- sort samples by user (counting sort, 1 block) + run starts -------------
__global__ __launch_bounds__(1024) void sort_kernel(
    const int* __restrict__ ul, int* __restrict__ order, int* __restrict__ rbase_g)
{
    __shared__ int cnt[1024];
    __shared__ int base[1024];
    const int tid = threadIdx.x;
    cnt[tid] = 0;
    __syncthreads();
    const int u = ul[tid];
    atomicAdd(&cnt[u], 1);
    __syncthreads();
    int c0 = cnt[tid];
    int v  = c0;
    for (int off = 1; off < 1024; off <<= 1) {
        int add = (tid >= off) ? cnt[tid - off] : 0;
        __syncthreads();
        v += add;
        cnt[tid] = v;
        __syncthreads();
    }
    base[tid]   = v - c0;
    rbase_g[tid] = v - c0;
    __syncthreads();
    int pos = atomicAdd(&base[u], 1);
    order[pos] = tid;
}

// =============== fused: attn (0..1023) | transpose (1024..1523) | wcat (1524..1779) ===============
#define FB_ATTN 1024
#define FB_TR   500
#define FB_WC   256
#define FB_TOT  (FB_ATTN + FB_TR + FB_WC)

__global__ __launch_bounds__(256, 3) void fused_pre_kernel(
    const float* __restrict__ hidden,       // (1,B,H)
    const float* __restrict__ inter_output, // (B,M,H)
    const int*   __restrict__ user_list,    // (B,)
    const int*   __restrict__ order,        // (B,)
    const int*   __restrict__ rbase,        // (1024,)
    const float* __restrict__ inter_W,      // (U,H,H)
    const float* __restrict__ inter_b,      // (U,H)
    const float* __restrict__ hidden_W,     // (U,H,H)
    const float* __restrict__ hidden_b,     // (U,H)
    const float* __restrict__ lt1_W,        // (U,2H,H)
    const float* __restrict__ lt1_b,        // (U,H)
    const float* __restrict__ scale_W,      // (U,H)
    const float* __restrict__ scale_b,      // (U,)
    const float* __restrict__ emb,          // (B,1,E)
    const float* __restrict__ Wih,          // (3H,2E)
    const float* __restrict__ Whh,          // (3H,H)
    const float* __restrict__ lin_W,        // (H,V)
    float* __restrict__ out,
    __bf16* __restrict__ xcat,              // (B,768)
    __bf16* __restrict__ wcat,              // (1024,768), gate-group-reordered
    __bf16* __restrict__ WT)                // (V,H)
{
    __shared__ __align__(16) char smem[34432];
    const int bid = blockIdx.x;
    const int tid = threadIdx.x;

    if (bid >= FB_ATTN + FB_TR) {
        // ---------------- wcat section (gate-group column order) ----------------
        // wcat2 row n holds orig row r = (n>>2) + 256*(n&3):
        //   c=0: r-sum (Wih|Whh), c=1: z-sum, c=2: gi_n (Wih|0), c=3: gh_n (0|Whh)
        const int wb   = bid - (FB_ATTN + FB_TR);
        const int wave = tid >> 6, lane = tid & 63;
        const int n    = wb * 4 + wave;
        const int r    = (n >> 2) + ((n & 3) << 8);
        #pragma unroll
        for (int i = 0; i < 3; ++i) {
            int k = i * 256 + lane * 4;
            vf4 v = {0.f, 0.f, 0.f, 0.f};
            if (r < 512) {
                v = (k < 512) ? *(const vf4*)&Wih[(size_t)r * 512 + k]
                              : *(const vf4*)&Whh[(size_t)r * 256 + (k - 512)];
            } else if (r < 768) {
                if (k < 512) v = *(const vf4*)&Wih[(size_t)r * 512 + k];
            } else {
                if (k >= 512) v = *(const vf4*)&Whh[(size_t)(r - 256) * 256 + (k - 512)];
            }
            BF4 p;
            p.h[0]=(__bf16)v[0]; p.h[1]=(__bf16)v[1]; p.h[2]=(__bf16)v[2]; p.h[3]=(__bf16)v[3];
            *(unsigned long long*)&wcat[(size_t)n * 768 + k] = p.u;
        }
        return;
    }

    if (bid >= FB_ATTN) {
        // ---------------- transpose section: lin_W -> WT ----------------
        const int t   = bid - FB_ATTN;
        const int v0  = (t % 125) * 240;
        const int k0  = (t / 125) * 64;
        const int lane = tid & 63, kq = tid >> 6;
        __bf16* T = (__bf16*)smem;            // 240*68 bf16 = 32640 B

        if (lane < 60) {
            #pragma unroll
            for (int i = 0; i < 4; ++i) {
                int kr = kq * 16 + i * 4;
                vf4 f0 = *(const vf4*)&lin_W[(size_t)(k0 + kr + 0) * V + v0 + lane * 4];
                vf4 f1 = *(const vf4*)&lin_W[(size_t)(k0 + kr + 1) * V + v0 + lane * 4];
                vf4 f2 = *(const vf4*)&lin_W[(size_t)(k0 + kr + 2) * V + v0 + lane * 4];
                vf4 f3 = *(const vf4*)&lin_W[(size_t)(k0 + kr + 3) * V + v0 + lane * 4];
                #pragma unroll
                for (int j = 0; j < 4; ++j) {
                    BF4 pk;
                    pk.h[0] = (__bf16)f0[j];
                    pk.h[1] = (__bf16)f1[j];
                    pk.h[2] = (__bf16)f2[j];
                    pk.h[3] = (__bf16)f3[j];
                    int v = lane * 4 + j;
                    *(unsigned long long*)&T[v * 68 + kr] = pk.u;
                }
            }
        }
        __syncthreads();
        for (int r = 0; r < 15; ++r) {
            int L = r * 256 + tid;
            int v = L >> 4, c = L & 15;
            *(unsigned long long*)&WT[(size_t)(v0 + v) * H + k0 + c * 4] =
                *(const unsigned long long*)&T[v * 68 + c * 4];
        }
        return;
    }

    // ---------------- attn section ----------------
    const int s   = ((bid & 7) << 7) + (bid >> 3);  // XCD chunk swizzle
    const int b0  = order[s];
    const int u   = user_list[b0];

    // cvt_xh for this block's sample (done by ALL 1024 blocks, head or not)
    {
        float ev = emb[(size_t)b0 * E + tid];
        float hv = hidden[(size_t)b0 * H + tid];
        xcat[(size_t)b0 * 768 + tid]       = (__bf16)ev;
        xcat[(size_t)b0 * 768 + 512 + tid] = (__bf16)hv;
        out[O_EMB + (size_t)b0 * E + tid]  = ev;
    }

    if ((s - rbase[u]) & 1) return;         // not a run head
    bool paired = false;
    int  b1 = b0;
    if (s + 1 < B) {
        int ob = order[s + 1];
        if (user_list[ob] == u) { paired = true; b1 = ob; }
    }

    const int lane = tid & 63;
    const int wave = tid >> 6;
    const int wn0  = wave * 64;

    __bf16* Abuf = (__bf16*)smem;                       // 32 KB
    __bf16* hta  = (__bf16*)(smem + 32768);             // 2*256 bf16 = 1 KB
    float*  red  = (float*)(smem + 32768 + 1024);       // 2*64 f32 = 512 B
    float*  e_lds= (float*)(smem + 32768 + 1024 + 512); // 2*16 f32 = 128 B

    // ---- phase 1: A = [io|0 ; 0|ht] for both samples ----
    {
        const int r    = tid >> 3;
        const int part = tid & 7;
        const int sm   = r >> 4;
        const int mr   = r & 15;
        const int bs   = sm ? b1 : b0;
        const bool zr  = (sm == 1) && !paired;
        #pragma unroll
        for (int it = 0; it < 8; ++it) {
            int c = part + it * 8;
            int k = c * 8;
            BF8 p;
            #pragma unroll
            for (int j = 0; j < 8; ++j) p.h[j] = (__bf16)0.f;
            if (!zr) {
                if (mr < 15 && k < 256) {
                    vf4 f0 = *(const vf4*)&inter_output[(size_t)bs * M * H + mr * H + k];
                    vf4 f1 = *(const vf4*)&inter_output[(size_t)bs * M * H + mr * H + k + 4];
                    p.h[0]=(__bf16)f0[0]; p.h[1]=(__bf16)f0[1]; p.h[2]=(__bf16)f0[2]; p.h[3]=(__bf16)f0[3];
                    p.h[4]=(__bf16)f1[0]; p.h[5]=(__bf16)f1[1]; p.h[6]=(__bf16)f1[2]; p.h[7]=(__bf16)f1[3];
                } else if (mr == 15 && k >= 256) {
                    vf4 f0 = *(const vf4*)&hidden[(size_t)bs * H + (k - 256)];
                    vf4 f1 = *(const vf4*)&hidden[(size_t)bs * H + (k - 256) + 4];
                    p.h[0]=(__bf16)f0[0]; p.h[1]=(__bf16)f0[1]; p.h[2]=(__bf16)f0[2]; p.h[3]=(__bf16)f0[3];
                    p.h[4]=(__bf16)f1[0]; p.h[5]=(__bf16)f1[1]; p.h[6]=(__bf16)f1[2]; p.h[7]=(__bf16)f1[3];
                }
            }
            *(bf16x8*)&Abuf[r * 512 + (c ^ (r & 7)) * 8] = p.v;
        }
    }
    __syncthreads();

    const float* Wi_base  = inter_W  + (size_t)u * H * H;
    const float* Wh_base  = hidden_W + (size_t)u * H * H;
    const float* lt1_base = lt1_W    + (size_t)u * 2 * H * H;

    const int ocol = wn0 + (lane & 15);
    const int krow = (lane >> 4) * 8;

    f32x4 acc1[2][4];
    #pragma unroll
    for (int mf = 0; mf < 2; ++mf)
        #pragma unroll
        for (int nf = 0; nf < 4; ++nf) { f32x4 z = {0.f,0.f,0.f,0.f}; acc1[mf][nf] = z; }

    // ================= GEMM 1 =================
    #pragma unroll 2
    for (int ks = 0; ks < 16; ++ks) {
        const float* Bp = ((ks < 8) ? (Wi_base + (size_t)(ks * 32) * H)
                                    : (Wh_base + (size_t)((ks - 8) * 32) * H))
                          + (size_t)krow * H + ocol;
        float t[4][8];
        #pragma unroll
        for (int j = 0; j < 8; ++j)
            #pragma unroll
            for (int nf = 0; nf < 4; ++nf)
                t[nf][j] = Bp[(size_t)j * H + nf * 16];
        bf16x8 bfr[4];
        #pragma unroll
        for (int nf = 0; nf < 4; ++nf) {
            BF8 pk;
            #pragma unroll
            for (int j = 0; j < 8; ++j) pk.h[j] = (__bf16)t[nf][j];
            bfr[nf] = pk.v;
        }
        int sca = ((ks * 4 + (lane >> 4)) ^ (lane & 7)) * 8;
        bf16x8 a0 = *(const bf16x8*)&Abuf[(lane & 15) * 512 + sca];
        #pragma unroll
        for (int nf = 0; nf < 4; ++nf)
            acc1[0][nf] = __builtin_amdgcn_mfma_f32_16x16x32_bf16(a0, bfr[nf], acc1[0][nf], 0, 0, 0);
        if (paired) {
            bf16x8 a1 = *(const bf16x8*)&Abuf[(16 + (lane & 15)) * 512 + sca];
            #pragma unroll
            for (int nf = 0; nf < 4; ++nf)
                acc1[1][nf] = __builtin_amdgcn_mfma_f32_16x16x32_bf16(a1, bfr[nf], acc1[1][nf], 0, 0, 0);
        }
    }
    __syncthreads();

    // ---- extract ht_a + hidden_b ; io_a+bi into Abuf k>=256 ----
    if ((lane >> 4) == 3) {
        #pragma unroll
        for (int nf = 0; nf < 4; ++nf) {
            int o = wn0 + nf * 16 + (lane & 15);
            float hb = hidden_b[(size_t)u * H + o];
            hta[o]       = (__bf16)(acc1[0][nf][3] + hb);
            hta[256 + o] = (__bf16)(acc1[1][nf][3] + hb);
        }
    }
    #pragma unroll
    for (int mf = 0; mf < 2; ++mf) {
        #pragma unroll
        for (int nf = 0; nf < 4; ++nf) {
            int o  = wn0 + nf * 16 + (lane & 15);
            float bi = inter_b[(size_t)u * H + o];
            int k  = 256 + o;
            #pragma unroll
            for (int j = 0; j < 4; ++j) {
                int r  = mf * 16 + (lane >> 4) * 4 + j;
                Abuf[r * 512 + ((k >> 3) ^ (r & 7)) * 8 + (k & 7)] = (__bf16)(acc1[mf][nf][j] + bi);
            }
        }
    }
    __syncthreads();

    // ---- phase 2 low-K: hta broadcast ----
    {
        const int r    = tid >> 3;
        const int part = tid & 7;
        const int sm   = r >> 4;
        #pragma unroll
        for (int it = 0; it < 4; ++it) {
            int c = part + it * 8;
            bf16x8 hv = *(const bf16x8*)&hta[sm * 256 + c * 8];
            *(bf16x8*)&Abuf[r * 512 + (c ^ (r & 7)) * 8] = hv;
        }
    }
    __syncthreads();

    f32x4 acc2[2][4];
    #pragma unroll
    for (int mf = 0; mf < 2; ++mf)
        #pragma unroll
        for (int nf = 0; nf < 4; ++nf) { f32x4 z = {0.f,0.f,0.f,0.f}; acc2[mf][nf] = z; }

    // ================= GEMM 2 =================
    #pragma unroll 2
    for (int ks = 0; ks < 16; ++ks) {
        const float* Bp = lt1_base + (size_t)(ks * 32) * H + (size_t)krow * H + ocol;
        float t[4][8];
        #pragma unroll
        for (int j = 0; j < 8; ++j)
            #pragma unroll
            for (int nf = 0; nf < 4; ++nf)
                t[nf][j] = Bp[(size_t)j * H + nf * 16];
        bf16x8 bfr[4];
        #pragma unroll
        for (int nf = 0; nf < 4; ++nf) {
            BF8 pk;
            #pragma unroll
            for (int j = 0; j < 8; ++j) pk.h[j] = (__bf16)t[nf][j];
            bfr[nf] = pk.v;
        }
        int sca = ((ks * 4 + (lane >> 4)) ^ (lane & 7)) * 8;
        bf16x8 a0 = *(const bf16x8*)&Abuf[(lane & 15) * 512 + sca];
        #pragma unroll
        for (int nf = 0; nf < 4; ++nf)
            acc2[0][nf] = __builtin_amdgcn_mfma_f32_16x16x32_bf16(a0, bfr[nf], acc2[0][nf], 0, 0, 0);
        if (paired) {
            bf16x8 a1 = *(const bf16x8*)&Abuf[(16 + (lane & 15)) * 512 + sca];
            #pragma unroll
            for (int nf = 0; nf < 4; ++nf)
                acc2[1][nf] = __builtin_amdgcn_mfma_f32_16x16x32_bf16(a1, bfr[nf], acc2[1][nf], 0, 0, 0);
        }
    }

    // ---- energies ----
    float p0[4] = {0.f,0.f,0.f,0.f};
    float p1[4] = {0.f,0.f,0.f,0.f};
    #pragma unroll
    for (int nf = 0; nf < 4; ++nf) {
        int o = wn0 + nf * 16 + (lane & 15);
        float l1b = lt1_b[(size_t)u * H + o];
        float sw  = scale_W[(size_t)u * H + o];
        #pragma unroll
        for (int j = 0; j < 4; ++j)
            p0[j] += tanhf(acc2[0][nf][j] + l1b) * sw;
        if (paired)
            #pragma unroll
            for (int j = 0; j < 4; ++j)
                p1[j] += tanhf(acc2[1][nf][j] + l1b) * sw;
    }
    #pragma unroll
    for (int j = 0; j < 4; ++j) {
        float v = p0[j];
        v += __shfl_xor(v, 1, 64); v += __shfl_xor(v, 2, 64);
        v += __shfl_xor(v, 4, 64); v += __shfl_xor(v, 8, 64);
        if ((lane & 15) == 0) red[0 * 64 + wave * 16 + (lane >> 4) * 4 + j] = v;
        float w = p1[j];
        w += __shfl_xor(w, 1, 64); w += __shfl_xor(w, 2, 64);
        w += __shfl_xor(w, 4, 64); w += __shfl_xor(w, 8, 64);
        if ((lane & 15) == 0) red[1 * 64 + wave * 16 + (lane >> 4) * 4 + j] = w;
    }
    __syncthreads();
    if (tid < 32) {
        int sm = tid >> 4, mm = tid & 15;
        e_lds[sm * 16 + mm] = red[sm * 64 + mm] + red[sm * 64 + 16 + mm]
                            + red[sm * 64 + 32 + mm] + red[sm * 64 + 48 + mm]
                            + scale_b[u];
    }
    __syncthreads();

    const int nsm = paired ? 2 : 1;
    for (int sm = 0; sm < nsm; ++sm) {
        const int bs = sm ? b1 : b0;
        float mx = -1e30f;
        #pragma unroll
        for (int m = 0; m < M; ++m) mx = fmaxf(mx, e_lds[sm * 16 + m]);
        float sum = 0.f;
        float aw[M];
        #pragma unroll
        for (int m = 0; m < M; ++m) { aw[m] = expf(e_lds[sm * 16 + m] - mx); sum += aw[m]; }
        float inv = 1.f / sum;
        if (tid < M) out[O_ATT + (size_t)bs * M + tid] = aw[tid] * inv;
        float ctx = 0.f;
        #pragma unroll
        for (int m = 0; m < M; ++m)
            ctx += aw[m] * inter_output[(size_t)bs * M * H + m * H + tid];
        xcat[(size_t)bs * 768 + 256 + tid] = (__bf16)(ctx * inv);
    }
}

// ---- fused GRU GEMM + gate: gates tile in LDS, hn written directly ----
// wcat is gate-group-reordered: col n = 4*j + c. 64x64 tile => whole groups.
__global__ __launch_bounds__(256) void xgemm_gate_kernel(
    const __bf16* __restrict__ xcat, const __bf16* __restrict__ wcat,
    const float* __restrict__ hidden,
    const float* __restrict__ bih, const float* __restrict__ bhh,
    float* __restrict__ out, __bf16* __restrict__ hnb)
{
    const int n0   = blockIdx.x * 64;
    const int m0   = blockIdx.y * 64;
    const int tid  = threadIdx.x;
    const int wave = tid >> 6, lane = tid & 63;
    const int wm   = wave >> 1, wn = wave & 1;

    __shared__ __align__(16) __bf16 Al[64 * 128];
    __shared__ __align__(16) __bf16 Bl[64 * 128];
    __shared__ __align__(16) float  Cs[64 * 68];   // padded stride 68 (16B-aligned rows)

    f32x4 acc[2][2];
    #pragma unroll
    for (int mf = 0; mf < 2; ++mf)
        #pragma unroll
        for (int nf = 0; nf < 2; ++nf) { f32x4 z = {0.f,0.f,0.f,0.f}; acc[mf][nf] = z; }

    for (int ks = 0; ks < 6; ++ks) {
        #pragma unroll
        for (int r = 0; r < 4; ++r) {
            int L = r * 256 + tid;
            int row = L >> 4, c = L & 15;
            int sc = c ^ (row & 7);
            GLDS(xcat + (size_t)(m0 + row) * 768 + ks * 128 + sc * 8, &Al[(size_t)L * 8]);
        }
        #pragma unroll
        for (int r = 0; r < 4; ++r) {
            int L = r * 256 + tid;
            int row = L >> 4, c = L & 15;
            int sc = c ^ (row & 7);
            GLDS(wcat + (size_t)(n0 + row) * 768 + ks * 128 + sc * 8, &Bl[(size_t)L * 8]);
        }
        __syncthreads();
        #pragma unroll
        for (int kk = 0; kk < 4; ++kk) {
            bf16x8 af[2];
            #pragma unroll
            for (int mf = 0; mf < 2; ++mf) {
                int row = wm * 32 + mf * 16 + (lane & 15);
                int c   = kk * 4 + (lane >> 4);
                af[mf] = *(const bf16x8*)&Al[row * 128 + (c ^ (row & 7)) * 8];
            }
            bf16x8 bfr[2];
            #pragma unroll
            for (int nf = 0; nf < 2; ++nf) {
                int col = wn * 32 + nf * 16 + (lane & 15);
                int c   = kk * 4 + (lane >> 4);
                bfr[nf] = *(const bf16x8*)&Bl[col * 128 + (c ^ (col & 7)) * 8];
            }
            #pragma unroll
            for (int mf = 0; mf < 2; ++mf)
                #pragma unroll
                for (int nf = 0; nf < 2; ++nf)
                    acc[mf][nf] = __builtin_amdgcn_mfma_f32_16x16x32_bf16(
                        af[mf], bfr[nf], acc[mf][nf], 0, 0, 0);
        }
        __syncthreads();
    }

    // stage gates tile into LDS
    #pragma unroll
    for (int nf = 0; nf < 2; ++nf) {
        int lc = wn * 32 + nf * 16 + (lane & 15);
        #pragma unroll
        for (int mf = 0; mf < 2; ++mf) {
            int lr = wm * 32 + mf * 16 + (lane >> 4) * 4;
            f32x4 a = acc[mf][nf];
            #pragma unroll
            for (int j = 0; j < 4; ++j)
                Cs[(lr + j) * 68 + lc] = a[j];
        }
    }
    __syncthreads();

    // gate epilogue: 1024 items = 64 rows x 16 groups; 4 per thread
    #pragma unroll
    for (int k = 0; k < 4; ++k) {
        int idx = k * 256 + tid;
        int r = idx >> 4, g = idx & 15;
        f32x4 c = *(const f32x4*)&Cs[r * 68 + g * 4];
        int b = m0 + r;
        int j = (n0 >> 2) + g;
        float rs  = c[0] + bih[j]       + bhh[j];
        float zs  = c[1] + bih[256 + j] + bhh[256 + j];
        float gin = c[2] + bih[512 + j];
        float ghn = c[3] + bhh[512 + j];
        float h   = hidden[(size_t)b * H + j];
        float r_  = 1.f / (1.f + expf(-rs));
        float z_  = 1.f / (1.f + expf(-zs));
        float n_  = tanhf(gin + r_ * ghn);
        float hn  = (1.f - z_) * n_ + z_ * h;
        out[O_HID + (size_t)b * H + j] = hn;
        out[O_GRU + (size_t)b * H + j] = hn;
        hnb[(size_t)b * H + j] = (__bf16)hn;
    }
}

// -------- Stage C (MFMA): out = hnew(bf16) @ WT^T + lin_b; LDS-staged coalesced C-write --------
#define GBM 64
#define GBN 256
#define GBK 64
#define NTM 16
#define NWG ((117 + 1) * NTM)
__global__ __launch_bounds__(256) void out_mfma_kernel(
    const __bf16* __restrict__ hnb,
    const __bf16* __restrict__ WT,
    const float* __restrict__ lin_b,
    float* __restrict__ out)
{
    const int L  = blockIdx.x;
    const int s  = (L & 7) * (NWG / 8) + (L >> 3);
    const int nt = s >> 4, mt = s & 15;
    const int n0 = nt * GBN;
    const int m0 = mt * GBM;
    const int tid  = threadIdx.x;
    const int wave = tid >> 6, lane = tid & 63;

    __shared__ __align__(16) char gsm[GBM * H * 2 + GBN * GBK * 2];  // 64 KB
    __bf16* Al = (__bf16*)gsm;
    __bf16* Bl = (__bf16*)(gsm + GBM * H * 2);

    #pragma unroll
    for (int r = 0; r < 8; ++r) {
        int Li = r * 256 + tid;
        int m = Li >> 5;
        int c = Li & 31;
        int sc = c ^ (m & 7);
        GLDS(hnb + (size_t)(m0 + m) * H + sc * 8, &Al[(size_t)Li * 8]);
    }

    f32x4 acc[4][4];
    #pragma unroll
    for (int mf = 0; mf < 4; ++mf)
        #pragma unroll
        for (int nf = 0; nf < 4; ++nf) {
            f32x4 z = {0.f, 0.f, 0.f, 0.f};
            acc[mf][nf] = z;
        }

    const int wn0 = wave * 64;

    for (int ks = 0; ks < 4; ++ks) {
        #pragma unroll
        for (int r = 0; r < 8; ++r) {
            int Li = r * 256 + tid;
            int n = Li >> 3;
            int c = Li & 7;
            int sc = c ^ (n & 7);
            int nn = n0 + n; if (nn >= V) nn = V - 1;
            GLDS(WT + (size_t)nn * H + ks * GBK + sc * 8, &Bl[(size_t)Li * 8]);
        }
        __syncthreads();

        #pragma unroll
        for (int kk = 0; kk < 2; ++kk) {
            bf16x8 af[4];
            #pragma unroll
            for (int mf = 0; mf < 4; ++mf) {
                int row = mf * 16 + (lane & 15);
                int c   = ks * 8 + kk * 4 + (lane >> 4);
                int cs  = c ^ (row & 7);
                af[mf] = *(const bf16x8*)&Al[row * H + cs * 8];
            }
            bf16x8 bfr[4];
            #pragma unroll
            for (int nf = 0; nf < 4; ++nf) {
                int col = wn0 + nf * 16 + (lane & 15);
                int c   = kk * 4 + (lane >> 4);
                int cs  = c ^ (col & 7);
                bfr[nf] = *(const bf16x8*)&Bl[col * GBK + cs * 8];
            }
            #pragma unroll
            for (int mf = 0; mf < 4; ++mf)
                #pragma unroll
                for (int nf = 0; nf < 4; ++nf)
                    acc[mf][nf] = __builtin_amdgcn_mfma_f32_16x16x32_bf16(
                        af[mf], bfr[nf], acc[mf][nf], 0, 0, 0);
        }
        __syncthreads();
    }

    // ---- epilogue: stage C tile in LDS (reusing gsm), write full-wave coalesced rows ----
    float* Cs = (float*)gsm;   // 64 x 256 f32 = 64 KB exactly
    #pragma unroll
    for (int nf = 0; nf < 4; ++nf) {
        int col = wn0 + nf * 16 + (lane & 15);
        #pragma unroll
        for (int mf = 0; mf < 4; ++mf) {
            #pragma unroll
            for (int j = 0; j < 4; ++j)
                Cs[(mf * 16 + (lane >> 4) * 4 + j) * 256 + col] = acc[mf][nf][j];
        }
    }
    __syncthreads();

    const bool nok = (n0 + lane * 4 + 3 < V);
    f32x4 lb = {0.f, 0.f, 0.f, 0.f};
    if (nok) lb = *(const f32x4*)&lin_b[n0 + lane * 4];
    for (int r = wave; r < 64; r += 4) {
        f32x4 c = *(const f32x4*)&Cs[r * 256 + lane * 4];
        c += lb;
        if (nok)
            *(f32x4*)&out[(size_t)(m0 + r) * V + n0 + lane * 4] = c;
    }
}

extern "C" void kernel_launch(void* const* d_in, const int* in_sizes, int n_in,
                              void* d_out, int out_size, void* d_ws, size_t ws_size,
                              hipStream_t stream) {
    const float* emb    = (const float*)d_in[1];
    const float* hidden = (const float*)d_in[2];
    const float* io     = (const float*)d_in[3];
    const int*   ul     = (const int*)  d_in[4];
    const float* iW     = (const float*)d_in[5];
    const float* ib     = (const float*)d_in[6];
    const float* hW     = (const float*)d_in[7];
    const float* hb     = (const float*)d_in[8];
    const float* l1W    = (const float*)d_in[9];
    const float* l1b    = (const float*)d_in[10];
    const float* sW     = (const float*)d_in[11];
    const float* sb     = (const float*)d_in[12];
    const float* Wih    = (const float*)d_in[13];
    const float* Whh    = (const float*)d_in[14];
    const float* bih    = (const float*)d_in[15];
    const float* bhh    = (const float*)d_in[16];
    const float* lW     = (const float*)d_in[17];
    const float* lb     = (const float*)d_in[18];

    float* out = (float*)d_out;
    char* ws = (char*)d_ws;
    int*    order = (int*)ws;                                       // 4 KB
    int*    rbase = (int*)(ws + 4096);                              // 4 KB
    __bf16* xcat  = (__bf16*)(ws + 8192);                           // 1.57 MB
    __bf16* wcat  = (__bf16*)(ws + 8192 + 1572864);                 // 1.57 MB
    __bf16* hnb   = (__bf16*)(ws + 8192 + 2 * 1572864);             // 0.5 MB
    __bf16* WT    = (__bf16*)(ws + 8192 + 2 * 1572864 + 524288);

    sort_kernel<<<1, 1024, 0, stream>>>(ul, order, rbase);
    fused_pre_kernel<<<FB_TOT, 256, 0, stream>>>(
        hidden, io, ul, order, rbase, iW, ib, hW, hb, l1W, l1b, sW, sb,
        emb, Wih, Whh, lW, out, xcat, wcat, WT);
    xgemm_gate_kernel<<<dim3(16, 16), 256, 0, stream>>>(xcat, wcat, hidden, bih, bhh, out, hnb);
    out_mfma_kernel<<<NWG, 256, 0, stream>>>(hnb, WT, lb, out);
}

// Round 9
// 232.521 us; speedup vs baseline: 4.1094x; 1.0324x over previous
//
#include <hip/hip_runtime.h>
#include <math.h>

#define B 1024
#define M 15
#define H 256
#define E 256
#define V 30000
#define U 1000

typedef float  vf4    __attribute__((ext_vector_type(4)));
typedef __bf16 bf16x8 __attribute__((ext_vector_type(8)));
typedef float  f32x4  __attribute__((ext_vector_type(4)));

// output layout (flat f32 concat, reference return order)
#define O_OUT   0
#define O_HID   ((size_t)B*V)
#define O_EMB   (O_HID + (size_t)B*H)
#define O_GRU   (O_EMB + (size_t)B*E)
#define O_ATT   (O_GRU + (size_t)B*H)

#define GLDS(g, l) __builtin_amdgcn_global_load_lds( \
    (const __attribute__((address_space(1))) void*)(g), \
    (__attribute__((address_space(3))) void*)(l), 16, 0, 0)

union BF8 { __bf16 h[8]; bf16x8 v; };
union BF4 { __bf16 h[4]; unsigned long long u; };

// ------------- sort samples by user (counting sort, 1 block) + run starts -------------
__global__ __launch_bounds__(1024) void sort_kernel(
    const int* __restrict__ ul, int* __restrict__ order, int* __restrict__ rbase_g)
{
    __shared__ int cnt[1024];
    __shared__ int base[1024];
    const int tid = threadIdx.x;
    cnt[tid] = 0;
    __syncthreads();
    const int u = ul[tid];
    atomicAdd(&cnt[u], 1);
    __syncthreads();
    int c0 = cnt[tid];
    int v  = c0;
    for (int off = 1; off < 1024; off <<= 1) {
        int add = (tid >= off) ? cnt[tid - off] : 0;
        __syncthreads();
        v += add;
        cnt[tid] = v;
        __syncthreads();
    }
    base[tid]   = v - c0;
    rbase_g[tid] = v - c0;
    __syncthreads();
    int pos = atomicAdd(&base[u], 1);
    order[pos] = tid;
}

// =============== fused: attn (0..1023) | transpose (1024..1523) | wcat (1524..1779) ===============
#define FB_ATTN 1024
#define FB_TR   500
#define FB_WC   256
#define FB_TOT  (FB_ATTN + FB_TR + FB_WC)

__global__ __launch_bounds__(256, 3) void fused_pre_kernel(
    const float* __restrict__ hidden,       // (1,B,H)
    const float* __restrict__ inter_output, // (B,M,H)
    const int*   __restrict__ user_list,    // (B,)
    const int*   __restrict__ order,        // (B,)
    const int*   __restrict__ rbase,        // (1024,)
    const float* __restrict__ inter_W,      // (U,H,H)
    const float* __restrict__ inter_b,      // (U,H)
    const float* __restrict__ hidden_W,     // (U,H,H)
    const float* __restrict__ hidden_b,     // (U,H)
    const float* __restrict__ lt1_W,        // (U,2H,H)
    const float* __restrict__ lt1_b,        // (U,H)
    const float* __restrict__ scale_W,      // (U,H)
    const float* __restrict__ scale_b,      // (U,)
    const float* __restrict__ emb,          // (B,1,E)
    const float* __restrict__ Wih,          // (3H,2E)
    const float* __restrict__ Whh,          // (3H,H)
    const float* __restrict__ lin_W,        // (H,V)
    float* __restrict__ out,
    __bf16* __restrict__ xcat,              // (B,768)
    __bf16* __restrict__ wcat,              // (1024,768), gate-group-reordered
    __bf16* __restrict__ WT)                // (V,H)
{
    __shared__ __align__(16) char smem[34432];
    const int bid = blockIdx.x;
    const int tid = threadIdx.x;

    if (bid >= FB_ATTN + FB_TR) {
        // ---------------- wcat section (gate-group column order) ----------------
        const int wb   = bid - (FB_ATTN + FB_TR);
        const int wave = tid >> 6, lane = tid & 63;
        const int n    = wb * 4 + wave;
        const int r    = (n >> 2) + ((n & 3) << 8);
        #pragma unroll
        for (int i = 0; i < 3; ++i) {
            int k = i * 256 + lane * 4;
            vf4 v = {0.f, 0.f, 0.f, 0.f};
            if (r < 512) {
                v = (k < 512) ? *(const vf4*)&Wih[(size_t)r * 512 + k]
                              : *(const vf4*)&Whh[(size_t)r * 256 + (k - 512)];
            } else if (r < 768) {
                if (k < 512) v = *(const vf4*)&Wih[(size_t)r * 512 + k];
            } else {
                if (k >= 512) v = *(const vf4*)&Whh[(size_t)(r - 256) * 256 + (k - 512)];
            }
            BF4 p;
            p.h[0]=(__bf16)v[0]; p.h[1]=(__bf16)v[1]; p.h[2]=(__bf16)v[2]; p.h[3]=(__bf16)v[3];
            *(unsigned long long*)&wcat[(size_t)n * 768 + k] = p.u;
        }
        return;
    }

    if (bid >= FB_ATTN) {
        // ---------------- transpose section: lin_W -> WT ----------------
        const int t   = bid - FB_ATTN;
        const int v0  = (t % 125) * 240;
        const int k0  = (t / 125) * 64;
        const int lane = tid & 63, kq = tid >> 6;
        __bf16* T = (__bf16*)smem;            // 240*68 bf16 = 32640 B

        if (lane < 60) {
            #pragma unroll
            for (int i = 0; i < 4; ++i) {
                int kr = kq * 16 + i * 4;
                vf4 f0 = *(const vf4*)&lin_W[(size_t)(k0 + kr + 0) * V + v0 + lane * 4];
                vf4 f1 = *(const vf4*)&lin_W[(size_t)(k0 + kr + 1) * V + v0 + lane * 4];
                vf4 f2 = *(const vf4*)&lin_W[(size_t)(k0 + kr + 2) * V + v0 + lane * 4];
                vf4 f3 = *(const vf4*)&lin_W[(size_t)(k0 + kr + 3) * V + v0 + lane * 4];
                #pragma unroll
                for (int j = 0; j < 4; ++j) {
                    BF4 pk;
                    pk.h[0] = (__bf16)f0[j];
                    pk.h[1] = (__bf16)f1[j];
                    pk.h[2] = (__bf16)f2[j];
                    pk.h[3] = (__bf16)f3[j];
                    int v = lane * 4 + j;
                    *(unsigned long long*)&T[v * 68 + kr] = pk.u;
                }
            }
        }
        __syncthreads();
        for (int r = 0; r < 15; ++r) {
            int L = r * 256 + tid;
            int v = L >> 4, c = L & 15;
            __builtin_nontemporal_store(
                *(const unsigned long long*)&T[v * 68 + c * 4],
                (unsigned long long*)&WT[(size_t)(v0 + v) * H + k0 + c * 4]);
        }
        return;
    }

    // ---------------- attn section ----------------
    const int s   = ((bid & 7) << 7) + (bid >> 3);  // XCD chunk swizzle
    const int b0  = order[s];
    const int u   = user_list[b0];

    // cvt_xh for this block's sample (done by ALL 1024 blocks, head or not)
    {
        float ev = emb[(size_t)b0 * E + tid];
        float hv = hidden[(size_t)b0 * H + tid];
        xcat[(size_t)b0 * 768 + tid]       = (__bf16)ev;
        xcat[(size_t)b0 * 768 + 512 + tid] = (__bf16)hv;
        __builtin_nontemporal_store(ev, &out[O_EMB + (size_t)b0 * E + tid]);
    }

    if ((s - rbase[u]) & 1) return;         // not a run head
    bool paired = false;
    int  b1 = b0;
    if (s + 1 < B) {
        int ob = order[s + 1];
        if (user_list[ob] == u) { paired = true; b1 = ob; }
    }

    const int lane = tid & 63;
    const int wave = tid >> 6;
    const int wn0  = wave * 64;

    __bf16* Abuf = (__bf16*)smem;                       // 32 KB
    __bf16* hta  = (__bf16*)(smem + 32768);             // 2*256 bf16 = 1 KB
    float*  red  = (float*)(smem + 32768 + 1024);       // 2*64 f32 = 512 B
    float*  e_lds= (float*)(smem + 32768 + 1024 + 512); // 2*16 f32 = 128 B

    // ---- phase 1: A = [io|0 ; 0|ht] for both samples ----
    {
        const int r    = tid >> 3;
        const int part = tid & 7;
        const int sm   = r >> 4;
        const int mr   = r & 15;
        const int bs   = sm ? b1 : b0;
        const bool zr  = (sm == 1) && !paired;
        #pragma unroll
        for (int it = 0; it < 8; ++it) {
            int c = part + it * 8;
            int k = c * 8;
            BF8 p;
            #pragma unroll
            for (int j = 0; j < 8; ++j) p.h[j] = (__bf16)0.f;
            if (!zr) {
                if (mr < 15 && k < 256) {
                    vf4 f0 = *(const vf4*)&inter_output[(size_t)bs * M * H + mr * H + k];
                    vf4 f1 = *(const vf4*)&inter_output[(size_t)bs * M * H + mr * H + k + 4];
                    p.h[0]=(__bf16)f0[0]; p.h[1]=(__bf16)f0[1]; p.h[2]=(__bf16)f0[2]; p.h[3]=(__bf16)f0[3];
                    p.h[4]=(__bf16)f1[0]; p.h[5]=(__bf16)f1[1]; p.h[6]=(__bf16)f1[2]; p.h[7]=(__bf16)f1[3];
                } else if (mr == 15 && k >= 256) {
                    vf4 f0 = *(const vf4*)&hidden[(size_t)bs * H + (k - 256)];
                    vf4 f1 = *(const vf4*)&hidden[(size_t)bs * H + (k - 256) + 4];
                    p.h[0]=(__bf16)f0[0]; p.h[1]=(__bf16)f0[1]; p.h[2]=(__bf16)f0[2]; p.h[3]=(__bf16)f0[3];
                    p.h[4]=(__bf16)f1[0]; p.h[5]=(__bf16)f1[1]; p.h[6]=(__bf16)f1[2]; p.h[7]=(__bf16)f1[3];
                }
            }
            *(bf16x8*)&Abuf[r * 512 + (c ^ (r & 7)) * 8] = p.v;
        }
    }
    __syncthreads();

    const float* Wi_base  = inter_W  + (size_t)u * H * H;
    const float* Wh_base  = hidden_W + (size_t)u * H * H;
    const float* lt1_base = lt1_W    + (size_t)u * 2 * H * H;

    const int ocol = wn0 + (lane & 15);
    const int krow = (lane >> 4) * 8;

    f32x4 acc1[2][4];
    #pragma unroll
    for (int mf = 0; mf < 2; ++mf)
        #pragma unroll
        for (int nf = 0; nf < 4; ++nf) { f32x4 z = {0.f,0.f,0.f,0.f}; acc1[mf][nf] = z; }

    // ================= GEMM 1 =================
    #pragma unroll 2
    for (int ks = 0; ks < 16; ++ks) {
        const float* Bp = ((ks < 8) ? (Wi_base + (size_t)(ks * 32) * H)
                                    : (Wh_base + (size_t)((ks - 8) * 32) * H))
                          + (size_t)krow * H + ocol;
        float t[4][8];
        #pragma unroll
        for (int j = 0; j < 8; ++j)
            #pragma unroll
            for (int nf = 0; nf < 4; ++nf)
                t[nf][j] = Bp[(size_t)j * H + nf * 16];
        bf16x8 bfr[4];
        #pragma unroll
        for (int nf = 0; nf < 4; ++nf) {
            BF8 pk;
            #pragma unroll
            for (int j = 0; j < 8; ++j) pk.h[j] = (__bf16)t[nf][j];
            bfr[nf] = pk.v;
        }
        int sca = ((ks * 4 + (lane >> 4)) ^ (lane & 7)) * 8;
        bf16x8 a0 = *(const bf16x8*)&Abuf[(lane & 15) * 512 + sca];
        #pragma unroll
        for (int nf = 0; nf < 4; ++nf)
            acc1[0][nf] = __builtin_amdgcn_mfma_f32_16x16x32_bf16(a0, bfr[nf], acc1[0][nf], 0, 0, 0);
        if (paired) {
            bf16x8 a1 = *(const bf16x8*)&Abuf[(16 + (lane & 15)) * 512 + sca];
            #pragma unroll
            for (int nf = 0; nf < 4; ++nf)
                acc1[1][nf] = __builtin_amdgcn_mfma_f32_16x16x32_bf16(a1, bfr[nf], acc1[1][nf], 0, 0, 0);
        }
    }
    __syncthreads();

    // ---- extract ht_a + hidden_b ; io_a+bi into Abuf k>=256 ----
    if ((lane >> 4) == 3) {
        #pragma unroll
        for (int nf = 0; nf < 4; ++nf) {
            int o = wn0 + nf * 16 + (lane & 15);
            float hb = hidden_b[(size_t)u * H + o];
            hta[o]       = (__bf16)(acc1[0][nf][3] + hb);
            hta[256 + o] = (__bf16)(acc1[1][nf][3] + hb);
        }
    }
    #pragma unroll
    for (int mf = 0; mf < 2; ++mf) {
        #pragma unroll
        for (int nf = 0; nf < 4; ++nf) {
            int o  = wn0 + nf * 16 + (lane & 15);
            float bi = inter_b[(size_t)u * H + o];
            int k  = 256 + o;
            #pragma unroll
            for (int j = 0; j < 4; ++j) {
                int r  = mf * 16 + (lane >> 4) * 4 + j;
                Abuf[r * 512 + ((k >> 3) ^ (r & 7)) * 8 + (k & 7)] = (__bf16)(acc1[mf][nf][j] + bi);
            }
        }
    }
    __syncthreads();

    // ---- phase 2 low-K: hta broadcast ----
    {
        const int r    = tid >> 3;
        const int part = tid & 7;
        const int sm   = r >> 4;
        #pragma unroll
        for (int it = 0; it < 4; ++it) {
            int c = part + it * 8;
            bf16x8 hv = *(const bf16x8*)&hta[sm * 256 + c * 8];
            *(bf16x8*)&Abuf[r * 512 + (c ^ (r & 7)) * 8] = hv;
        }
    }
    __syncthreads();

    f32x4 acc2[2][4];
    #pragma unroll
    for (int mf = 0; mf < 2; ++mf)
        #pragma unroll
        for (int nf = 0; nf < 4; ++nf) { f32x4 z = {0.f,0.f,0.f,0.f}; acc2[mf][nf] = z; }

    // ================= GEMM 2 =================
    #pragma unroll 2
    for (int ks = 0; ks < 16; ++ks) {
        const float* Bp = lt1_base + (size_t)(ks * 32) * H + (size_t)krow * H + ocol;
        float t[4][8];
        #pragma unroll
        for (int j = 0; j < 8; ++j)
            #pragma unroll
            for (int nf = 0; nf < 4; ++nf)
                t[nf][j] = Bp[(size_t)j * H + nf * 16];
        bf16x8 bfr[4];
        #pragma unroll
        for (int nf = 0; nf < 4; ++nf) {
            BF8 pk;
            #pragma unroll
            for (int j = 0; j < 8; ++j) pk.h[j] = (__bf16)t[nf][j];
            bfr[nf] = pk.v;
        }
        int sca = ((ks * 4 + (lane >> 4)) ^ (lane & 7)) * 8;
        bf16x8 a0 = *(const bf16x8*)&Abuf[(lane & 15) * 512 + sca];
        #pragma unroll
        for (int nf = 0; nf < 4; ++nf)
            acc2[0][nf] = __builtin_amdgcn_mfma_f32_16x16x32_bf16(a0, bfr[nf], acc2[0][nf], 0, 0, 0);
        if (paired) {
            bf16x8 a1 = *(const bf16x8*)&Abuf[(16 + (lane & 15)) * 512 + sca];
            #pragma unroll
            for (int nf = 0; nf < 4; ++nf)
                acc2[1][nf] = __builtin_amdgcn_mfma_f32_16x16x32_bf16(a1, bfr[nf], acc2[1][nf], 0, 0, 0);
        }
    }

    // ---- energies ----
    float p0[4] = {0.f,0.f,0.f,0.f};
    float p1[4] = {0.f,0.f,0.f,0.f};
    #pragma unroll
    for (int nf = 0; nf < 4; ++nf) {
        int o = wn0 + nf * 16 + (lane & 15);
        float l1b = lt1_b[(size_t)u * H + o];
        float sw  = scale_W[(size_t)u * H + o];
        #pragma unroll
        for (int j = 0; j < 4; ++j)
            p0[j] += tanhf(acc2[0][nf][j] + l1b) * sw;
        if (paired)
            #pragma unroll
            for (int j = 0; j < 4; ++j)
                p1[j] += tanhf(acc2[1][nf][j] + l1b) * sw;
    }
    #pragma unroll
    for (int j = 0; j < 4; ++j) {
        float v = p0[j];
        v += __shfl_xor(v, 1, 64); v += __shfl_xor(v, 2, 64);
        v += __shfl_xor(v, 4, 64); v += __shfl_xor(v, 8, 64);
        if ((lane & 15) == 0) red[0 * 64 + wave * 16 + (lane >> 4) * 4 + j] = v;
        float w = p1[j];
        w += __shfl_xor(w, 1, 64); w += __shfl_xor(w, 2, 64);
        w += __shfl_xor(w, 4, 64); w += __shfl_xor(w, 8, 64);
        if ((lane & 15) == 0) red[1 * 64 + wave * 16 + (lane >> 4) * 4 + j] = w;
    }
    __syncthreads();
    if (tid < 32) {
        int sm = tid >> 4, mm = tid & 15;
        e_lds[sm * 16 + mm] = red[sm * 64 + mm] + red[sm * 64 + 16 + mm]
                            + red[sm * 64 + 32 + mm] + red[sm * 64 + 48 + mm]
                            + scale_b[u];
    }
    __syncthreads();

    const int nsm = paired ? 2 : 1;
    for (int sm = 0; sm < nsm; ++sm) {
        const int bs = sm ? b1 : b0;
        float mx = -1e30f;
        #pragma unroll
        for (int m = 0; m < M; ++m) mx = fmaxf(mx, e_lds[sm * 16 + m]);
        float sum = 0.f;
        float aw[M];
        #pragma unroll
        for (int m = 0; m < M; ++m) { aw[m] = expf(e_lds[sm * 16 + m] - mx); sum += aw[m]; }
        float inv = 1.f / sum;
        if (tid < M)
            __builtin_nontemporal_store(aw[tid] * inv, &out[O_ATT + (size_t)bs * M + tid]);
        float ctx = 0.f;
        #pragma unroll
        for (int m = 0; m < M; ++m)
            ctx += aw[m] * inter_output[(size_t)bs * M * H + m * H + tid];
        xcat[(size_t)bs * 768 + 256 + tid] = (__bf16)(ctx * inv);
    }
}

// ---- fused GRU GEMM + gate: gates tile in LDS, hn written directly ----
__global__ __launch_bounds__(256) void xgemm_gate_kernel(
    const __bf16* __restrict__ xcat, const __bf16* __restrict__ wcat,
    const float* __restrict__ hidden,
    const float* __restrict__ bih, const float* __restrict__ bhh,
    float* __restrict__ out, __bf16* __restrict__ hnb)
{
    const int n0   = blockIdx.x * 64;
    const int m0   = blockIdx.y * 64;
    const int tid  = threadIdx.x;
    const int wave = tid >> 6, lane = tid & 63;
    const int wm   = wave >> 1, wn = wave & 1;

    __shared__ __align__(16) __bf16 Al[64 * 128];
    __shared__ __align__(16) __bf16 Bl[64 * 128];
    __shared__ __align__(16) float  Cs[64 * 68];

    f32x4 acc[2][2];
    #pragma unroll
    for (int mf = 0; mf < 2; ++mf)
        #pragma unroll
        for (int nf = 0; nf < 2; ++nf) { f32x4 z = {0.f,0.f,0.f,0.f}; acc[mf][nf] = z; }

    for (int ks = 0; ks < 6; ++ks) {
        #pragma unroll
        for (int r = 0; r < 4; ++r) {
            int L = r * 256 + tid;
            int row = L >> 4, c = L & 15;
            int sc = c ^ (row & 7);
            GLDS(xcat + (size_t)(m0 + row) * 768 + ks * 128 + sc * 8, &Al[(size_t)L * 8]);
        }
        #pragma unroll
        for (int r = 0; r < 4; ++r) {
            int L = r * 256 + tid;
            int row = L >> 4, c = L & 15;
            int sc = c ^ (row & 7);
            GLDS(wcat + (size_t)(n0 + row) * 768 + ks * 128 + sc * 8, &Bl[(size_t)L * 8]);
        }
        __syncthreads();
        #pragma unroll
        for (int kk = 0; kk < 4; ++kk) {
            bf16x8 af[2];
            #pragma unroll
            for (int mf = 0; mf < 2; ++mf) {
                int row = wm * 32 + mf * 16 + (lane & 15);
                int c   = kk * 4 + (lane >> 4);
                af[mf] = *(const bf16x8*)&Al[row * 128 + (c ^ (row & 7)) * 8];
            }
            bf16x8 bfr[2];
            #pragma unroll
            for (int nf = 0; nf < 2; ++nf) {
                int col = wn * 32 + nf * 16 + (lane & 15);
                int c   = kk * 4 + (lane >> 4);
                bfr[nf] = *(const bf16x8*)&Bl[col * 128 + (c ^ (col & 7)) * 8];
            }
            #pragma unroll
            for (int mf = 0; mf < 2; ++mf)
                #pragma unroll
                for (int nf = 0; nf < 2; ++nf)
                    acc[mf][nf] = __builtin_amdgcn_mfma_f32_16x16x32_bf16(
                        af[mf], bfr[nf], acc[mf][nf], 0, 0, 0);
        }
        __syncthreads();
    }

    #pragma unroll
    for (int nf = 0; nf < 2; ++nf) {
        int lc = wn * 32 + nf * 16 + (lane & 15);
        #pragma unroll
        for (int mf = 0; mf < 2; ++mf) {
            int lr = wm * 32 + mf * 16 + (lane >> 4) * 4;
            f32x4 a = acc[mf][nf];
            #pragma unroll
            for (int j = 0; j < 4; ++j)
                Cs[(lr + j) * 68 + lc] = a[j];
        }
    }
    __syncthreads();

    #pragma unroll
    for (int k = 0; k < 4; ++k) {
        int idx = k * 256 + tid;
        int r = idx >> 4, g = idx & 15;
        f32x4 c = *(const f32x4*)&Cs[r * 68 + g * 4];
        int b = m0 + r;
        int j = (n0 >> 2) + g;
        float rs  = c[0] + bih[j]       + bhh[j];
        float zs  = c[1] + bih[256 + j] + bhh[256 + j];
        float gin = c[2] + bih[512 + j];
        float ghn = c[3] + bhh[512 + j];
        float h   = hidden[(size_t)b * H + j];
        float r_  = 1.f / (1.f + expf(-rs));
        float z_  = 1.f / (1.f + expf(-zs));
        float n_  = tanhf(gin + r_ * ghn);
        float hn  = (1.f - z_) * n_ + z_ * h;
        __builtin_nontemporal_store(hn, &out[O_HID + (size_t)b * H + j]);
        __builtin_nontemporal_store(hn, &out[O_GRU + (size_t)b * H + j]);
        hnb[(size_t)b * H + j] = (__bf16)hn;
    }
}

// -------- Stage C (MFMA): out = hnew(bf16) @ WT^T + lin_b --------
// GBN=128 -> 48 KB LDS -> 3 blocks/CU; nt stores keep L2 for WT reuse.
#define GBM 64
#define GBN 128
#define GBK 64
#define NTM 16
#define NTN 235                      // ceil(30000/128)
#define NWG (NTN * NTM)              // 3760, divisible by 8
__global__ __launch_bounds__(256, 3) void out_mfma_kernel(
    const __bf16* __restrict__ hnb,
    const __bf16* __restrict__ WT,
    const float* __restrict__ lin_b,
    float* __restrict__ out)
{
    const int L  = blockIdx.x;
    const int s  = (L & 7) * (NWG / 8) + (L >> 3);
    const int nt = s >> 4, mt = s & 15;
    const int n0 = nt * GBN;
    const int m0 = mt * GBM;
    const int tid  = threadIdx.x;
    const int wave = tid >> 6, lane = tid & 63;

    __shared__ __align__(16) char gsm[GBM * H * 2 + GBN * GBK * 2];  // 48 KB
    __bf16* Al = (__bf16*)gsm;
    __bf16* Bl = (__bf16*)(gsm + GBM * H * 2);

    #pragma unroll
    for (int r = 0; r < 8; ++r) {
        int Li = r * 256 + tid;
        int m = Li >> 5;
        int c = Li & 31;
        int sc = c ^ (m & 7);
        GLDS(hnb + (size_t)(m0 + m) * H + sc * 8, &Al[(size_t)Li * 8]);
    }

    f32x4 acc[4][2];
    #pragma unroll
    for (int mf = 0; mf < 4; ++mf)
        #pragma unroll
        for (int nf = 0; nf < 2; ++nf) {
            f32x4 z = {0.f, 0.f, 0.f, 0.f};
            acc[mf][nf] = z;
        }

    const int wn0 = wave * 32;

    for (int ks = 0; ks < 4; ++ks) {
        // stage B: 128 rows x 64 k bf16 = 1024 slots of 16 B
        #pragma unroll
        for (int r = 0; r < 4; ++r) {
            int Li = r * 256 + tid;
            int n = Li >> 3;
            int c = Li & 7;
            int sc = c ^ (n & 7);
            int nn = n0 + n; if (nn >= V) nn = V - 1;
            GLDS(WT + (size_t)nn * H + ks * GBK + sc * 8, &Bl[(size_t)Li * 8]);
        }
        __syncthreads();

        #pragma unroll
        for (int kk = 0; kk < 2; ++kk) {
            bf16x8 af[4];
            #pragma unroll
            for (int mf = 0; mf < 4; ++mf) {
                int row = mf * 16 + (lane & 15);
                int c   = ks * 8 + kk * 4 + (lane >> 4);
                int cs  = c ^ (row & 7);
                af[mf] = *(const bf16x8*)&Al[row * H + cs * 8];
            }
            bf16x8 bfr[2];
            #pragma unroll
            for (int nf = 0; nf < 2; ++nf) {
                int col = wn0 + nf * 16 + (lane & 15);
                int c   = kk * 4 + (lane >> 4);
                int cs  = c ^ (col & 7);
                bfr[nf] = *(const bf16x8*)&Bl[col * GBK + cs * 8];
            }
            #pragma unroll
            for (int mf = 0; mf < 4; ++mf)
                #pragma unroll
                for (int nf = 0; nf < 2; ++nf)
                    acc[mf][nf] = __builtin_amdgcn_mfma_f32_16x16x32_bf16(
                        af[mf], bfr[nf], acc[mf][nf], 0, 0, 0);
        }
        __syncthreads();
    }

    // ---- epilogue: stage C tile (64x128 f32 = 32 KB) in LDS, coalesced nt row writes ----
    float* Cs = (float*)gsm;
    #pragma unroll
    for (int nf = 0; nf < 2; ++nf) {
        int col = wn0 + nf * 16 + (lane & 15);
        #pragma unroll
        for (int mf = 0; mf < 4; ++mf) {
            #pragma unroll
            for (int j = 0; j < 4; ++j)
                Cs[(mf * 16 + (lane >> 4) * 4 + j) * 128 + col] = acc[mf][nf][j];
        }
    }
    __syncthreads();

    const int c4 = tid & 31;                  // col quad 0..31
    const bool nok = (n0 + c4 * 4 + 3 < V);
    f32x4 lb = {0.f, 0.f, 0.f, 0.f};
    if (nok) lb = *(const f32x4*)&lin_b[n0 + c4 * 4];
    #pragma unroll
    for (int it = 0; it < 8; ++it) {
        int idx = it * 256 + tid;
        int r = idx >> 5;                     // 0..63
        f32x4 c = *(const f32x4*)&Cs[r * 128 + c4 * 4];
        c += lb;
        if (nok)
            __builtin_nontemporal_store(c, (f32x4*)&out[(size_t)(m0 + r) * V + n0 + c4 * 4]);
    }
}

extern "C" void kernel_launch(void* const* d_in, const int* in_sizes, int n_in,
                              void* d_out, int out_size, void* d_ws, size_t ws_size,
                              hipStream_t stream) {
    const float* emb    = (const float*)d_in[1];
    const float* hidden = (const float*)d_in[2];
    const float* io     = (const float*)d_in[3];
    const int*   ul     = (const int*)  d_in[4];
    const float* iW     = (const float*)d_in[5];
    const float* ib     = (const float*)d_in[6];
    const float* hW     = (const float*)d_in[7];
    const float* hb     = (const float*)d_in[8];
    const float* l1W    = (const float*)d_in[9];
    const float* l1b    = (const float*)d_in[10];
    const float* sW     = (const float*)d_in[11];
    const float* sb     = (const float*)d_in[12];
    const float* Wih    = (const float*)d_in[13];
    const float* Whh    = (const float*)d_in[14];
    const float* bih    = (const float*)d_in[15];
    const float* bhh    = (const float*)d_in[16];
    const float* lW     = (const float*)d_in[17];
    const float* lb     = (const float*)d_in[18];

    float* out = (float*)d_out;
    char* ws = (char*)d_ws;
    int*    order = (int*)ws;                                       // 4 KB
    int*    rbase = (int*)(ws + 4096);                              // 4 KB
    __bf16* xcat  = (__bf16*)(ws + 8192);                           // 1.57 MB
    __bf16* wcat  = (__bf16*)(ws + 8192 + 1572864);                 // 1.57 MB
    __bf16* hnb   = (__bf16*)(ws + 8192 + 2 * 1572864);             // 0.5 MB
    __bf16* WT    = (__bf16*)(ws + 8192 + 2 * 1572864 + 524288);

    sort_kernel<<<1, 1024, 0, stream>>>(ul, order, rbase);
    fused_pre_kernel<<<FB_TOT, 256, 0, stream>>>(
        hidden, io, ul, order, rbase, iW, ib, hW, hb, l1W, l1b, sW, sb,
        emb, Wih, Whh, lW, out, xcat, wcat, WT);
    xgemm_gate_kernel<<<dim3(16, 16), 256, 0, stream>>>(xcat, wcat, hidden, bih, bhh, out, hnb);
    out_mfma_kernel<<<NWG, 256, 0, stream>>>(hnb, WT, lb, out);
}

// Round 10
// 224.648 us; speedup vs baseline: 4.2534x; 1.0350x over previous
//
#include <hip/hip_runtime.h>
#include <math.h>

#define B 1024
#define M 15
#define H 256
#define E 256
#define V 30000
#define U 1000

typedef float  vf4    __attribute__((ext_vector_type(4)));
typedef __bf16 bf16x8 __attribute__((ext_vector_type(8)));
typedef float  f32x4  __attribute__((ext_vector_type(4)));

// output layout (flat f32 concat, reference return order)
#define O_OUT   0
#define O_HID   ((size_t)B*V)
#define O_EMB   (O_HID + (size_t)B*H)
#define O_GRU   (O_EMB + (size_t)B*E)
#define O_ATT   (O_GRU + (size_t)B*H)

#define GLDS(g, l) __builtin_amdgcn_global_load_lds( \
    (const __attribute__((address_space(1))) void*)(g), \
    (__attribute__((address_space(3))) void*)(l), 16, 0, 0)

union BF8 { __bf16 h[8]; bf16x8 v; };
union BF4 { __bf16 h[4]; unsigned long long u; };

// =============== kernel1: sort (bid 0) | transpose (1..500) | wcat (501..564) ===============
// 1024 threads/block. sort's serial latency hides under the 135 MB section stream.
#define K1_TR   500
#define K1_WC   64
#define K1_TOT  (1 + K1_TR + K1_WC)

__global__ __launch_bounds__(1024) void pre_kernel(
    const int*   __restrict__ ul,
    const float* __restrict__ Wih,          // (3H,2E)
    const float* __restrict__ Whh,          // (3H,H)
    const float* __restrict__ lin_W,        // (H,V)
    int* __restrict__ order, int* __restrict__ rbase_g,
    __bf16* __restrict__ wcat,              // (1024,768), gate-group-reordered
    __bf16* __restrict__ WT)                // (V,H)
{
    __shared__ __align__(16) char smem[32640];
    const int bid = blockIdx.x;
    const int tid = threadIdx.x;

    if (bid == 0) {
        // ---------------- counting sort by user ----------------
        __shared__ int cnt[1024];
        __shared__ int base[1024];
        cnt[tid] = 0;
        __syncthreads();
        const int u = ul[tid];
        atomicAdd(&cnt[u], 1);
        __syncthreads();
        int c0 = cnt[tid];
        int v  = c0;
        for (int off = 1; off < 1024; off <<= 1) {
            int add = (tid >= off) ? cnt[tid - off] : 0;
            __syncthreads();
            v += add;
            cnt[tid] = v;
            __syncthreads();
        }
        base[tid]    = v - c0;
        rbase_g[tid] = v - c0;
        __syncthreads();
        int pos = atomicAdd(&base[u], 1);
        order[pos] = tid;
        return;
    }

    if (bid <= K1_TR) {
        // ---------------- transpose: lin_W (H,V) f32 -> WT (V,H) bf16 ----------------
        const int t   = bid - 1;
        const int v0  = (t % 125) * 240;
        const int k0  = (t / 125) * 64;
        const int lane = tid & 63, kq = tid >> 6;   // kq 0..15
        __bf16* T = (__bf16*)smem;                  // 240*68 bf16 = 32640 B

        if (lane < 60) {
            int kr = kq * 4;
            vf4 f0 = *(const vf4*)&lin_W[(size_t)(k0 + kr + 0) * V + v0 + lane * 4];
            vf4 f1 = *(const vf4*)&lin_W[(size_t)(k0 + kr + 1) * V + v0 + lane * 4];
            vf4 f2 = *(const vf4*)&lin_W[(size_t)(k0 + kr + 2) * V + v0 + lane * 4];
            vf4 f3 = *(const vf4*)&lin_W[(size_t)(k0 + kr + 3) * V + v0 + lane * 4];
            #pragma unroll
            for (int j = 0; j < 4; ++j) {
                BF4 pk;
                pk.h[0] = (__bf16)f0[j];
                pk.h[1] = (__bf16)f1[j];
                pk.h[2] = (__bf16)f2[j];
                pk.h[3] = (__bf16)f3[j];
                int v = lane * 4 + j;
                *(unsigned long long*)&T[v * 68 + kr] = pk.u;
            }
        }
        __syncthreads();
        #pragma unroll
        for (int r = 0; r < 4; ++r) {
            int L = r * 1024 + tid;
            int v = L >> 4, c = L & 15;
            if (v < 240)
                __builtin_nontemporal_store(
                    *(const unsigned long long*)&T[v * 68 + c * 4],
                    (unsigned long long*)&WT[(size_t)(v0 + v) * H + k0 + c * 4]);
        }
        return;
    }

    // ---------------- wcat (gate-group column order) ----------------
    // wcat row n holds orig row r = (n>>2) + 256*(n&3)
    {
        const int wb   = bid - 1 - K1_TR;
        const int lane = tid & 63;
        const int n    = wb * 16 + (tid >> 6);
        const int r    = (n >> 2) + ((n & 3) << 8);
        #pragma unroll
        for (int i = 0; i < 3; ++i) {
            int k = i * 256 + lane * 4;
            vf4 v = {0.f, 0.f, 0.f, 0.f};
            if (r < 512) {
                v = (k < 512) ? *(const vf4*)&Wih[(size_t)r * 512 + k]
                              : *(const vf4*)&Whh[(size_t)r * 256 + (k - 512)];
            } else if (r < 768) {
                if (k < 512) v = *(const vf4*)&Wih[(size_t)r * 512 + k];
            } else {
                if (k >= 512) v = *(const vf4*)&Whh[(size_t)(r - 256) * 256 + (k - 512)];
            }
            BF4 p;
            p.h[0]=(__bf16)v[0]; p.h[1]=(__bf16)v[1]; p.h[2]=(__bf16)v[2]; p.h[3]=(__bf16)v[3];
            *(unsigned long long*)&wcat[(size_t)n * 768 + k] = p.u;
        }
    }
}

// ---------------- Stage A: per-user attention (MFMA, reg-B, paired) ----------------
__global__ __launch_bounds__(256, 3) void attn_kernel(
    const float* __restrict__ hidden,       // (1,B,H)
    const float* __restrict__ inter_output, // (B,M,H)
    const int*   __restrict__ user_list,    // (B,)
    const int*   __restrict__ order,        // (B,)
    const int*   __restrict__ rbase,        // (1024,)
    const float* __restrict__ inter_W,      // (U,H,H)
    const float* __restrict__ inter_b,      // (U,H)
    const float* __restrict__ hidden_W,     // (U,H,H)
    const float* __restrict__ hidden_b,     // (U,H)
    const float* __restrict__ lt1_W,        // (U,2H,H)
    const float* __restrict__ lt1_b,        // (U,H)
    const float* __restrict__ scale_W,      // (U,H)
    const float* __restrict__ scale_b,      // (U,)
    const float* __restrict__ emb,          // (B,1,E)
    float* __restrict__ out,
    __bf16* __restrict__ xcat)              // (B,768)
{
    __shared__ __align__(16) char smem[34432];
    const int bid = blockIdx.x;
    const int tid = threadIdx.x;

    const int s   = ((bid & 7) << 7) + (bid >> 3);  // XCD chunk swizzle
    const int b0  = order[s];
    const int u   = user_list[b0];

    // cvt_xh for this block's sample (all 1024 blocks)
    {
        float ev = emb[(size_t)b0 * E + tid];
        float hv = hidden[(size_t)b0 * H + tid];
        xcat[(size_t)b0 * 768 + tid]       = (__bf16)ev;
        xcat[(size_t)b0 * 768 + 512 + tid] = (__bf16)hv;
        __builtin_nontemporal_store(ev, &out[O_EMB + (size_t)b0 * E + tid]);
    }

    if ((s - rbase[u]) & 1) return;         // not a run head
    bool paired = false;
    int  b1 = b0;
    if (s + 1 < B) {
        int ob = order[s + 1];
        if (user_list[ob] == u) { paired = true; b1 = ob; }
    }

    const int lane = tid & 63;
    const int wave = tid >> 6;
    const int wn0  = wave * 64;

    __bf16* Abuf = (__bf16*)smem;                       // 32 KB
    __bf16* hta  = (__bf16*)(smem + 32768);             // 2*256 bf16 = 1 KB
    float*  red  = (float*)(smem + 32768 + 1024);       // 2*64 f32 = 512 B
    float*  e_lds= (float*)(smem + 32768 + 1024 + 512); // 2*16 f32 = 128 B

    // ---- phase 1: A = [io|0 ; 0|ht] for both samples ----
    {
        const int r    = tid >> 3;
        const int part = tid & 7;
        const int sm   = r >> 4;
        const int mr   = r & 15;
        const int bs   = sm ? b1 : b0;
        const bool zr  = (sm == 1) && !paired;
        #pragma unroll
        for (int it = 0; it < 8; ++it) {
            int c = part + it * 8;
            int k = c * 8;
            BF8 p;
            #pragma unroll
            for (int j = 0; j < 8; ++j) p.h[j] = (__bf16)0.f;
            if (!zr) {
                if (mr < 15 && k < 256) {
                    vf4 f0 = *(const vf4*)&inter_output[(size_t)bs * M * H + mr * H + k];
                    vf4 f1 = *(const vf4*)&inter_output[(size_t)bs * M * H + mr * H + k + 4];
                    p.h[0]=(__bf16)f0[0]; p.h[1]=(__bf16)f0[1]; p.h[2]=(__bf16)f0[2]; p.h[3]=(__bf16)f0[3];
                    p.h[4]=(__bf16)f1[0]; p.h[5]=(__bf16)f1[1]; p.h[6]=(__bf16)f1[2]; p.h[7]=(__bf16)f1[3];
                } else if (mr == 15 && k >= 256) {
                    vf4 f0 = *(const vf4*)&hidden[(size_t)bs * H + (k - 256)];
                    vf4 f1 = *(const vf4*)&hidden[(size_t)bs * H + (k - 256) + 4];
                    p.h[0]=(__bf16)f0[0]; p.h[1]=(__bf16)f0[1]; p.h[2]=(__bf16)f0[2]; p.h[3]=(__bf16)f0[3];
                    p.h[4]=(__bf16)f1[0]; p.h[5]=(__bf16)f1[1]; p.h[6]=(__bf16)f1[2]; p.h[7]=(__bf16)f1[3];
                }
            }
            *(bf16x8*)&Abuf[r * 512 + (c ^ (r & 7)) * 8] = p.v;
        }
    }
    __syncthreads();

    const float* Wi_base  = inter_W  + (size_t)u * H * H;
    const float* Wh_base  = hidden_W + (size_t)u * H * H;
    const float* lt1_base = lt1_W    + (size_t)u * 2 * H * H;

    const int ocol = wn0 + (lane & 15);
    const int krow = (lane >> 4) * 8;

    f32x4 acc1[2][4];
    #pragma unroll
    for (int mf = 0; mf < 2; ++mf)
        #pragma unroll
        for (int nf = 0; nf < 4; ++nf) { f32x4 z = {0.f,0.f,0.f,0.f}; acc1[mf][nf] = z; }

    // ================= GEMM 1 =================
    #pragma unroll 2
    for (int ks = 0; ks < 16; ++ks) {
        const float* Bp = ((ks < 8) ? (Wi_base + (size_t)(ks * 32) * H)
                                    : (Wh_base + (size_t)((ks - 8) * 32) * H))
                          + (size_t)krow * H + ocol;
        float t[4][8];
        #pragma unroll
        for (int j = 0; j < 8; ++j)
            #pragma unroll
            for (int nf = 0; nf < 4; ++nf)
                t[nf][j] = Bp[(size_t)j * H + nf * 16];
        bf16x8 bfr[4];
        #pragma unroll
        for (int nf = 0; nf < 4; ++nf) {
            BF8 pk;
            #pragma unroll
            for (int j = 0; j < 8; ++j) pk.h[j] = (__bf16)t[nf][j];
            bfr[nf] = pk.v;
        }
        int sca = ((ks * 4 + (lane >> 4)) ^ (lane & 7)) * 8;
        bf16x8 a0 = *(const bf16x8*)&Abuf[(lane & 15) * 512 + sca];
        #pragma unroll
        for (int nf = 0; nf < 4; ++nf)
            acc1[0][nf] = __builtin_amdgcn_mfma_f32_16x16x32_bf16(a0, bfr[nf], acc1[0][nf], 0, 0, 0);
        if (paired) {
            bf16x8 a1 = *(const bf16x8*)&Abuf[(16 + (lane & 15)) * 512 + sca];
            #pragma unroll
            for (int nf = 0; nf < 4; ++nf)
                acc1[1][nf] = __builtin_amdgcn_mfma_f32_16x16x32_bf16(a1, bfr[nf], acc1[1][nf], 0, 0, 0);
        }
    }
    __syncthreads();

    // ---- extract ht_a + hidden_b ; io_a+bi into Abuf k>=256 ----
    if ((lane >> 4) == 3) {
        #pragma unroll
        for (int nf = 0; nf < 4; ++nf) {
            int o = wn0 + nf * 16 + (lane & 15);
            float hb = hidden_b[(size_t)u * H + o];
            hta[o]       = (__bf16)(acc1[0][nf][3] + hb);
            hta[256 + o] = (__bf16)(acc1[1][nf][3] + hb);
        }
    }
    #pragma unroll
    for (int mf = 0; mf < 2; ++mf) {
        #pragma unroll
        for (int nf = 0; nf < 4; ++nf) {
            int o  = wn0 + nf * 16 + (lane & 15);
            float bi = inter_b[(size_t)u * H + o];
            int k  = 256 + o;
            #pragma unroll
            for (int j = 0; j < 4; ++j) {
                int r  = mf * 16 + (lane >> 4) * 4 + j;
                Abuf[r * 512 + ((k >> 3) ^ (r & 7)) * 8 + (k & 7)] = (__bf16)(acc1[mf][nf][j] + bi);
            }
        }
    }
    __syncthreads();

    // ---- phase 2 low-K: hta broadcast ----
    {
        const int r    = tid >> 3;
        const int part = tid & 7;
        const int sm   = r >> 4;
        #pragma unroll
        for (int it = 0; it < 4; ++it) {
            int c = part + it * 8;
            bf16x8 hv = *(const bf16x8*)&hta[sm * 256 + c * 8];
            *(bf16x8*)&Abuf[r * 512 + (c ^ (r & 7)) * 8] = hv;
        }
    }
    __syncthreads();

    f32x4 acc2[2][4];
    #pragma unroll
    for (int mf = 0; mf < 2; ++mf)
        #pragma unroll
        for (int nf = 0; nf < 4; ++nf) { f32x4 z = {0.f,0.f,0.f,0.f}; acc2[mf][nf] = z; }

    // ================= GEMM 2 =================
    #pragma unroll 2
    for (int ks = 0; ks < 16; ++ks) {
        const float* Bp = lt1_base + (size_t)(ks * 32) * H + (size_t)krow * H + ocol;
        float t[4][8];
        #pragma unroll
        for (int j = 0; j < 8; ++j)
            #pragma unroll
            for (int nf = 0; nf < 4; ++nf)
                t[nf][j] = Bp[(size_t)j * H + nf * 16];
        bf16x8 bfr[4];
        #pragma unroll
        for (int nf = 0; nf < 4; ++nf) {
            BF8 pk;
            #pragma unroll
            for (int j = 0; j < 8; ++j) pk.h[j] = (__bf16)t[nf][j];
            bfr[nf] = pk.v;
        }
        int sca = ((ks * 4 + (lane >> 4)) ^ (lane & 7)) * 8;
        bf16x8 a0 = *(const bf16x8*)&Abuf[(lane & 15) * 512 + sca];
        #pragma unroll
        for (int nf = 0; nf < 4; ++nf)
            acc2[0][nf] = __builtin_amdgcn_mfma_f32_16x16x32_bf16(a0, bfr[nf], acc2[0][nf], 0, 0, 0);
        if (paired) {
            bf16x8 a1 = *(const bf16x8*)&Abuf[(16 + (lane & 15)) * 512 + sca];
            #pragma unroll
            for (int nf = 0; nf < 4; ++nf)
                acc2[1][nf] = __builtin_amdgcn_mfma_f32_16x16x32_bf16(a1, bfr[nf], acc2[1][nf], 0, 0, 0);
        }
    }

    // ---- energies ----
    float p0[4] = {0.f,0.f,0.f,0.f};
    float p1[4] = {0.f,0.f,0.f,0.f};
    #pragma unroll
    for (int nf = 0; nf < 4; ++nf) {
        int o = wn0 + nf * 16 + (lane & 15);
        float l1b = lt1_b[(size_t)u * H + o];
        float sw  = scale_W[(size_t)u * H + o];
        #pragma unroll
        for (int j = 0; j < 4; ++j)
            p0[j] += tanhf(acc2[0][nf][j] + l1b) * sw;
        if (paired)
            #pragma unroll
            for (int j = 0; j < 4; ++j)
                p1[j] += tanhf(acc2[1][nf][j] + l1b) * sw;
    }
    #pragma unroll
    for (int j = 0; j < 4; ++j) {
        float v = p0[j];
        v += __shfl_xor(v, 1, 64); v += __shfl_xor(v, 2, 64);
        v += __shfl_xor(v, 4, 64); v += __shfl_xor(v, 8, 64);
        if ((lane & 15) == 0) red[0 * 64 + wave * 16 + (lane >> 4) * 4 + j] = v;
        float w = p1[j];
        w += __shfl_xor(w, 1, 64); w += __shfl_xor(w, 2, 64);
        w += __shfl_xor(w, 4, 64); w += __shfl_xor(w, 8, 64);
        if ((lane & 15) == 0) red[1 * 64 + wave * 16 + (lane >> 4) * 4 + j] = w;
    }
    __syncthreads();
    if (tid < 32) {
        int sm = tid >> 4, mm = tid & 15;
        e_lds[sm * 16 + mm] = red[sm * 64 + mm] + red[sm * 64 + 16 + mm]
                            + red[sm * 64 + 32 + mm] + red[sm * 64 + 48 + mm]
                            + scale_b[u];
    }
    __syncthreads();

    const int nsm = paired ? 2 : 1;
    for (int sm = 0; sm < nsm; ++sm) {
        const int bs = sm ? b1 : b0;
        float mx = -1e30f;
        #pragma unroll
        for (int m = 0; m < M; ++m) mx = fmaxf(mx, e_lds[sm * 16 + m]);
        float sum = 0.f;
        float aw[M];
        #pragma unroll
        for (int m = 0; m < M; ++m) { aw[m] = expf(e_lds[sm * 16 + m] - mx); sum += aw[m]; }
        float inv = 1.f / sum;
        if (tid < M)
            __builtin_nontemporal_store(aw[tid] * inv, &out[O_ATT + (size_t)bs * M + tid]);
        float ctx = 0.f;
        #pragma unroll
        for (int m = 0; m < M; ++m)
            ctx += aw[m] * inter_output[(size_t)bs * M * H + m * H + tid];
        xcat[(size_t)bs * 768 + 256 + tid] = (__bf16)(ctx * inv);
    }
}

// ---- fused GRU GEMM + gate: gates tile in LDS, hn written directly ----
__global__ __launch_bounds__(256) void xgemm_gate_kernel(
    const __bf16* __restrict__ xcat, const __bf16* __restrict__ wcat,
    const float* __restrict__ hidden,
    const float* __restrict__ bih, const float* __restrict__ bhh,
    float* __restrict__ out, __bf16* __restrict__ hnb)
{
    const int n0   = blockIdx.x * 64;
    const int m0   = blockIdx.y * 64;
    const int tid  = threadIdx.x;
    const int wave = tid >> 6, lane = tid & 63;
    const int wm   = wave >> 1, wn = wave & 1;

    __shared__ __align__(16) __bf16 Al[64 * 128];
    __shared__ __align__(16) __bf16 Bl[64 * 128];
    __shared__ __align__(16) float  Cs[64 * 68];

    f32x4 acc[2][2];
    #pragma unroll
    for (int mf = 0; mf < 2; ++mf)
        #pragma unroll
        for (int nf = 0; nf < 2; ++nf) { f32x4 z = {0.f,0.f,0.f,0.f}; acc[mf][nf] = z; }

    for (int ks = 0; ks < 6; ++ks) {
        #pragma unroll
        for (int r = 0; r < 4; ++r) {
            int L = r * 256 + tid;
            int row = L >> 4, c = L & 15;
            int sc = c ^ (row & 7);
            GLDS(xcat + (size_t)(m0 + row) * 768 + ks * 128 + sc * 8, &Al[(size_t)L * 8]);
        }
        #pragma unroll
        for (int r = 0; r < 4; ++r) {
            int L = r * 256 + tid;
            int row = L >> 4, c = L & 15;
            int sc = c ^ (row & 7);
            GLDS(wcat + (size_t)(n0 + row) * 768 + ks * 128 + sc * 8, &Bl[(size_t)L * 8]);
        }
        __syncthreads();
        #pragma unroll
        for (int kk = 0; kk < 4; ++kk) {
            bf16x8 af[2];
            #pragma unroll
            for (int mf = 0; mf < 2; ++mf) {
                int row = wm * 32 + mf * 16 + (lane & 15);
                int c   = kk * 4 + (lane >> 4);
                af[mf] = *(const bf16x8*)&Al[row * 128 + (c ^ (row & 7)) * 8];
            }
            bf16x8 bfr[2];
            #pragma unroll
            for (int nf = 0; nf < 2; ++nf) {
                int col = wn * 32 + nf * 16 + (lane & 15);
                int c   = kk * 4 + (lane >> 4);
                bfr[nf] = *(const bf16x8*)&Bl[col * 128 + (c ^ (col & 7)) * 8];
            }
            #pragma unroll
            for (int mf = 0; mf < 2; ++mf)
                #pragma unroll
                for (int nf = 0; nf < 2; ++nf)
                    acc[mf][nf] = __builtin_amdgcn_mfma_f32_16x16x32_bf16(
                        af[mf], bfr[nf], acc[mf][nf], 0, 0, 0);
        }
        __syncthreads();
    }

    #pragma unroll
    for (int nf = 0; nf < 2; ++nf) {
        int lc = wn * 32 + nf * 16 + (lane & 15);
        #pragma unroll
        for (int mf = 0; mf < 2; ++mf) {
            int lr = wm * 32 + mf * 16 + (lane >> 4) * 4;
            f32x4 a = acc[mf][nf];
            #pragma unroll
            for (int j = 0; j < 4; ++j)
                Cs[(lr + j) * 68 + lc] = a[j];
        }
    }
    __syncthreads();

    #pragma unroll
    for (int k = 0; k < 4; ++k) {
        int idx = k * 256 + tid;
        int r = idx >> 4, g = idx & 15;
        f32x4 c = *(const f32x4*)&Cs[r * 68 + g * 4];
        int b = m0 + r;
        int j = (n0 >> 2) + g;
        float rs  = c[0] + bih[j]       + bhh[j];
        float zs  = c[1] + bih[256 + j] + bhh[256 + j];
        float gin = c[2] + bih[512 + j];
        float ghn = c[3] + bhh[512 + j];
        float h   = hidden[(size_t)b * H + j];
        float r_  = 1.f / (1.f + expf(-rs));
        float z_  = 1.f / (1.f + expf(-zs));
        float n_  = tanhf(gin + r_ * ghn);
        float hn  = (1.f - z_) * n_ + z_ * h;
        __builtin_nontemporal_store(hn, &out[O_HID + (size_t)b * H + j]);
        __builtin_nontemporal_store(hn, &out[O_GRU + (size_t)b * H + j]);
        hnb[(size_t)b * H + j] = (__bf16)hn;
    }
}

// -------- Stage C (MFMA): out = hnew(bf16) @ WT^T + lin_b --------
#define GBM 64
#define GBN 128
#define GBK 64
#define NTM 16
#define NTN 235
#define NWG (NTN * NTM)
__global__ __launch_bounds__(256, 3) void out_mfma_kernel(
    const __bf16* __restrict__ hnb,
    const __bf16* __restrict__ WT,
    const float* __restrict__ lin_b,
    float* __restrict__ out)
{
    const int L  = blockIdx.x;
    const int s  = (L & 7) * (NWG / 8) + (L >> 3);
    const int nt = s >> 4, mt = s & 15;
    const int n0 = nt * GBN;
    const int m0 = mt * GBM;
    const int tid  = threadIdx.x;
    const int wave = tid >> 6, lane = tid & 63;

    __shared__ __align__(16) char gsm[GBM * H * 2 + GBN * GBK * 2];  // 48 KB
    __bf16* Al = (__bf16*)gsm;
    __bf16* Bl = (__bf16*)(gsm + GBM * H * 2);

    #pragma unroll
    for (int r = 0; r < 8; ++r) {
        int Li = r * 256 + tid;
        int m = Li >> 5;
        int c = Li & 31;
        int sc = c ^ (m & 7);
        GLDS(hnb + (size_t)(m0 + m) * H + sc * 8, &Al[(size_t)Li * 8]);
    }

    f32x4 acc[4][2];
    #pragma unroll
    for (int mf = 0; mf < 4; ++mf)
        #pragma unroll
        for (int nf = 0; nf < 2; ++nf) {
            f32x4 z = {0.f, 0.f, 0.f, 0.f};
            acc[mf][nf] = z;
        }

    const int wn0 = wave * 32;

    for (int ks = 0; ks < 4; ++ks) {
        #pragma unroll
        for (int r = 0; r < 4; ++r) {
            int Li = r * 256 + tid;
            int n = Li >> 3;
            int c = Li & 7;
            int sc = c ^ (n & 7);
            int nn = n0 + n; if (nn >= V) nn = V - 1;
            GLDS(WT + (size_t)nn * H + ks * GBK + sc * 8, &Bl[(size_t)Li * 8]);
        }
        __syncthreads();

        #pragma unroll
        for (int kk = 0; kk < 2; ++kk) {
            bf16x8 af[4];
            #pragma unroll
            for (int mf = 0; mf < 4; ++mf) {
                int row = mf * 16 + (lane & 15);
                int c   = ks * 8 + kk * 4 + (lane >> 4);
                int cs  = c ^ (row & 7);
                af[mf] = *(const bf16x8*)&Al[row * H + cs * 8];
            }
            bf16x8 bfr[2];
            #pragma unroll
            for (int nf = 0; nf < 2; ++nf) {
                int col = wn0 + nf * 16 + (lane & 15);
                int c   = kk * 4 + (lane >> 4);
                int cs  = c ^ (col & 7);
                bfr[nf] = *(const bf16x8*)&Bl[col * GBK + cs * 8];
            }
            #pragma unroll
            for (int mf = 0; mf < 4; ++mf)
                #pragma unroll
                for (int nf = 0; nf < 2; ++nf)
                    acc[mf][nf] = __builtin_amdgcn_mfma_f32_16x16x32_bf16(
                        af[mf], bfr[nf], acc[mf][nf], 0, 0, 0);
        }
        __syncthreads();
    }

    // ---- epilogue: stage C tile (64x128 f32 = 32 KB) in LDS, coalesced nt row writes ----
    float* Cs = (float*)gsm;
    #pragma unroll
    for (int nf = 0; nf < 2; ++nf) {
        int col = wn0 + nf * 16 + (lane & 15);
        #pragma unroll
        for (int mf = 0; mf < 4; ++mf) {
            #pragma unroll
            for (int j = 0; j < 4; ++j)
                Cs[(mf * 16 + (lane >> 4) * 4 + j) * 128 + col] = acc[mf][nf][j];
        }
    }
    __syncthreads();

    const int c4 = tid & 31;
    const bool nok = (n0 + c4 * 4 + 3 < V);
    f32x4 lb = {0.f, 0.f, 0.f, 0.f};
    if (nok) lb = *(const f32x4*)&lin_b[n0 + c4 * 4];
    #pragma unroll
    for (int it = 0; it < 8; ++it) {
        int idx = it * 256 + tid;
        int r = idx >> 5;
        f32x4 c = *(const f32x4*)&Cs[r * 128 + c4 * 4];
        c += lb;
        if (nok)
            __builtin_nontemporal_store(c, (f32x4*)&out[(size_t)(m0 + r) * V + n0 + c4 * 4]);
    }
}

extern "C" void kernel_launch(void* const* d_in, const int* in_sizes, int n_in,
                              void* d_out, int out_size, void* d_ws, size_t ws_size,
                              hipStream_t stream) {
    const float* emb    = (const float*)d_in[1];
    const float* hidden = (const float*)d_in[2];
    const float* io     = (const float*)d_in[3];
    const int*   ul     = (const int*)  d_in[4];
    const float* iW     = (const float*)d_in[5];
    const float* ib     = (const float*)d_in[6];
    const float* hW     = (const float*)d_in[7];
    const float* hb     = (const float*)d_in[8];
    const float* l1W    = (const float*)d_in[9];
    const float* l1b    = (const float*)d_in[10];
    const float* sW     = (const float*)d_in[11];
    const float* sb     = (const float*)d_in[12];
    const float* Wih    = (const float*)d_in[13];
    const float* Whh    = (const float*)d_in[14];
    const float* bih    = (const float*)d_in[15];
    const float* bhh    = (const float*)d_in[16];
    const float* lW     = (const float*)d_in[17];
    const float* lb     = (const float*)d_in[18];

    float* out = (float*)d_out;
    char* ws = (char*)d_ws;
    int*    order = (int*)ws;                                       // 4 KB
    int*    rbase = (int*)(ws + 4096);                              // 4 KB
    __bf16* xcat  = (__bf16*)(ws + 8192);                           // 1.57 MB
    __bf16* wcat  = (__bf16*)(ws + 8192 + 1572864);                 // 1.57 MB
    __bf16* hnb   = (__bf16*)(ws + 8192 + 2 * 1572864);             // 0.5 MB
    __bf16* WT    = (__bf16*)(ws + 8192 + 2 * 1572864 + 524288);

    pre_kernel<<<K1_TOT, 1024, 0, stream>>>(ul, Wih, Whh, lW, order, rbase, wcat, WT);
    attn_kernel<<<B, 256, 0, stream>>>(hidden, io, ul, order, rbase, iW, ib, hW, hb,
                                       l1W, l1b, sW, sb, emb, out, xcat);
    xgemm_gate_kernel<<<dim3(16, 16), 256, 0, stream>>>(xcat, wcat, hidden, bih, bhh, out, hnb);
    out_mfma_kernel<<<NWG, 256, 0, stream>>>(hnb, WT, lb, out);
}